// Round 1
// baseline (567.360 us; speedup 1.0000x reference)
//
#include <hip/hip_runtime.h>
#include <stdint.h>

#pragma clang fp contract(off)

typedef unsigned int u32;
typedef unsigned long long u64;

#define A_TOTAL 242991
#define KTOT    4741

// level tables
__constant__ int c_LN[5]   = {182400, 45600, 11400, 2850, 741};
__constant__ int c_LOFF[5] = {0, 182400, 228000, 239400, 242250};
__constant__ int c_LK[5]   = {1000, 1000, 1000, 1000, 741};

// workspace byte offsets (total ~8.73 MB)
static const size_t OFF_HIST     = 0;        // 40*2048*4 = 327680
static const size_t OFF_SELCNT   = 327680;   // 40*4
static const size_t OFF_CANDCNT  = 327840;   // 40*4
static const size_t MEMSET_BYTES = 328000;
static const size_t OFF_TBIN     = 328000;   // 40*4
static const size_t OFF_CLESS    = 328160;   // 40*4
static const size_t OFF_SELG     = 328320;   // 40*1024*8  -> 656000
static const size_t OFF_CANDG    = 656000;   // 40*4096*8  -> 1966720
static const size_t OFF_KEYS     = 1966720;  // 8*4741*8   -> 2270144
static const size_t OFF_BOX      = 2270144;  // 8*4741*4*4 -> 2876992
static const size_t OFF_SCORE    = 2876992;  // 8*4741*4   -> 3028704
static const size_t OFF_VALID    = 3028704;  // 8*4741*4   -> 3180416
static const size_t OFF_MASK     = 3180416;  // 8*5*16*1024*8 -> 8423296
static const size_t OFF_OUTK     = 8423296;  // 8*4741*8   -> 8726720

// monotone float<->uint map: fmap ascending in float value
__device__ __forceinline__ u32 fmap(float f){
  u32 b = __float_as_uint(f);
  return (b & 0x80000000u) ? ~b : (b | 0x80000000u);
}
__device__ __forceinline__ float funmap(u32 m){
  return __uint_as_float((m & 0x80000000u) ? (m & 0x7FFFFFFFu) : ~m);
}

template<int N, int T>
__device__ __forceinline__ void bitonic_sort(u64* d, int tid){
  for (int k = 2; k <= N; k <<= 1){
    for (int j = k >> 1; j > 0; j >>= 1){
      __syncthreads();
      #pragma unroll 1
      for (int i = tid; i < N; i += T){
        int ixj = i ^ j;
        if (ixj > i){
          u64 a = d[i], b = d[ixj];
          bool sw = ((i & k) == 0) ? (a > b) : (a < b);
          if (sw){ d[i] = b; d[ixj] = a; }
        }
      }
    }
  }
  __syncthreads();
}

// block -> (b, level, segment) mapping: 7 blocks/image (3 for level0, 1 each l1..l4)
__device__ __forceinline__ void seg_map(int blk, int& b, int& l, int& start, int& cnt){
  b = blk / 7; int s = blk % 7;
  l = (s < 3) ? 0 : (s - 2);
  int seg = (s < 3) ? s : 0;
  int n = c_LN[l];
  start = seg * 65536;
  cnt = n - start; if (cnt > 65536) cnt = 65536;
}

// ---------- K1a: per-(b,l) 2048-bin histogram of key-high-11-bits ----------
__global__ void __launch_bounds__(1024)
k_hist(const float* __restrict__ obj, u32* __restrict__ hist)
{
  int b, l, start, cnt; seg_map(blockIdx.x, b, l, start, cnt);
  int bl = b * 5 + l;
  __shared__ u32 h[2048];
  for (int i = threadIdx.x; i < 2048; i += 1024) h[i] = 0;
  __syncthreads();
  const float* p = obj + (size_t)b * A_TOTAL + c_LOFF[l] + start;
  for (int i = threadIdx.x; i < cnt; i += 1024){
    u32 m = ~fmap(p[i]);           // ascending m == descending objectness
    atomicAdd(&h[m >> 21], 1u);
  }
  __syncthreads();
  for (int i = threadIdx.x; i < 2048; i += 1024){
    u32 v = h[i];
    if (v) atomicAdd(&hist[bl * 2048 + i], v);
  }
}

// ---------- K1b: find cutoff bin t and count_less ----------
__global__ void __launch_bounds__(256)
k_cutoff(const u32* __restrict__ hist, u32* __restrict__ tbin, u32* __restrict__ cless)
{
  int bl = blockIdx.x; int l = bl % 5;
  int K = c_LK[l], n = c_LN[l];
  int tid = threadIdx.x;
  if (K >= n){ if (tid == 0){ tbin[bl] = 2048u; cless[bl] = (u32)n; } return; }
  __shared__ u32 cum[2048];
  __shared__ u32 part[256];
  __shared__ int s_t;
  u32 vals[8]; u32 sum = 0;
  for (int q = 0; q < 8; ++q){ vals[q] = hist[bl * 2048 + tid * 8 + q]; sum += vals[q]; }
  part[tid] = sum;
  __syncthreads();
  for (int off = 1; off < 256; off <<= 1){
    u32 add = (tid >= off) ? part[tid - off] : 0u;
    __syncthreads();
    part[tid] += add;
    __syncthreads();
  }
  u32 run = (tid > 0) ? part[tid - 1] : 0u;
  for (int q = 0; q < 8; ++q){ run += vals[q]; cum[tid * 8 + q] = run; }
  if (tid == 0) s_t = 0;
  __syncthreads();
  for (int q = 0; q < 8; ++q){
    int i = tid * 8 + q;
    u32 c = cum[i], cp = (i > 0) ? cum[i - 1] : 0u;
    if (c >= (u32)K && cp < (u32)K) s_t = i;
  }
  __syncthreads();
  if (tid == 0){
    int t = s_t;
    tbin[bl] = (u32)t;
    cless[bl] = (t > 0) ? cum[t - 1] : 0u;
  }
}

// ---------- K1c: collect selected + boundary-bin candidates ----------
__global__ void __launch_bounds__(1024)
k_collect(const float* __restrict__ obj, const u32* __restrict__ tbin,
          u32* __restrict__ selcnt, u32* __restrict__ candcnt,
          u64* __restrict__ selg, u64* __restrict__ candg)
{
  int b, l, start, cnt; seg_map(blockIdx.x, b, l, start, cnt);
  int bl = b * 5 + l;
  u32 t = tbin[bl];
  const float* p = obj + (size_t)b * A_TOTAL + c_LOFF[l] + start;
  for (int i = threadIdx.x; i < cnt; i += 1024){
    u32 m = ~fmap(p[i]);
    u32 bin = m >> 21;
    u64 key = ((u64)m << 32) | (u32)(start + i);
    if (bin < t){
      u32 pos = atomicAdd(&selcnt[bl], 1u);
      selg[(size_t)bl * 1024 + pos] = key;
    } else if (bin == t){
      u32 pos = atomicAdd(&candcnt[bl], 1u);
      if (pos < 4096u) candg[(size_t)bl * 4096 + pos] = key;
    }
  }
}

// ---------- K1d: assemble exact top-K and sort descending-by-obj ----------
__global__ void __launch_bounds__(1024)
k_select(const u32* __restrict__ selcnt, const u32* __restrict__ candcnt,
         const u64* __restrict__ selg, const u64* __restrict__ candg,
         u64* __restrict__ keys)
{
  int bl = blockIdx.x; int b = bl / 5, l = bl % 5;
  int K = c_LK[l];
  int tid = threadIdx.x;
  __shared__ u64 cand[4096];
  __shared__ u64 sel[1024];
  u32 nc = candcnt[bl]; if (nc > 4096u) nc = 4096u;
  u32 ns = selcnt[bl];
  int R = K - (int)ns;
  for (int i = tid; i < 4096; i += 1024) cand[i] = (i < (int)nc) ? candg[(size_t)bl * 4096 + i] : ~0ULL;
  sel[tid] = ~0ULL;
  __syncthreads();
  if (R > 0){
    bitonic_sort<4096, 1024>(cand, tid);
  }
  for (int i = tid; i < (int)ns; i += 1024) sel[i] = selg[(size_t)bl * 1024 + i];
  for (int i = tid; i < R; i += 1024) sel[(int)ns + i] = cand[i];
  bitonic_sort<1024, 1024>(sel, tid);
  for (int i = tid; i < K; i += 1024) keys[(size_t)b * KTOT + l * 1000 + i] = sel[i];
}

// ---------- K2: gather + decode + clip + sigmoid + validity ----------
__global__ void __launch_bounds__(256)
k_decode(const u64* __restrict__ keys, const float* __restrict__ deltas,
         const float* __restrict__ anchors, float* __restrict__ boxes,
         float* __restrict__ scores, u32* __restrict__ valid)
{
  int g = blockIdx.x * 256 + threadIdx.x;
  if (g >= 8 * KTOT) return;
  int b = g / KTOT, kpos = g % KTOT;
  int l = kpos / 1000; if (l > 4) l = 4;
  u64 key = keys[g];
  u32 idx = (u32)key;
  float o = funmap(~(u32)(key >> 32));
  int ai = c_LOFF[l] + (int)idx;
  const float* a = anchors + (size_t)ai * 4;
  const float* d = deltas + ((size_t)b * A_TOTAL + ai) * 4;
  float a0 = a[0], a1 = a[1], a2 = a[2], a3 = a[3];
  float wa = __fsub_rn(a2, a0), ha = __fsub_rn(a3, a1);
  float cxa = __fadd_rn(a0, __fmul_rn(0.5f, wa));
  float cya = __fadd_rn(a1, __fmul_rn(0.5f, ha));
  float dx = d[0], dy = d[1];
  float dw = fminf(d[2], 4.135166556742356f);   // log(1000/16)
  float dh = fminf(d[3], 4.135166556742356f);
  float cx = __fadd_rn(__fmul_rn(dx, wa), cxa);
  float cy = __fadd_rn(__fmul_rn(dy, ha), cya);
  float w  = __fmul_rn(expf(dw), wa);
  float h  = __fmul_rn(expf(dh), ha);
  float hw = __fmul_rn(0.5f, w), hh = __fmul_rn(0.5f, h);
  float x1 = __fsub_rn(cx, hw), y1 = __fsub_rn(cy, hh);
  float x2 = __fadd_rn(cx, hw), y2 = __fadd_rn(cy, hh);
  x1 = fminf(fmaxf(x1, 0.0f), 1216.0f);
  x2 = fminf(fmaxf(x2, 0.0f), 1216.0f);
  y1 = fminf(fmaxf(y1, 0.0f), 800.0f);
  y2 = fminf(fmaxf(y2, 0.0f), 800.0f);
  float s = __fdiv_rn(1.0f, __fadd_rn(1.0f, expf(-o)));
  int v = (__fsub_rn(x2, x1) >= 0.001f) && (__fsub_rn(y2, y1) >= 0.001f) && (s >= 0.0f);
  float* bo = boxes + (size_t)g * 4;
  bo[0] = x1; bo[1] = y1; bo[2] = x2; bo[3] = y2;
  scores[g] = s;
  valid[g] = (u32)v;
}

// ---------- K3: per-level suppression bitmask (word-major: mask[bl][w][row]) ----------
__global__ void __launch_bounds__(256)
k_mask(const float* __restrict__ boxes, u64* __restrict__ mask)
{
  int s = blockIdx.x % 19, b = blockIdx.x / 19;
  int l    = (s < 16) ? (s >> 2) : 4;
  int rblk = (s < 16) ? (s & 3) : (s - 16);
  int N = c_LK[l];
  int koff = l * 1000;
  float offv = (float)(l * 4096);   // exact
  __shared__ float sx1[1024], sy1[1024], sx2[1024], sy2[1024], sar[1024];
  for (int i = threadIdx.x; i < N; i += 256){
    const float* p = boxes + ((size_t)(b * KTOT + koff + i)) * 4;
    float bx1 = __fadd_rn(p[0], offv), by1 = __fadd_rn(p[1], offv);
    float bx2 = __fadd_rn(p[2], offv), by2 = __fadd_rn(p[3], offv);
    sx1[i] = bx1; sy1[i] = by1; sx2[i] = bx2; sy2[i] = by2;
    sar[i] = __fmul_rn(__fsub_rn(bx2, bx1), __fsub_rn(by2, by1));
  }
  __syncthreads();
  int i = rblk * 256 + threadIdx.x;
  if (i >= N) return;
  float bx1 = sx1[i], by1 = sy1[i], bx2 = sx2[i], by2 = sy2[i], bar = sar[i];
  u64* mb = mask + ((size_t)(b * 5 + l) * 16) * 1024;
  u64 bits = 0;
  #pragma unroll 1
  for (int j = 0; j < N; ++j){
    float ltx = fmaxf(bx1, sx1[j]), lty = fmaxf(by1, sy1[j]);
    float rbx = fminf(bx2, sx2[j]), rby = fminf(by2, sy2[j]);
    float wx = fmaxf(__fsub_rn(rbx, ltx), 0.0f);
    float wy = fmaxf(__fsub_rn(rby, lty), 0.0f);
    float inter = __fmul_rn(wx, wy);
    bool sup = false;
    if (inter > 0.0f && j > i){
      float den = __fsub_rn(__fadd_rn(bar, sar[j]), inter);
      sup = __fdiv_rn(inter, den) > 0.7f;
    }
    bits |= ((u64)sup) << (j & 63);
    if ((j & 63) == 63){ mb[(size_t)(j >> 6) * 1024 + i] = bits; bits = 0; }
  }
  if (N & 63) mb[(size_t)((N - 1) >> 6) * 1024 + i] = bits;
}

// ---------- K4: exact greedy NMS scan, one wave per (b,level) ----------
__global__ void __launch_bounds__(64)
k_nms(const u64* __restrict__ mask, const u32* __restrict__ valid,
      const float* __restrict__ scores, u64* __restrict__ outk)
{
  int bl = blockIdx.x; int b = bl / 5, l = bl % 5;
  int N = c_LK[l], koff = l * 1000;
  int WN = (N + 63) >> 6;
  int lane = threadIdx.x;
  __shared__ u64 kw[16];
  const u64* mb = mask + (size_t)bl * 16 * 1024;
  // init keep = valid
  for (int c = 0; c < WN; ++c){
    int i = c * 64 + lane;
    int pred = (i < N) && (valid[(size_t)b * KTOT + koff + i] != 0u);
    u64 bal = __ballot(pred);
    if (lane == 0) kw[c] = bal;
  }
  __syncthreads();
  for (int w = 0; w < WN; ++w){
    // suppression of word w from finalized kept rows in words < w
    u64 supl = 0;
    for (int jb = 0; jb < w; ++jb){
      u64 kb = kw[jb];
      if ((kb >> lane) & 1ULL) supl |= mb[(size_t)w * 1024 + jb * 64 + lane];
    }
    for (int off = 32; off; off >>= 1) supl |= __shfl_xor(supl, off);
    // in-word rows held per-lane in registers
    int jr = w * 64 + lane;
    u64 rowl = (jr < N) ? mb[(size_t)w * 1024 + jr] : 0ULL;
    u64 cur = kw[w] & ~supl;
    u64 kept = 0;
    while (cur){
      int ib = __ffsll((unsigned long long)cur) - 1;
      kept |= (1ULL << ib);
      u64 r = __shfl(rowl, ib);
      cur &= ~r;
      cur &= ~(1ULL << ib);
    }
    __syncthreads();
    if (lane == 0) kw[w] = kept;
    __syncthreads();
  }
  // emit final-merge keys: (~fmap(score))<<32 | concat_pos ; suppressed -> ~0
  for (int i = lane; i < N; i += 64){
    u64 key = ~0ULL;
    if ((kw[i >> 6] >> (i & 63)) & 1ULL){
      float sc = scores[(size_t)b * KTOT + koff + i];
      key = ((u64)(~fmap(sc)) << 32) | (u32)(koff + i);
    }
    outk[(size_t)b * KTOT + koff + i] = key;
  }
}

// ---------- K5: per-image final sort + output ----------
__global__ void __launch_bounds__(1024)
k_final(const u64* __restrict__ outk, const float* __restrict__ boxes,
        float* __restrict__ out)
{
  __shared__ u64 sh[8192];   // 64 KiB
  int b = blockIdx.x, tid = threadIdx.x;
  for (int i = tid; i < 8192; i += 1024)
    sh[i] = (i < KTOT) ? outk[(size_t)b * KTOT + i] : ~0ULL;
  bitonic_sort<8192, 1024>(sh, tid);
  for (int r = tid; r < 1000; r += 1024){
    u64 key = sh[r];
    float o0 = 0.f, o1 = 0.f, o2 = 0.f, o3 = 0.f, sc = 0.f;
    if (key != ~0ULL){
      int kpos = (int)(u32)key;
      const float* p = boxes + ((size_t)(b * KTOT + kpos)) * 4;
      o0 = p[0]; o1 = p[1]; o2 = p[2]; o3 = p[3];
      sc = funmap(~(u32)(key >> 32));
    }
    float* ob = out + ((size_t)(b * 1000 + r)) * 4;
    ob[0] = o0; ob[1] = o1; ob[2] = o2; ob[3] = o3;
    out[32000 + b * 1000 + r] = sc;
  }
}

extern "C" void kernel_launch(void* const* d_in, const int* in_sizes, int n_in,
                              void* d_out, int out_size, void* d_ws, size_t ws_size,
                              hipStream_t stream)
{
  (void)in_sizes; (void)n_in; (void)out_size; (void)ws_size; // needs ~8.73 MB ws
  const float* obj     = (const float*)d_in[0];
  const float* deltas  = (const float*)d_in[1];
  const float* anchors = (const float*)d_in[2];
  float* out = (float*)d_out;
  char* ws = (char*)d_ws;

  u32* hist    = (u32*)(ws + OFF_HIST);
  u32* selcnt  = (u32*)(ws + OFF_SELCNT);
  u32* candcnt = (u32*)(ws + OFF_CANDCNT);
  u32* tbin    = (u32*)(ws + OFF_TBIN);
  u32* cless   = (u32*)(ws + OFF_CLESS);
  u64* selg    = (u64*)(ws + OFF_SELG);
  u64* candg   = (u64*)(ws + OFF_CANDG);
  u64* keys    = (u64*)(ws + OFF_KEYS);
  float* boxes = (float*)(ws + OFF_BOX);
  float* score = (float*)(ws + OFF_SCORE);
  u32* valid   = (u32*)(ws + OFF_VALID);
  u64* mask    = (u64*)(ws + OFF_MASK);
  u64* outk    = (u64*)(ws + OFF_OUTK);

  hipMemsetAsync(ws, 0, MEMSET_BYTES, stream);
  hipLaunchKernelGGL(k_hist,    dim3(56),  dim3(1024), 0, stream, obj, hist);
  hipLaunchKernelGGL(k_cutoff,  dim3(40),  dim3(256),  0, stream, hist, tbin, cless);
  hipLaunchKernelGGL(k_collect, dim3(56),  dim3(1024), 0, stream, obj, tbin, selcnt, candcnt, selg, candg);
  hipLaunchKernelGGL(k_select,  dim3(40),  dim3(1024), 0, stream, selcnt, candcnt, selg, candg, keys);
  hipLaunchKernelGGL(k_decode,  dim3(149), dim3(256),  0, stream, keys, deltas, anchors, boxes, score, valid);
  hipLaunchKernelGGL(k_mask,    dim3(152), dim3(256),  0, stream, boxes, mask);
  hipLaunchKernelGGL(k_nms,     dim3(40),  dim3(64),   0, stream, mask, valid, score, outk);
  hipLaunchKernelGGL(k_final,   dim3(8),   dim3(1024), 0, stream, outk, boxes, out);
}

// Round 3
// 430.890 us; speedup vs baseline: 1.3167x; 1.3167x over previous
//
#include <hip/hip_runtime.h>
#include <stdint.h>

#pragma clang fp contract(off)

typedef unsigned int u32;
typedef unsigned long long u64;

#define A_TOTAL 242991
#define KTOT    4741

// level tables
__constant__ int c_LN[5]   = {182400, 45600, 11400, 2850, 741};
__constant__ int c_LOFF[5] = {0, 182400, 228000, 239400, 242250};
__constant__ int c_LK[5]   = {1000, 1000, 1000, 1000, 741};

// k_mask tile tables: 46 upper-triangle (it<=jt) tiles per image
// levels 0..3: 4x4 tiles -> 10 pairs each; level 4: 3x3 -> 6 pairs
__constant__ int c_TL[46] = {0,0,0,0,0,0,0,0,0,0, 1,1,1,1,1,1,1,1,1,1,
                             2,2,2,2,2,2,2,2,2,2, 3,3,3,3,3,3,3,3,3,3,
                             4,4,4,4,4,4};
__constant__ int c_TI[46] = {0,0,0,0,1,1,1,2,2,3, 0,0,0,0,1,1,1,2,2,3,
                             0,0,0,0,1,1,1,2,2,3, 0,0,0,0,1,1,1,2,2,3,
                             0,0,0,1,1,2};
__constant__ int c_TJ[46] = {0,1,2,3,1,2,3,2,3,3, 0,1,2,3,1,2,3,2,3,3,
                             0,1,2,3,1,2,3,2,3,3, 0,1,2,3,1,2,3,2,3,3,
                             0,1,2,1,2,2};

// workspace byte offsets (total ~8.73 MB)
static const size_t OFF_HIST     = 0;        // 40*2048*4 = 327680
static const size_t OFF_SELCNT   = 327680;   // 40*4
static const size_t OFF_CANDCNT  = 327840;   // 40*4
static const size_t MEMSET_BYTES = 328000;
static const size_t OFF_TBIN     = 328000;   // 40*4
static const size_t OFF_CLESS    = 328160;   // 40*4
static const size_t OFF_SELG     = 328320;   // 40*1024*8  -> 656000
static const size_t OFF_CANDG    = 656000;   // 40*4096*8  -> 1966720
static const size_t OFF_KEYS     = 1966720;  // 8*4741*8   -> 2270144
static const size_t OFF_BOX      = 2270144;  // 8*4741*4*4 -> 2876992
static const size_t OFF_SCORE    = 2876992;  // 8*4741*4   -> 3028704
static const size_t OFF_VALID    = 3028704;  // 8*4741*4   -> 3180416
static const size_t OFF_MASK     = 3180416;  // 8*5*16*1024*8 -> 8423296
static const size_t OFF_OUTK     = 8423296;  // 8*4741*8   -> 8726720

// monotone float<->uint map: fmap ascending in float value
__device__ __forceinline__ u32 fmap(float f){
  u32 b = __float_as_uint(f);
  return (b & 0x80000000u) ? ~b : (b | 0x80000000u);
}
__device__ __forceinline__ float funmap(u32 m){
  return __uint_as_float((m & 0x80000000u) ? (m & 0x7FFFFFFFu) : ~m);
}

template<int N, int T>
__device__ __forceinline__ void bitonic_sort(u64* d, int tid){
  for (int k = 2; k <= N; k <<= 1){
    for (int j = k >> 1; j > 0; j >>= 1){
      __syncthreads();
      #pragma unroll 1
      for (int i = tid; i < N; i += T){
        int ixj = i ^ j;
        if (ixj > i){
          u64 a = d[i], b = d[ixj];
          bool sw = ((i & k) == 0) ? (a > b) : (a < b);
          if (sw){ d[i] = b; d[ixj] = a; }
        }
      }
    }
  }
  __syncthreads();
}

// block -> (b, level, segment) mapping for 16K-element scan segments:
// 18 blocks/image (12 for l0, 3 for l1, 1 each l2..l4)
__device__ __forceinline__ void seg_map(int blk, int& b, int& l, int& start, int& cnt){
  b = blk / 18; int s = blk % 18;
  if (s < 12)      { l = 0; start = s * 16384; }
  else if (s < 15) { l = 1; start = (s - 12) * 16384; }
  else             { l = s - 13; start = 0; }   // 15->l2, 16->l3, 17->l4
  int n = c_LN[l];
  cnt = n - start; if (cnt > 16384) cnt = 16384;
}

// ---------- K1a: per-(b,l) 2048-bin histogram of key-high-11-bits ----------
__global__ void __launch_bounds__(1024)
k_hist(const float* __restrict__ obj, u32* __restrict__ hist)
{
  int b, l, start, cnt; seg_map(blockIdx.x, b, l, start, cnt);
  int bl = b * 5 + l;
  __shared__ u32 h[2048];
  for (int i = threadIdx.x; i < 2048; i += 1024) h[i] = 0;
  __syncthreads();
  const float* p = obj + (size_t)b * A_TOTAL + c_LOFF[l] + start;
  for (int i = threadIdx.x; i < cnt; i += 1024){
    u32 m = ~fmap(p[i]);           // ascending m == descending objectness
    atomicAdd(&h[m >> 21], 1u);
  }
  __syncthreads();
  for (int i = threadIdx.x; i < 2048; i += 1024){
    u32 v = h[i];
    if (v) atomicAdd(&hist[bl * 2048 + i], v);
  }
}

// ---------- K1b: find cutoff bin t and count_less ----------
__global__ void __launch_bounds__(256)
k_cutoff(const u32* __restrict__ hist, u32* __restrict__ tbin, u32* __restrict__ cless)
{
  int bl = blockIdx.x; int l = bl % 5;
  int K = c_LK[l], n = c_LN[l];
  int tid = threadIdx.x;
  if (K >= n){ if (tid == 0){ tbin[bl] = 2048u; cless[bl] = (u32)n; } return; }
  __shared__ u32 cum[2048];
  __shared__ u32 part[256];
  __shared__ int s_t;
  u32 vals[8]; u32 sum = 0;
  for (int q = 0; q < 8; ++q){ vals[q] = hist[bl * 2048 + tid * 8 + q]; sum += vals[q]; }
  part[tid] = sum;
  __syncthreads();
  for (int off = 1; off < 256; off <<= 1){
    u32 add = (tid >= off) ? part[tid - off] : 0u;
    __syncthreads();
    part[tid] += add;
    __syncthreads();
  }
  u32 run = (tid > 0) ? part[tid - 1] : 0u;
  for (int q = 0; q < 8; ++q){ run += vals[q]; cum[tid * 8 + q] = run; }
  if (tid == 0) s_t = 0;
  __syncthreads();
  for (int q = 0; q < 8; ++q){
    int i = tid * 8 + q;
    u32 c = cum[i], cp = (i > 0) ? cum[i - 1] : 0u;
    if (c >= (u32)K && cp < (u32)K) s_t = i;
  }
  __syncthreads();
  if (tid == 0){
    int t = s_t;
    tbin[bl] = (u32)t;
    cless[bl] = (t > 0) ? cum[t - 1] : 0u;
  }
}

// ---------- K1c: collect selected + boundary-bin candidates ----------
__global__ void __launch_bounds__(1024)
k_collect(const float* __restrict__ obj, const u32* __restrict__ tbin,
          u32* __restrict__ selcnt, u32* __restrict__ candcnt,
          u64* __restrict__ selg, u64* __restrict__ candg)
{
  int b, l, start, cnt; seg_map(blockIdx.x, b, l, start, cnt);
  int bl = b * 5 + l;
  u32 t = tbin[bl];
  const float* p = obj + (size_t)b * A_TOTAL + c_LOFF[l] + start;
  for (int i = threadIdx.x; i < cnt; i += 1024){
    u32 m = ~fmap(p[i]);
    u32 bin = m >> 21;
    u64 key = ((u64)m << 32) | (u32)(start + i);
    if (bin < t){
      u32 pos = atomicAdd(&selcnt[bl], 1u);
      selg[(size_t)bl * 1024 + pos] = key;
    } else if (bin == t){
      u32 pos = atomicAdd(&candcnt[bl], 1u);
      if (pos < 4096u) candg[(size_t)bl * 4096 + pos] = key;
    }
  }
}

// ---------- K1d: assemble exact top-K and sort descending-by-obj ----------
__global__ void __launch_bounds__(1024)
k_select(const u32* __restrict__ selcnt, const u32* __restrict__ candcnt,
         const u64* __restrict__ selg, const u64* __restrict__ candg,
         u64* __restrict__ keys)
{
  int bl = blockIdx.x; int b = bl / 5, l = bl % 5;
  int K = c_LK[l];
  int tid = threadIdx.x;
  __shared__ u64 cand[4096];
  __shared__ u64 sel[1024];
  u32 nc = candcnt[bl]; if (nc > 4096u) nc = 4096u;
  u32 ns = selcnt[bl];
  int R = K - (int)ns;
  for (int i = tid; i < 4096; i += 1024) cand[i] = (i < (int)nc) ? candg[(size_t)bl * 4096 + i] : ~0ULL;
  sel[tid] = ~0ULL;
  __syncthreads();
  if (R > 0){
    bitonic_sort<4096, 1024>(cand, tid);
  }
  for (int i = tid; i < (int)ns; i += 1024) sel[i] = selg[(size_t)bl * 1024 + i];
  for (int i = tid; i < R; i += 1024) sel[(int)ns + i] = cand[i];
  bitonic_sort<1024, 1024>(sel, tid);
  for (int i = tid; i < K; i += 1024) keys[(size_t)b * KTOT + l * 1000 + i] = sel[i];
}

// ---------- K2: gather + decode + clip + sigmoid + validity ----------
__global__ void __launch_bounds__(256)
k_decode(const u64* __restrict__ keys, const float* __restrict__ deltas,
         const float* __restrict__ anchors, float* __restrict__ boxes,
         float* __restrict__ scores, u32* __restrict__ valid)
{
  int g = blockIdx.x * 256 + threadIdx.x;
  if (g >= 8 * KTOT) return;
  int b = g / KTOT, kpos = g % KTOT;
  int l = kpos / 1000; if (l > 4) l = 4;
  u64 key = keys[g];
  u32 idx = (u32)key;
  float o = funmap(~(u32)(key >> 32));
  int ai = c_LOFF[l] + (int)idx;
  const float* a = anchors + (size_t)ai * 4;
  const float* d = deltas + ((size_t)b * A_TOTAL + ai) * 4;
  float a0 = a[0], a1 = a[1], a2 = a[2], a3 = a[3];
  float wa = __fsub_rn(a2, a0), ha = __fsub_rn(a3, a1);
  float cxa = __fadd_rn(a0, __fmul_rn(0.5f, wa));
  float cya = __fadd_rn(a1, __fmul_rn(0.5f, ha));
  float dx = d[0], dy = d[1];
  float dw = fminf(d[2], 4.135166556742356f);   // log(1000/16)
  float dh = fminf(d[3], 4.135166556742356f);
  float cx = __fadd_rn(__fmul_rn(dx, wa), cxa);
  float cy = __fadd_rn(__fmul_rn(dy, ha), cya);
  float w  = __fmul_rn(expf(dw), wa);
  float h  = __fmul_rn(expf(dh), ha);
  float hw = __fmul_rn(0.5f, w), hh = __fmul_rn(0.5f, h);
  float x1 = __fsub_rn(cx, hw), y1 = __fsub_rn(cy, hh);
  float x2 = __fadd_rn(cx, hw), y2 = __fadd_rn(cy, hh);
  x1 = fminf(fmaxf(x1, 0.0f), 1216.0f);
  x2 = fminf(fmaxf(x2, 0.0f), 1216.0f);
  y1 = fminf(fmaxf(y1, 0.0f), 800.0f);
  y2 = fminf(fmaxf(y2, 0.0f), 800.0f);
  float s = __fdiv_rn(1.0f, __fadd_rn(1.0f, expf(-o)));
  int v = (__fsub_rn(x2, x1) >= 0.001f) && (__fsub_rn(y2, y1) >= 0.001f) && (s >= 0.0f);
  float* bo = boxes + (size_t)g * 4;
  bo[0] = x1; bo[1] = y1; bo[2] = x2; bo[3] = y2;
  scores[g] = s;
  valid[g] = (u32)v;
}

// ---------- K3: per-level suppression bitmask, 256x256 upper-tri tiles ----------
// mask layout unchanged: mask[bl][w][row], w = column word (64 cols), row padded to 1024.
// Tile (it,jt) with it<=jt covers every (row,word) pair k_nms reads:
// reads of word w touch rows <= w*64+63, and w's tile jt = w/4 satisfies
// w*64+63 <= jt*256+255, so row-tile <= jt always.
__global__ void __launch_bounds__(256)
k_mask(const float* __restrict__ boxes, u64* __restrict__ mask)
{
  int b = blockIdx.x / 46, s = blockIdx.x % 46;
  int l = c_TL[s], it = c_TI[s], jt = c_TJ[s];
  int N = c_LK[l];
  int koff = l * 1000;
  float offv = (float)(l * 4096);   // exact
  __shared__ float4 sxy[256];
  __shared__ float  sar[256];
  int j0 = jt * 256;
  {
    int tj = j0 + (int)threadIdx.x;
    float4 q; float ar;
    if (tj < N){
      float4 p = ((const float4*)boxes)[(size_t)(b * KTOT + koff + tj)];
      q.x = __fadd_rn(p.x, offv); q.y = __fadd_rn(p.y, offv);
      q.z = __fadd_rn(p.z, offv); q.w = __fadd_rn(p.w, offv);
      ar = __fmul_rn(__fsub_rn(q.z, q.x), __fsub_rn(q.w, q.y));
    } else {
      // sentinel: empty box far away -> inter = 0 -> never suppresses
      q.x = 3e38f; q.y = 3e38f; q.z = -3e38f; q.w = -3e38f; ar = 0.f;
    }
    sxy[threadIdx.x] = q; sar[threadIdx.x] = ar;
  }
  __syncthreads();
  int i = it * 256 + (int)threadIdx.x;
  if (i >= N) return;
  float4 p = ((const float4*)boxes)[(size_t)(b * KTOT + koff + i)];
  float bx1 = __fadd_rn(p.x, offv), by1 = __fadd_rn(p.y, offv);
  float bx2 = __fadd_rn(p.z, offv), by2 = __fadd_rn(p.w, offv);
  float bar = __fmul_rn(__fsub_rn(bx2, bx1), __fsub_rn(by2, by1));
  u64* mb = mask + ((size_t)(b * 5 + l) * 16) * 1024;
  for (int w = 0; w < 4; ++w){
    int jbase = j0 + w * 64;
    if (jbase >= N) break;
    u64 bw = 0;
    #pragma unroll 16
    for (int jj = 0; jj < 64; ++jj){
      int j = jbase + jj;
      float4 q = sxy[w * 64 + jj];
      float aj = sar[w * 64 + jj];
      float ltx = fmaxf(bx1, q.x), lty = fmaxf(by1, q.y);
      float rbx = fminf(bx2, q.z), rby = fminf(by2, q.w);
      float wx = fmaxf(__fsub_rn(rbx, ltx), 0.0f);
      float wy = fmaxf(__fsub_rn(rby, lty), 0.0f);
      float inter = __fmul_rn(wx, wy);
      bool sup = false;
      if (inter > 0.0f && j > i){
        float den = __fsub_rn(__fadd_rn(bar, aj), inter);
        sup = __fdiv_rn(inter, den) > 0.7f;
      }
      bw |= ((u64)sup) << jj;
    }
    mb[(size_t)(jbase >> 6) * 1024 + i] = bw;
  }
}

// ---------- K4: exact greedy NMS scan, one wave per (b,level) ----------
__global__ void __launch_bounds__(64)
k_nms(const u64* __restrict__ mask, const u32* __restrict__ valid,
      const float* __restrict__ scores, u64* __restrict__ outk)
{
  int bl = blockIdx.x; int b = bl / 5, l = bl % 5;
  int N = c_LK[l], koff = l * 1000;
  int WN = (N + 63) >> 6;
  int lane = threadIdx.x;
  __shared__ u64 kw[16];
  const u64* mb = mask + (size_t)bl * 16 * 1024;
  // init keep = valid
  for (int c = 0; c < WN; ++c){
    int i = c * 64 + lane;
    int pred = (i < N) && (valid[(size_t)b * KTOT + koff + i] != 0u);
    u64 bal = __ballot(pred);
    if (lane == 0) kw[c] = bal;
  }
  __syncthreads();
  for (int w = 0; w < WN; ++w){
    // suppression of word w from finalized kept rows in words < w
    u64 supl = 0;
    for (int jb = 0; jb < w; ++jb){
      u64 kb = kw[jb];
      if ((kb >> lane) & 1ULL) supl |= mb[(size_t)w * 1024 + jb * 64 + lane];
    }
    for (int off = 32; off; off >>= 1) supl |= __shfl_xor(supl, off);
    // in-word rows held per-lane in registers
    int jr = w * 64 + lane;
    u64 rowl = (jr < N) ? mb[(size_t)w * 1024 + jr] : 0ULL;
    u64 cur = kw[w] & ~supl;
    u64 kept = 0;
    while (cur){
      int ib = __ffsll((unsigned long long)cur) - 1;
      kept |= (1ULL << ib);
      u64 r = __shfl(rowl, ib);
      cur &= ~r;
      cur &= ~(1ULL << ib);
    }
    __syncthreads();
    if (lane == 0) kw[w] = kept;
    __syncthreads();
  }
  // emit final-merge keys: (~fmap(score))<<32 | concat_pos ; suppressed -> ~0
  for (int i = lane; i < N; i += 64){
    u64 key = ~0ULL;
    if ((kw[i >> 6] >> (i & 63)) & 1ULL){
      float sc = scores[(size_t)b * KTOT + koff + i];
      key = ((u64)(~fmap(sc)) << 32) | (u32)(koff + i);
    }
    outk[(size_t)b * KTOT + koff + i] = key;
  }
}

// ---------- K5: per-image final sort + output ----------
__global__ void __launch_bounds__(1024)
k_final(const u64* __restrict__ outk, const float* __restrict__ boxes,
        float* __restrict__ out)
{
  __shared__ u64 sh[8192];   // 64 KiB
  int b = blockIdx.x, tid = threadIdx.x;
  for (int i = tid; i < 8192; i += 1024)
    sh[i] = (i < KTOT) ? outk[(size_t)b * KTOT + i] : ~0ULL;
  bitonic_sort<8192, 1024>(sh, tid);
  for (int r = tid; r < 1000; r += 1024){
    u64 key = sh[r];
    float o0 = 0.f, o1 = 0.f, o2 = 0.f, o3 = 0.f, sc = 0.f;
    if (key != ~0ULL){
      int kpos = (int)(u32)key;
      const float* p = boxes + ((size_t)(b * KTOT + kpos)) * 4;
      o0 = p[0]; o1 = p[1]; o2 = p[2]; o3 = p[3];
      sc = funmap(~(u32)(key >> 32));
    }
    float* ob = out + ((size_t)(b * 1000 + r)) * 4;
    ob[0] = o0; ob[1] = o1; ob[2] = o2; ob[3] = o3;
    out[32000 + b * 1000 + r] = sc;
  }
}

extern "C" void kernel_launch(void* const* d_in, const int* in_sizes, int n_in,
                              void* d_out, int out_size, void* d_ws, size_t ws_size,
                              hipStream_t stream)
{
  (void)in_sizes; (void)n_in; (void)out_size; (void)ws_size; // needs ~8.73 MB ws
  const float* obj     = (const float*)d_in[0];
  const float* deltas  = (const float*)d_in[1];
  const float* anchors = (const float*)d_in[2];
  float* out = (float*)d_out;
  char* ws = (char*)d_ws;

  u32* hist    = (u32*)(ws + OFF_HIST);
  u32* selcnt  = (u32*)(ws + OFF_SELCNT);
  u32* candcnt = (u32*)(ws + OFF_CANDCNT);
  u32* tbin    = (u32*)(ws + OFF_TBIN);
  u32* cless   = (u32*)(ws + OFF_CLESS);
  u64* selg    = (u64*)(ws + OFF_SELG);
  u64* candg   = (u64*)(ws + OFF_CANDG);
  u64* keys    = (u64*)(ws + OFF_KEYS);
  float* boxes = (float*)(ws + OFF_BOX);
  float* score = (float*)(ws + OFF_SCORE);
  u32* valid   = (u32*)(ws + OFF_VALID);
  u64* mask    = (u64*)(ws + OFF_MASK);
  u64* outk    = (u64*)(ws + OFF_OUTK);

  hipMemsetAsync(ws, 0, MEMSET_BYTES, stream);
  hipLaunchKernelGGL(k_hist,    dim3(144), dim3(1024), 0, stream, obj, hist);
  hipLaunchKernelGGL(k_cutoff,  dim3(40),  dim3(256),  0, stream, hist, tbin, cless);
  hipLaunchKernelGGL(k_collect, dim3(144), dim3(1024), 0, stream, obj, tbin, selcnt, candcnt, selg, candg);
  hipLaunchKernelGGL(k_select,  dim3(40),  dim3(1024), 0, stream, selcnt, candcnt, selg, candg, keys);
  hipLaunchKernelGGL(k_decode,  dim3(149), dim3(256),  0, stream, keys, deltas, anchors, boxes, score, valid);
  hipLaunchKernelGGL(k_mask,    dim3(368), dim3(256),  0, stream, boxes, mask);
  hipLaunchKernelGGL(k_nms,     dim3(40),  dim3(64),   0, stream, mask, valid, score, outk);
  hipLaunchKernelGGL(k_final,   dim3(8),   dim3(1024), 0, stream, outk, boxes, out);
}

// Round 5
// 407.137 us; speedup vs baseline: 1.3935x; 1.0583x over previous
//
#include <hip/hip_runtime.h>
#include <stdint.h>

#pragma clang fp contract(off)

typedef unsigned int u32;
typedef unsigned long long u64;

#define A_TOTAL 242991
#define KTOT    4741

// level tables
__constant__ int c_LN[5]   = {182400, 45600, 11400, 2850, 741};
__constant__ int c_LOFF[5] = {0, 182400, 228000, 239400, 242250};
__constant__ int c_LK[5]   = {1000, 1000, 1000, 1000, 741};

// k_mask tile tables: 46 upper-triangle (it<=jt) tiles per image
__constant__ int c_TL[46] = {0,0,0,0,0,0,0,0,0,0, 1,1,1,1,1,1,1,1,1,1,
                             2,2,2,2,2,2,2,2,2,2, 3,3,3,3,3,3,3,3,3,3,
                             4,4,4,4,4,4};
__constant__ int c_TI[46] = {0,0,0,0,1,1,1,2,2,3, 0,0,0,0,1,1,1,2,2,3,
                             0,0,0,0,1,1,1,2,2,3, 0,0,0,0,1,1,1,2,2,3,
                             0,0,0,1,1,2};
__constant__ int c_TJ[46] = {0,1,2,3,1,2,3,2,3,3, 0,1,2,3,1,2,3,2,3,3,
                             0,1,2,3,1,2,3,2,3,3, 0,1,2,3,1,2,3,2,3,3,
                             0,1,2,1,2,2};

// workspace byte offsets (total ~8.73 MB)
static const size_t OFF_HIST     = 0;        // 40*2048*4 = 327680
static const size_t OFF_SELCNT   = 327680;   // 40*4
static const size_t OFF_CANDCNT  = 327840;   // 40*4
static const size_t MEMSET_BYTES = 328000;
static const size_t OFF_TBIN     = 328000;   // 40*4
static const size_t OFF_CLESS    = 328160;   // 40*4
static const size_t OFF_SELG     = 328320;   // 40*1024*8  -> 656000
static const size_t OFF_CANDG    = 656000;   // 40*4096*8  -> 1966720
static const size_t OFF_KEYS     = 1966720;  // 8*4741*8   -> 2270144
static const size_t OFF_BOX      = 2270144;  // 8*4741*4*4 -> 2876992
static const size_t OFF_SCORE    = 2876992;  // 8*4741*4   -> 3028704
static const size_t OFF_VALID    = 3028704;  // 8*4741*4   -> 3180416
static const size_t OFF_MASK     = 3180416;  // 8*5*16*1024*8 -> 8423296
static const size_t OFF_OUTK     = 8423296;  // 8*4741*8   -> 8726720

// monotone float<->uint map: fmap ascending in float value
__device__ __forceinline__ u32 fmap(float f){
  u32 b = __float_as_uint(f);
  return (b & 0x80000000u) ? ~b : (b | 0x80000000u);
}
__device__ __forceinline__ float funmap(u32 m){
  return __uint_as_float((m & 0x80000000u) ? (m & 0x7FFFFFFFu) : ~m);
}

template<int N, int T>
__device__ __forceinline__ void bitonic_sort(u64* d, int tid){
  for (int k = 2; k <= N; k <<= 1){
    for (int j = k >> 1; j > 0; j >>= 1){
      __syncthreads();
      #pragma unroll 1
      for (int i = tid; i < N; i += T){
        int ixj = i ^ j;
        if (ixj > i){
          u64 a = d[i], b = d[ixj];
          bool sw = ((i & k) == 0) ? (a > b) : (a < b);
          if (sw){ d[i] = b; d[ixj] = a; }
        }
      }
    }
  }
  __syncthreads();
}

// block -> (b, level, segment) mapping for 16K-element scan segments:
// 18 blocks/image (12 for l0, 3 for l1, 1 each l2..l4)
__device__ __forceinline__ void seg_map(int blk, int& b, int& l, int& start, int& cnt){
  b = blk / 18; int s = blk % 18;
  if (s < 12)      { l = 0; start = s * 16384; }
  else if (s < 15) { l = 1; start = (s - 12) * 16384; }
  else             { l = s - 13; start = 0; }   // 15->l2, 16->l3, 17->l4
  int n = c_LN[l];
  cnt = n - start; if (cnt > 16384) cnt = 16384;
}

// ---------- K1a: per-(b,l) 2048-bin histogram of key-high-11-bits ----------
__global__ void __launch_bounds__(1024)
k_hist(const float* __restrict__ obj, u32* __restrict__ hist)
{
  int b, l, start, cnt; seg_map(blockIdx.x, b, l, start, cnt);
  int bl = b * 5 + l;
  __shared__ u32 h[2048];
  for (int i = threadIdx.x; i < 2048; i += 1024) h[i] = 0;
  __syncthreads();
  const float* p = obj + (size_t)b * A_TOTAL + c_LOFF[l] + start;
  for (int i = threadIdx.x; i < cnt; i += 1024){
    u32 m = ~fmap(p[i]);           // ascending m == descending objectness
    atomicAdd(&h[m >> 21], 1u);
  }
  __syncthreads();
  for (int i = threadIdx.x; i < 2048; i += 1024){
    u32 v = h[i];
    if (v) atomicAdd(&hist[bl * 2048 + i], v);
  }
}

// ---------- K1b: find cutoff bin t and count_less ----------
__global__ void __launch_bounds__(256)
k_cutoff(const u32* __restrict__ hist, u32* __restrict__ tbin, u32* __restrict__ cless)
{
  int bl = blockIdx.x; int l = bl % 5;
  int K = c_LK[l], n = c_LN[l];
  int tid = threadIdx.x;
  if (K >= n){ if (tid == 0){ tbin[bl] = 2048u; cless[bl] = (u32)n; } return; }
  __shared__ u32 cum[2048];
  __shared__ u32 part[256];
  __shared__ int s_t;
  u32 vals[8]; u32 sum = 0;
  for (int q = 0; q < 8; ++q){ vals[q] = hist[bl * 2048 + tid * 8 + q]; sum += vals[q]; }
  part[tid] = sum;
  __syncthreads();
  for (int off = 1; off < 256; off <<= 1){
    u32 add = (tid >= off) ? part[tid - off] : 0u;
    __syncthreads();
    part[tid] += add;
    __syncthreads();
  }
  u32 run = (tid > 0) ? part[tid - 1] : 0u;
  for (int q = 0; q < 8; ++q){ run += vals[q]; cum[tid * 8 + q] = run; }
  if (tid == 0) s_t = 0;
  __syncthreads();
  for (int q = 0; q < 8; ++q){
    int i = tid * 8 + q;
    u32 c = cum[i], cp = (i > 0) ? cum[i - 1] : 0u;
    if (c >= (u32)K && cp < (u32)K) s_t = i;
  }
  __syncthreads();
  if (tid == 0){
    int t = s_t;
    tbin[bl] = (u32)t;
    cless[bl] = (t > 0) ? cum[t - 1] : 0u;
  }
}

// ---------- K1c: collect selected + boundary-bin candidates ----------
__global__ void __launch_bounds__(1024)
k_collect(const float* __restrict__ obj, const u32* __restrict__ tbin,
          u32* __restrict__ selcnt, u32* __restrict__ candcnt,
          u64* __restrict__ selg, u64* __restrict__ candg)
{
  int b, l, start, cnt; seg_map(blockIdx.x, b, l, start, cnt);
  int bl = b * 5 + l;
  u32 t = tbin[bl];
  const float* p = obj + (size_t)b * A_TOTAL + c_LOFF[l] + start;
  for (int i = threadIdx.x; i < cnt; i += 1024){
    u32 m = ~fmap(p[i]);
    u32 bin = m >> 21;
    u64 key = ((u64)m << 32) | (u32)(start + i);
    if (bin < t){
      u32 pos = atomicAdd(&selcnt[bl], 1u);
      selg[(size_t)bl * 1024 + pos] = key;
    } else if (bin == t){
      u32 pos = atomicAdd(&candcnt[bl], 1u);
      if (pos < 4096u) candg[(size_t)bl * 4096 + pos] = key;
    }
  }
}

// ---------- K1d: assemble exact top-K and sort descending-by-obj ----------
__global__ void __launch_bounds__(1024)
k_select(const u32* __restrict__ selcnt, const u32* __restrict__ candcnt,
         const u64* __restrict__ selg, const u64* __restrict__ candg,
         u64* __restrict__ keys)
{
  int bl = blockIdx.x; int b = bl / 5, l = bl % 5;
  int K = c_LK[l];
  int tid = threadIdx.x;
  __shared__ u64 cand[4096];
  __shared__ u64 sel[1024];
  u32 nc = candcnt[bl]; if (nc > 4096u) nc = 4096u;
  u32 ns = selcnt[bl];
  int R = K - (int)ns;
  for (int i = tid; i < 4096; i += 1024) cand[i] = (i < (int)nc) ? candg[(size_t)bl * 4096 + i] : ~0ULL;
  sel[tid] = ~0ULL;
  __syncthreads();
  if (R > 0){
    bitonic_sort<4096, 1024>(cand, tid);
  }
  for (int i = tid; i < (int)ns; i += 1024) sel[i] = selg[(size_t)bl * 1024 + i];
  for (int i = tid; i < R; i += 1024) sel[(int)ns + i] = cand[i];
  bitonic_sort<1024, 1024>(sel, tid);
  for (int i = tid; i < K; i += 1024) keys[(size_t)b * KTOT + l * 1000 + i] = sel[i];
}

// ---------- K2: gather + decode + clip + sigmoid + validity ----------
__global__ void __launch_bounds__(256)
k_decode(const u64* __restrict__ keys, const float* __restrict__ deltas,
         const float* __restrict__ anchors, float* __restrict__ boxes,
         float* __restrict__ scores, u32* __restrict__ valid)
{
  int g = blockIdx.x * 256 + threadIdx.x;
  if (g >= 8 * KTOT) return;
  int b = g / KTOT, kpos = g % KTOT;
  int l = kpos / 1000; if (l > 4) l = 4;
  u64 key = keys[g];
  u32 idx = (u32)key;
  float o = funmap(~(u32)(key >> 32));
  int ai = c_LOFF[l] + (int)idx;
  const float* a = anchors + (size_t)ai * 4;
  const float* d = deltas + ((size_t)b * A_TOTAL + ai) * 4;
  float a0 = a[0], a1 = a[1], a2 = a[2], a3 = a[3];
  float wa = __fsub_rn(a2, a0), ha = __fsub_rn(a3, a1);
  float cxa = __fadd_rn(a0, __fmul_rn(0.5f, wa));
  float cya = __fadd_rn(a1, __fmul_rn(0.5f, ha));
  float dx = d[0], dy = d[1];
  float dw = fminf(d[2], 4.135166556742356f);   // log(1000/16)
  float dh = fminf(d[3], 4.135166556742356f);
  float cx = __fadd_rn(__fmul_rn(dx, wa), cxa);
  float cy = __fadd_rn(__fmul_rn(dy, ha), cya);
  float w  = __fmul_rn(expf(dw), wa);
  float h  = __fmul_rn(expf(dh), ha);
  float hw = __fmul_rn(0.5f, w), hh = __fmul_rn(0.5f, h);
  float x1 = __fsub_rn(cx, hw), y1 = __fsub_rn(cy, hh);
  float x2 = __fadd_rn(cx, hw), y2 = __fadd_rn(cy, hh);
  x1 = fminf(fmaxf(x1, 0.0f), 1216.0f);
  x2 = fminf(fmaxf(x2, 0.0f), 1216.0f);
  y1 = fminf(fmaxf(y1, 0.0f), 800.0f);
  y2 = fminf(fmaxf(y2, 0.0f), 800.0f);
  float s = __fdiv_rn(1.0f, __fadd_rn(1.0f, expf(-o)));
  int v = (__fsub_rn(x2, x1) >= 0.001f) && (__fsub_rn(y2, y1) >= 0.001f) && (s >= 0.0f);
  float* bo = boxes + (size_t)g * 4;
  bo[0] = x1; bo[1] = y1; bo[2] = x2; bo[3] = y2;
  scores[g] = s;
  valid[g] = (u32)v;
}

// ---------- K3: per-level suppression bitmask, 256x256 upper-tri tiles ----------
__global__ void __launch_bounds__(256)
k_mask(const float* __restrict__ boxes, u64* __restrict__ mask)
{
  int b = blockIdx.x / 46, s = blockIdx.x % 46;
  int l = c_TL[s], it = c_TI[s], jt = c_TJ[s];
  int N = c_LK[l];
  int koff = l * 1000;
  float offv = (float)(l * 4096);   // exact
  __shared__ float4 sxy[256];
  __shared__ float  sar[256];
  int j0 = jt * 256;
  {
    int tj = j0 + (int)threadIdx.x;
    float4 q; float ar;
    if (tj < N){
      float4 p = ((const float4*)boxes)[(size_t)(b * KTOT + koff + tj)];
      q.x = __fadd_rn(p.x, offv); q.y = __fadd_rn(p.y, offv);
      q.z = __fadd_rn(p.z, offv); q.w = __fadd_rn(p.w, offv);
      ar = __fmul_rn(__fsub_rn(q.z, q.x), __fsub_rn(q.w, q.y));
    } else {
      q.x = 3e38f; q.y = 3e38f; q.z = -3e38f; q.w = -3e38f; ar = 0.f;
    }
    sxy[threadIdx.x] = q; sar[threadIdx.x] = ar;
  }
  __syncthreads();
  int i = it * 256 + (int)threadIdx.x;
  if (i >= N) return;
  float4 p = ((const float4*)boxes)[(size_t)(b * KTOT + koff + i)];
  float bx1 = __fadd_rn(p.x, offv), by1 = __fadd_rn(p.y, offv);
  float bx2 = __fadd_rn(p.z, offv), by2 = __fadd_rn(p.w, offv);
  float bar = __fmul_rn(__fsub_rn(bx2, bx1), __fsub_rn(by2, by1));
  u64* mb = mask + ((size_t)(b * 5 + l) * 16) * 1024;
  for (int w = 0; w < 4; ++w){
    int jbase = j0 + w * 64;
    if (jbase >= N) break;
    u64 bw = 0;
    #pragma unroll 16
    for (int jj = 0; jj < 64; ++jj){
      int j = jbase + jj;
      float4 q = sxy[w * 64 + jj];
      float aj = sar[w * 64 + jj];
      float ltx = fmaxf(bx1, q.x), lty = fmaxf(by1, q.y);
      float rbx = fminf(bx2, q.z), rby = fminf(by2, q.w);
      float wx = fmaxf(__fsub_rn(rbx, ltx), 0.0f);
      float wy = fmaxf(__fsub_rn(rby, lty), 0.0f);
      float inter = __fmul_rn(wx, wy);
      bool sup = false;
      if (inter > 0.0f && j > i){
        float den = __fsub_rn(__fadd_rn(bar, aj), inter);
        sup = __fdiv_rn(inter, den) > 0.7f;
      }
      bw |= ((u64)sup) << jj;
    }
    mb[(size_t)(jbase >> 6) * 1024 + i] = bw;
  }
}

// ---------- K4: exact greedy NMS scan, LDS-staged, 256 threads/block ----------
// Word w consumes mask rows < (w+1)*64. Words 0..14 (7680 u64 = 60 KiB) are
// staged to LDS by all 4 waves with pipelined coalesced loads; word 15 reads
// global UNCONDITIONALLY (cndmask-selected) so its 15 loads issue in parallel.
// The greedy scan itself runs in wave 0 (wave-lockstep => no barriers needed).
__global__ void __launch_bounds__(256)
k_nms(const u64* __restrict__ mask, const u32* __restrict__ valid,
      const float* __restrict__ scores, u64* __restrict__ outk)
{
  int bl = blockIdx.x; int b = bl / 5, l = bl % 5;
  int N = c_LK[l], koff = l * 1000;
  int WN = (N + 63) >> 6;           // 16 (levels 0-3) or 12 (level 4)
  int tid = threadIdx.x;
  __shared__ u64 s_kw[16];
  __shared__ u64 s_m[7680];         // 60 KiB: word w at 64*w*(w+1)/2, rows <(w+1)*64
  const u64* mb = mask + (size_t)bl * 16 * 1024;
  int wstage = (WN < 15) ? WN : 15;
  for (int w = 0; w < wstage; ++w){
    int rows = (w + 1) * 64;
    int base = 32 * w * (w + 1);    // = 64*w*(w+1)/2
    for (int r = tid; r < rows; r += 256)
      s_m[base + r] = mb[(size_t)w * 1024 + r];
  }
  __syncthreads();
  if (tid < 64){
    int lane = tid;
    // keep init = valid
    for (int c = 0; c < WN; ++c){
      int i = c * 64 + lane;
      int pred = (i < N) && (valid[(size_t)b * KTOT + koff + i] != 0u);
      u64 bal = __ballot(pred);
      if (lane == 0) s_kw[c] = bal;
    }
    for (int w = 0; w < WN; ++w){
      u64 supl = 0;
      if (w < 15){
        int base = 32 * w * (w + 1);
        for (int jb = 0; jb < w; ++jb){
          u64 kb = s_kw[jb];
          u64 m = s_m[base + jb * 64 + lane];          // unconditional ds_read
          supl |= (((kb >> lane) & 1ULL) ? m : 0ULL);
        }
      } else {
        for (int jb = 0; jb < w; ++jb){
          u64 kb = s_kw[jb];
          u64 m = mb[(size_t)w * 1024 + jb * 64 + lane]; // unconditional global
          supl |= (((kb >> lane) & 1ULL) ? m : 0ULL);
        }
      }
      for (int off = 32; off; off >>= 1) supl |= __shfl_xor(supl, off);
      int jr = w * 64 + lane;
      u64 rowl;
      if (w < 15){
        rowl = s_m[32 * w * (w + 1) + jr];             // diagonal rows staged
      } else {
        rowl = (jr < N) ? mb[(size_t)w * 1024 + jr] : 0ULL;
      }
      u64 cur = s_kw[w] & ~supl;
      u64 kept = 0;
      while (cur){
        int ib = __ffsll((unsigned long long)cur) - 1;
        kept |= (1ULL << ib);
        u64 r = __shfl(rowl, ib);
        cur &= ~r;
        cur &= ~(1ULL << ib);
      }
      if (lane == 0) s_kw[w] = kept;
    }
  }
  __syncthreads();
  // emit final-merge keys: (~fmap(score))<<32 | concat_pos ; suppressed -> ~0
  for (int i = tid; i < N; i += 256){
    u64 key = ~0ULL;
    if ((s_kw[i >> 6] >> (i & 63)) & 1ULL){
      float sc = scores[(size_t)b * KTOT + koff + i];
      key = ((u64)(~fmap(sc)) << 32) | (u32)(koff + i);
    }
    outk[(size_t)b * KTOT + koff + i] = key;
  }
}

// ---------- K5: per-image final sort + output ----------
__global__ void __launch_bounds__(1024)
k_final(const u64* __restrict__ outk, const float* __restrict__ boxes,
        float* __restrict__ out)
{
  __shared__ u64 sh[8192];   // 64 KiB
  int b = blockIdx.x, tid = threadIdx.x;
  for (int i = tid; i < 8192; i += 1024)
    sh[i] = (i < KTOT) ? outk[(size_t)b * KTOT + i] : ~0ULL;
  bitonic_sort<8192, 1024>(sh, tid);
  for (int r = tid; r < 1000; r += 1024){
    u64 key = sh[r];
    float o0 = 0.f, o1 = 0.f, o2 = 0.f, o3 = 0.f, sc = 0.f;
    if (key != ~0ULL){
      int kpos = (int)(u32)key;
      const float* p = boxes + ((size_t)(b * KTOT + kpos)) * 4;
      o0 = p[0]; o1 = p[1]; o2 = p[2]; o3 = p[3];
      sc = funmap(~(u32)(key >> 32));
    }
    float* ob = out + ((size_t)(b * 1000 + r)) * 4;
    ob[0] = o0; ob[1] = o1; ob[2] = o2; ob[3] = o3;
    out[32000 + b * 1000 + r] = sc;
  }
}

extern "C" void kernel_launch(void* const* d_in, const int* in_sizes, int n_in,
                              void* d_out, int out_size, void* d_ws, size_t ws_size,
                              hipStream_t stream)
{
  (void)in_sizes; (void)n_in; (void)out_size; (void)ws_size; // needs ~8.73 MB ws
  const float* obj     = (const float*)d_in[0];
  const float* deltas  = (const float*)d_in[1];
  const float* anchors = (const float*)d_in[2];
  float* out = (float*)d_out;
  char* ws = (char*)d_ws;

  u32* hist    = (u32*)(ws + OFF_HIST);
  u32* selcnt  = (u32*)(ws + OFF_SELCNT);
  u32* candcnt = (u32*)(ws + OFF_CANDCNT);
  u32* tbin    = (u32*)(ws + OFF_TBIN);
  u32* cless   = (u32*)(ws + OFF_CLESS);
  u64* selg    = (u64*)(ws + OFF_SELG);
  u64* candg   = (u64*)(ws + OFF_CANDG);
  u64* keys    = (u64*)(ws + OFF_KEYS);
  float* boxes = (float*)(ws + OFF_BOX);
  float* score = (float*)(ws + OFF_SCORE);
  u32* valid   = (u32*)(ws + OFF_VALID);
  u64* mask    = (u64*)(ws + OFF_MASK);
  u64* outk    = (u64*)(ws + OFF_OUTK);

  hipMemsetAsync(ws, 0, MEMSET_BYTES, stream);
  hipLaunchKernelGGL(k_hist,    dim3(144), dim3(1024), 0, stream, obj, hist);
  hipLaunchKernelGGL(k_cutoff,  dim3(40),  dim3(256),  0, stream, hist, tbin, cless);
  hipLaunchKernelGGL(k_collect, dim3(144), dim3(1024), 0, stream, obj, tbin, selcnt, candcnt, selg, candg);
  hipLaunchKernelGGL(k_select,  dim3(40),  dim3(1024), 0, stream, selcnt, candcnt, selg, candg, keys);
  hipLaunchKernelGGL(k_decode,  dim3(149), dim3(256),  0, stream, keys, deltas, anchors, boxes, score, valid);
  hipLaunchKernelGGL(k_mask,    dim3(368), dim3(256),  0, stream, boxes, mask);
  hipLaunchKernelGGL(k_nms,     dim3(40),  dim3(256),  0, stream, mask, valid, score, outk);
  hipLaunchKernelGGL(k_final,   dim3(8),   dim3(1024), 0, stream, outk, boxes, out);
}

// Round 6
// 367.823 us; speedup vs baseline: 1.5425x; 1.1069x over previous
//
#include <hip/hip_runtime.h>
#include <stdint.h>

#pragma clang fp contract(off)

typedef unsigned int u32;
typedef unsigned long long u64;

#define A_TOTAL 242991
#define KTOT    4741

// level tables
__constant__ int c_LN[5]   = {182400, 45600, 11400, 2850, 741};
__constant__ int c_LOFF[5] = {0, 182400, 228000, 239400, 242250};
__constant__ int c_LK[5]   = {1000, 1000, 1000, 1000, 741};

// k_mask tile tables: 46 upper-triangle (it<=jt) tiles per image
__constant__ int c_TL[46] = {0,0,0,0,0,0,0,0,0,0, 1,1,1,1,1,1,1,1,1,1,
                             2,2,2,2,2,2,2,2,2,2, 3,3,3,3,3,3,3,3,3,3,
                             4,4,4,4,4,4};
__constant__ int c_TI[46] = {0,0,0,0,1,1,1,2,2,3, 0,0,0,0,1,1,1,2,2,3,
                             0,0,0,0,1,1,1,2,2,3, 0,0,0,0,1,1,1,2,2,3,
                             0,0,0,1,1,2};
__constant__ int c_TJ[46] = {0,1,2,3,1,2,3,2,3,3, 0,1,2,3,1,2,3,2,3,3,
                             0,1,2,3,1,2,3,2,3,3, 0,1,2,3,1,2,3,2,3,3,
                             0,1,2,1,2,2};

// workspace byte offsets (total ~8.73 MB)
static const size_t OFF_HIST     = 0;        // 40*2048*4 = 327680
static const size_t OFF_SELCNT   = 327680;   // 40*4
static const size_t OFF_CANDCNT  = 327840;   // 40*4
static const size_t MEMSET_BYTES = 328000;
static const size_t OFF_TBIN     = 328000;   // 40*4
static const size_t OFF_CLESS    = 328160;   // 40*4
static const size_t OFF_SELG     = 328320;   // 40*1024*8  -> 656000
static const size_t OFF_CANDG    = 656000;   // 40*4096*8  -> 1966720
static const size_t OFF_KEYS     = 1966720;  // 8*4741*8   -> 2270144
static const size_t OFF_BOX      = 2270144;  // 8*4741*4*4 -> 2876992
static const size_t OFF_SCORE    = 2876992;  // 8*4741*4   -> 3028704
static const size_t OFF_VALID    = 3028704;  // 8*4741*4   -> 3180416
static const size_t OFF_MASK     = 3180416;  // 8*5*16*1024*8 -> 8423296
static const size_t OFF_OUTK     = 8423296;  // 8*4741*8   -> 8726720

// monotone float<->uint map: fmap ascending in float value
__device__ __forceinline__ u32 fmap(float f){
  u32 b = __float_as_uint(f);
  return (b & 0x80000000u) ? ~b : (b | 0x80000000u);
}
__device__ __forceinline__ float funmap(u32 m){
  return __uint_as_float((m & 0x80000000u) ? (m & 0x7FFFFFFFu) : ~m);
}

template<int N, int T>
__device__ __forceinline__ void bitonic_sort(u64* d, int tid){
  for (int k = 2; k <= N; k <<= 1){
    for (int j = k >> 1; j > 0; j >>= 1){
      __syncthreads();
      #pragma unroll 1
      for (int i = tid; i < N; i += T){
        int ixj = i ^ j;
        if (ixj > i){
          u64 a = d[i], b = d[ixj];
          bool sw = ((i & k) == 0) ? (a > b) : (a < b);
          if (sw){ d[i] = b; d[ixj] = a; }
        }
      }
    }
  }
  __syncthreads();
}

// block -> (b, level, segment) mapping for 16K-element scan segments:
// 18 blocks/image (12 for l0, 3 for l1, 1 each l2..l4)
__device__ __forceinline__ void seg_map(int blk, int& b, int& l, int& start, int& cnt){
  b = blk / 18; int s = blk % 18;
  if (s < 12)      { l = 0; start = s * 16384; }
  else if (s < 15) { l = 1; start = (s - 12) * 16384; }
  else             { l = s - 13; start = 0; }   // 15->l2, 16->l3, 17->l4
  int n = c_LN[l];
  cnt = n - start; if (cnt > 16384) cnt = 16384;
}

// ---------- K1a: per-(b,l) 2048-bin histogram of key-high-11-bits ----------
__global__ void __launch_bounds__(1024)
k_hist(const float* __restrict__ obj, u32* __restrict__ hist)
{
  int b, l, start, cnt; seg_map(blockIdx.x, b, l, start, cnt);
  int bl = b * 5 + l;
  __shared__ u32 h[2048];
  for (int i = threadIdx.x; i < 2048; i += 1024) h[i] = 0;
  __syncthreads();
  const float* p = obj + (size_t)b * A_TOTAL + c_LOFF[l] + start;
  for (int i = threadIdx.x; i < cnt; i += 1024){
    u32 m = ~fmap(p[i]);           // ascending m == descending objectness
    atomicAdd(&h[m >> 21], 1u);
  }
  __syncthreads();
  for (int i = threadIdx.x; i < 2048; i += 1024){
    u32 v = h[i];
    if (v) atomicAdd(&hist[bl * 2048 + i], v);
  }
}

// ---------- K1b: find cutoff bin t and count_less ----------
__global__ void __launch_bounds__(256)
k_cutoff(const u32* __restrict__ hist, u32* __restrict__ tbin, u32* __restrict__ cless)
{
  int bl = blockIdx.x; int l = bl % 5;
  int K = c_LK[l], n = c_LN[l];
  int tid = threadIdx.x;
  if (K >= n){ if (tid == 0){ tbin[bl] = 2048u; cless[bl] = (u32)n; } return; }
  __shared__ u32 cum[2048];
  __shared__ u32 part[256];
  __shared__ int s_t;
  u32 vals[8]; u32 sum = 0;
  for (int q = 0; q < 8; ++q){ vals[q] = hist[bl * 2048 + tid * 8 + q]; sum += vals[q]; }
  part[tid] = sum;
  __syncthreads();
  for (int off = 1; off < 256; off <<= 1){
    u32 add = (tid >= off) ? part[tid - off] : 0u;
    __syncthreads();
    part[tid] += add;
    __syncthreads();
  }
  u32 run = (tid > 0) ? part[tid - 1] : 0u;
  for (int q = 0; q < 8; ++q){ run += vals[q]; cum[tid * 8 + q] = run; }
  if (tid == 0) s_t = 0;
  __syncthreads();
  for (int q = 0; q < 8; ++q){
    int i = tid * 8 + q;
    u32 c = cum[i], cp = (i > 0) ? cum[i - 1] : 0u;
    if (c >= (u32)K && cp < (u32)K) s_t = i;
  }
  __syncthreads();
  if (tid == 0){
    int t = s_t;
    tbin[bl] = (u32)t;
    cless[bl] = (t > 0) ? cum[t - 1] : 0u;
  }
}

// ---------- K1c: collect selected + boundary-bin candidates ----------
__global__ void __launch_bounds__(1024)
k_collect(const float* __restrict__ obj, const u32* __restrict__ tbin,
          u32* __restrict__ selcnt, u32* __restrict__ candcnt,
          u64* __restrict__ selg, u64* __restrict__ candg)
{
  int b, l, start, cnt; seg_map(blockIdx.x, b, l, start, cnt);
  int bl = b * 5 + l;
  u32 t = tbin[bl];
  const float* p = obj + (size_t)b * A_TOTAL + c_LOFF[l] + start;
  for (int i = threadIdx.x; i < cnt; i += 1024){
    u32 m = ~fmap(p[i]);
    u32 bin = m >> 21;
    u64 key = ((u64)m << 32) | (u32)(start + i);
    if (bin < t){
      u32 pos = atomicAdd(&selcnt[bl], 1u);
      selg[(size_t)bl * 1024 + pos] = key;
    } else if (bin == t){
      u32 pos = atomicAdd(&candcnt[bl], 1u);
      if (pos < 4096u) candg[(size_t)bl * 4096 + pos] = key;
    }
  }
}

// ---------- K1d: assemble exact top-K and sort descending-by-obj ----------
__global__ void __launch_bounds__(1024)
k_select(const u32* __restrict__ selcnt, const u32* __restrict__ candcnt,
         const u64* __restrict__ selg, const u64* __restrict__ candg,
         u64* __restrict__ keys)
{
  int bl = blockIdx.x; int b = bl / 5, l = bl % 5;
  int K = c_LK[l];
  int tid = threadIdx.x;
  __shared__ u64 cand[4096];
  __shared__ u64 sel[1024];
  u32 nc = candcnt[bl]; if (nc > 4096u) nc = 4096u;
  u32 ns = selcnt[bl];
  int R = K - (int)ns;
  for (int i = tid; i < 4096; i += 1024) cand[i] = (i < (int)nc) ? candg[(size_t)bl * 4096 + i] : ~0ULL;
  sel[tid] = ~0ULL;
  __syncthreads();
  if (R > 0){
    bitonic_sort<4096, 1024>(cand, tid);
  }
  for (int i = tid; i < (int)ns; i += 1024) sel[i] = selg[(size_t)bl * 1024 + i];
  for (int i = tid; i < R; i += 1024) sel[(int)ns + i] = cand[i];
  bitonic_sort<1024, 1024>(sel, tid);
  for (int i = tid; i < K; i += 1024) keys[(size_t)b * KTOT + l * 1000 + i] = sel[i];
}

// ---------- K2: gather + decode + clip + sigmoid + validity ----------
__global__ void __launch_bounds__(256)
k_decode(const u64* __restrict__ keys, const float* __restrict__ deltas,
         const float* __restrict__ anchors, float* __restrict__ boxes,
         float* __restrict__ scores, u32* __restrict__ valid)
{
  int g = blockIdx.x * 256 + threadIdx.x;
  if (g >= 8 * KTOT) return;
  int b = g / KTOT, kpos = g % KTOT;
  int l = kpos / 1000; if (l > 4) l = 4;
  u64 key = keys[g];
  u32 idx = (u32)key;
  float o = funmap(~(u32)(key >> 32));
  int ai = c_LOFF[l] + (int)idx;
  const float* a = anchors + (size_t)ai * 4;
  const float* d = deltas + ((size_t)b * A_TOTAL + ai) * 4;
  float a0 = a[0], a1 = a[1], a2 = a[2], a3 = a[3];
  float wa = __fsub_rn(a2, a0), ha = __fsub_rn(a3, a1);
  float cxa = __fadd_rn(a0, __fmul_rn(0.5f, wa));
  float cya = __fadd_rn(a1, __fmul_rn(0.5f, ha));
  float dx = d[0], dy = d[1];
  float dw = fminf(d[2], 4.135166556742356f);   // log(1000/16)
  float dh = fminf(d[3], 4.135166556742356f);
  float cx = __fadd_rn(__fmul_rn(dx, wa), cxa);
  float cy = __fadd_rn(__fmul_rn(dy, ha), cya);
  float w  = __fmul_rn(expf(dw), wa);
  float h  = __fmul_rn(expf(dh), ha);
  float hw = __fmul_rn(0.5f, w), hh = __fmul_rn(0.5f, h);
  float x1 = __fsub_rn(cx, hw), y1 = __fsub_rn(cy, hh);
  float x2 = __fadd_rn(cx, hw), y2 = __fadd_rn(cy, hh);
  x1 = fminf(fmaxf(x1, 0.0f), 1216.0f);
  x2 = fminf(fmaxf(x2, 0.0f), 1216.0f);
  y1 = fminf(fmaxf(y1, 0.0f), 800.0f);
  y2 = fminf(fmaxf(y2, 0.0f), 800.0f);
  float s = __fdiv_rn(1.0f, __fadd_rn(1.0f, expf(-o)));
  int v = (__fsub_rn(x2, x1) >= 0.001f) && (__fsub_rn(y2, y1) >= 0.001f) && (s >= 0.0f);
  float* bo = boxes + (size_t)g * 4;
  bo[0] = x1; bo[1] = y1; bo[2] = x2; bo[3] = y2;
  scores[g] = s;
  valid[g] = (u32)v;
}

// ---------- K3: per-level suppression bitmask, 256x256 upper-tri tiles ----------
__global__ void __launch_bounds__(256)
k_mask(const float* __restrict__ boxes, u64* __restrict__ mask)
{
  int b = blockIdx.x / 46, s = blockIdx.x % 46;
  int l = c_TL[s], it = c_TI[s], jt = c_TJ[s];
  int N = c_LK[l];
  int koff = l * 1000;
  float offv = (float)(l * 4096);   // exact
  __shared__ float4 sxy[256];
  __shared__ float  sar[256];
  int j0 = jt * 256;
  {
    int tj = j0 + (int)threadIdx.x;
    float4 q; float ar;
    if (tj < N){
      float4 p = ((const float4*)boxes)[(size_t)(b * KTOT + koff + tj)];
      q.x = __fadd_rn(p.x, offv); q.y = __fadd_rn(p.y, offv);
      q.z = __fadd_rn(p.z, offv); q.w = __fadd_rn(p.w, offv);
      ar = __fmul_rn(__fsub_rn(q.z, q.x), __fsub_rn(q.w, q.y));
    } else {
      q.x = 3e38f; q.y = 3e38f; q.z = -3e38f; q.w = -3e38f; ar = 0.f;
    }
    sxy[threadIdx.x] = q; sar[threadIdx.x] = ar;
  }
  __syncthreads();
  int i = it * 256 + (int)threadIdx.x;
  if (i >= N) return;
  float4 p = ((const float4*)boxes)[(size_t)(b * KTOT + koff + i)];
  float bx1 = __fadd_rn(p.x, offv), by1 = __fadd_rn(p.y, offv);
  float bx2 = __fadd_rn(p.z, offv), by2 = __fadd_rn(p.w, offv);
  float bar = __fmul_rn(__fsub_rn(bx2, bx1), __fsub_rn(by2, by1));
  u64* mb = mask + ((size_t)(b * 5 + l) * 16) * 1024;
  for (int w = 0; w < 4; ++w){
    int jbase = j0 + w * 64;
    if (jbase >= N) break;
    u64 bw = 0;
    #pragma unroll 16
    for (int jj = 0; jj < 64; ++jj){
      int j = jbase + jj;
      float4 q = sxy[w * 64 + jj];
      float aj = sar[w * 64 + jj];
      float ltx = fmaxf(bx1, q.x), lty = fmaxf(by1, q.y);
      float rbx = fminf(bx2, q.z), rby = fminf(by2, q.w);
      float wx = fmaxf(__fsub_rn(rbx, ltx), 0.0f);
      float wy = fmaxf(__fsub_rn(rby, lty), 0.0f);
      float inter = __fmul_rn(wx, wy);
      bool sup = false;
      if (inter > 0.0f && j > i){
        float den = __fsub_rn(__fadd_rn(bar, aj), inter);
        sup = __fdiv_rn(inter, den) > 0.7f;
      }
      bw |= ((u64)sup) << jj;
    }
    mb[(size_t)(jbase >> 6) * 1024 + i] = bw;
  }
}

// ---------- K4: exact greedy NMS scan, LDS-staged, 256 threads/block ----------
__global__ void __launch_bounds__(256)
k_nms(const u64* __restrict__ mask, const u32* __restrict__ valid,
      const float* __restrict__ scores, u64* __restrict__ outk)
{
  int bl = blockIdx.x; int b = bl / 5, l = bl % 5;
  int N = c_LK[l], koff = l * 1000;
  int WN = (N + 63) >> 6;           // 16 (levels 0-3) or 12 (level 4)
  int tid = threadIdx.x;
  __shared__ u64 s_kw[16];
  __shared__ u64 s_m[7680];         // 60 KiB: word w at 64*w*(w+1)/2, rows <(w+1)*64
  const u64* mb = mask + (size_t)bl * 16 * 1024;
  int wstage = (WN < 15) ? WN : 15;
  for (int w = 0; w < wstage; ++w){
    int rows = (w + 1) * 64;
    int base = 32 * w * (w + 1);    // = 64*w*(w+1)/2
    for (int r = tid; r < rows; r += 256)
      s_m[base + r] = mb[(size_t)w * 1024 + r];
  }
  __syncthreads();
  if (tid < 64){
    int lane = tid;
    // keep init = valid
    for (int c = 0; c < WN; ++c){
      int i = c * 64 + lane;
      int pred = (i < N) && (valid[(size_t)b * KTOT + koff + i] != 0u);
      u64 bal = __ballot(pred);
      if (lane == 0) s_kw[c] = bal;
    }
    for (int w = 0; w < WN; ++w){
      u64 supl = 0;
      if (w < 15){
        int base = 32 * w * (w + 1);
        for (int jb = 0; jb < w; ++jb){
          u64 kb = s_kw[jb];
          u64 m = s_m[base + jb * 64 + lane];          // unconditional ds_read
          supl |= (((kb >> lane) & 1ULL) ? m : 0ULL);
        }
      } else {
        for (int jb = 0; jb < w; ++jb){
          u64 kb = s_kw[jb];
          u64 m = mb[(size_t)w * 1024 + jb * 64 + lane]; // unconditional global
          supl |= (((kb >> lane) & 1ULL) ? m : 0ULL);
        }
      }
      for (int off = 32; off; off >>= 1) supl |= __shfl_xor(supl, off);
      int jr = w * 64 + lane;
      u64 rowl;
      if (w < 15){
        rowl = s_m[32 * w * (w + 1) + jr];             // diagonal rows staged
      } else {
        rowl = (jr < N) ? mb[(size_t)w * 1024 + jr] : 0ULL;
      }
      u64 cur = s_kw[w] & ~supl;
      u64 kept = 0;
      while (cur){
        int ib = __ffsll((unsigned long long)cur) - 1;
        kept |= (1ULL << ib);
        u64 r = __shfl(rowl, ib);
        cur &= ~r;
        cur &= ~(1ULL << ib);
      }
      if (lane == 0) s_kw[w] = kept;
    }
  }
  __syncthreads();
  // emit final-merge keys: (~fmap(score))<<32 | concat_pos ; suppressed -> ~0
  for (int i = tid; i < N; i += 256){
    u64 key = ~0ULL;
    if ((s_kw[i >> 6] >> (i & 63)) & 1ULL){
      float sc = scores[(size_t)b * KTOT + koff + i];
      key = ((u64)(~fmap(sc)) << 32) | (u32)(koff + i);
    }
    outk[(size_t)b * KTOT + koff + i] = key;
  }
}

// ---------- K5: rank-by-counting final selection (replaces 8192-bitonic) ----------
// All real keys are distinct; suppressed slots hold ~0ULL (maximal) so they never
// lower a real key's rank. rank(i) = #{j: key_j < key_i}; write iff rank < 1000.
// Output pre-zeroed by hipMemsetAsync (reference zero-pads ranks >= kept count).
#define KPAD 4744   // KTOT rounded up to multiple of 4; pad keys = ~0ULL (add 0 to ranks)
__global__ void __launch_bounds__(256)
k_rank(const u64* __restrict__ outk, const float* __restrict__ boxes,
       float* __restrict__ out)
{
  int b = blockIdx.x / 19, chunk = blockIdx.x % 19;
  int tid = threadIdx.x;
  __shared__ u64 sk[KPAD];
  for (int i = tid; i < KPAD; i += 256)
    sk[i] = (i < KTOT) ? outk[(size_t)b * KTOT + i] : ~0ULL;
  __syncthreads();
  int i = chunk * 256 + tid;
  if (i >= KTOT) return;
  u64 key = sk[i];
  if (key == ~0ULL) return;     // suppressed / invalid
  int rank = 0;
  #pragma unroll 4
  for (int j = 0; j < KPAD; j += 2){
    ulonglong2 v = *reinterpret_cast<const ulonglong2*>(&sk[j]);  // LDS broadcast
    rank += (v.x < key) + (v.y < key);
  }
  if (rank < 1000){
    float4 bx = ((const float4*)boxes)[(size_t)(b * KTOT + i)];
    ((float4*)out)[(size_t)(b * 1000 + rank)] = bx;
    out[32000 + b * 1000 + rank] = funmap(~(u32)(key >> 32));
  }
}

extern "C" void kernel_launch(void* const* d_in, const int* in_sizes, int n_in,
                              void* d_out, int out_size, void* d_ws, size_t ws_size,
                              hipStream_t stream)
{
  (void)in_sizes; (void)n_in; (void)ws_size; // needs ~8.73 MB ws
  const float* obj     = (const float*)d_in[0];
  const float* deltas  = (const float*)d_in[1];
  const float* anchors = (const float*)d_in[2];
  float* out = (float*)d_out;
  char* ws = (char*)d_ws;

  u32* hist    = (u32*)(ws + OFF_HIST);
  u32* selcnt  = (u32*)(ws + OFF_SELCNT);
  u32* candcnt = (u32*)(ws + OFF_CANDCNT);
  u32* tbin    = (u32*)(ws + OFF_TBIN);
  u32* cless   = (u32*)(ws + OFF_CLESS);
  u64* selg    = (u64*)(ws + OFF_SELG);
  u64* candg   = (u64*)(ws + OFF_CANDG);
  u64* keys    = (u64*)(ws + OFF_KEYS);
  float* boxes = (float*)(ws + OFF_BOX);
  float* score = (float*)(ws + OFF_SCORE);
  u32* valid   = (u32*)(ws + OFF_VALID);
  u64* mask    = (u64*)(ws + OFF_MASK);
  u64* outk    = (u64*)(ws + OFF_OUTK);

  hipMemsetAsync(ws, 0, MEMSET_BYTES, stream);
  hipMemsetAsync(d_out, 0, (size_t)out_size * sizeof(float), stream);
  hipLaunchKernelGGL(k_hist,    dim3(144), dim3(1024), 0, stream, obj, hist);
  hipLaunchKernelGGL(k_cutoff,  dim3(40),  dim3(256),  0, stream, hist, tbin, cless);
  hipLaunchKernelGGL(k_collect, dim3(144), dim3(1024), 0, stream, obj, tbin, selcnt, candcnt, selg, candg);
  hipLaunchKernelGGL(k_select,  dim3(40),  dim3(1024), 0, stream, selcnt, candcnt, selg, candg, keys);
  hipLaunchKernelGGL(k_decode,  dim3(149), dim3(256),  0, stream, keys, deltas, anchors, boxes, score, valid);
  hipLaunchKernelGGL(k_mask,    dim3(368), dim3(256),  0, stream, boxes, mask);
  hipLaunchKernelGGL(k_nms,     dim3(40),  dim3(256),  0, stream, mask, valid, score, outk);
  hipLaunchKernelGGL(k_rank,    dim3(152), dim3(256),  0, stream, outk, boxes, out);
}

// Round 7
// 361.641 us; speedup vs baseline: 1.5688x; 1.0171x over previous
//
#include <hip/hip_runtime.h>
#include <stdint.h>

#pragma clang fp contract(off)

typedef unsigned int u32;
typedef unsigned long long u64;

#define A_TOTAL 242991
#define KTOT    4741

// level tables
__constant__ int c_LN[5]   = {182400, 45600, 11400, 2850, 741};
__constant__ int c_LOFF[5] = {0, 182400, 228000, 239400, 242250};
__constant__ int c_LK[5]   = {1000, 1000, 1000, 1000, 741};

// k_mask tile tables: 46 upper-triangle (it<=jt) tiles per image
__constant__ int c_TL[46] = {0,0,0,0,0,0,0,0,0,0, 1,1,1,1,1,1,1,1,1,1,
                             2,2,2,2,2,2,2,2,2,2, 3,3,3,3,3,3,3,3,3,3,
                             4,4,4,4,4,4};
__constant__ int c_TI[46] = {0,0,0,0,1,1,1,2,2,3, 0,0,0,0,1,1,1,2,2,3,
                             0,0,0,0,1,1,1,2,2,3, 0,0,0,0,1,1,1,2,2,3,
                             0,0,0,1,1,2};
__constant__ int c_TJ[46] = {0,1,2,3,1,2,3,2,3,3, 0,1,2,3,1,2,3,2,3,3,
                             0,1,2,3,1,2,3,2,3,3, 0,1,2,3,1,2,3,2,3,3,
                             0,1,2,1,2,2};

// workspace byte offsets (total ~8.73 MB)
static const size_t OFF_HIST     = 0;        // 40*2048*4 = 327680
static const size_t OFF_SELCNT   = 327680;   // 40*4
static const size_t OFF_CANDCNT  = 327840;   // 40*4
static const size_t MEMSET_BYTES = 328000;
static const size_t OFF_TBIN     = 328000;   // 40*4
static const size_t OFF_CLESS    = 328160;   // 40*4
static const size_t OFF_SELG     = 328320;   // 40*1024*8  -> 656000
static const size_t OFF_CANDG    = 656000;   // 40*4096*8  -> 1966720
static const size_t OFF_KEYS     = 1966720;  // 8*4741*8   -> 2270144
static const size_t OFF_BOX      = 2270144;  // 8*4741*4*4 -> 2876992
static const size_t OFF_SCORE    = 2876992;  // 8*4741*4   -> 3028704
static const size_t OFF_VALID    = 3028704;  // 8*4741*4   -> 3180416
static const size_t OFF_MASK     = 3180416;  // 8*5*16*1024*8 -> 8423296
static const size_t OFF_OUTK     = 8423296;  // 8*4741*8   -> 8726720

// monotone float<->uint map: fmap ascending in float value
__device__ __forceinline__ u32 fmap(float f){
  u32 b = __float_as_uint(f);
  return (b & 0x80000000u) ? ~b : (b | 0x80000000u);
}
__device__ __forceinline__ float funmap(u32 m){
  return __uint_as_float((m & 0x80000000u) ? (m & 0x7FFFFFFFu) : ~m);
}

template<int N, int T>
__device__ __forceinline__ void bitonic_sort(u64* d, int tid){
  for (int k = 2; k <= N; k <<= 1){
    for (int j = k >> 1; j > 0; j >>= 1){
      __syncthreads();
      #pragma unroll 1
      for (int i = tid; i < N; i += T){
        int ixj = i ^ j;
        if (ixj > i){
          u64 a = d[i], b = d[ixj];
          bool sw = ((i & k) == 0) ? (a > b) : (a < b);
          if (sw){ d[i] = b; d[ixj] = a; }
        }
      }
    }
  }
  __syncthreads();
}

// block -> (b, level, segment) mapping for 16K-element scan segments:
// 18 blocks/image (12 for l0, 3 for l1, 1 each l2..l4)
__device__ __forceinline__ void seg_map(int blk, int& b, int& l, int& start, int& cnt){
  b = blk / 18; int s = blk % 18;
  if (s < 12)      { l = 0; start = s * 16384; }
  else if (s < 15) { l = 1; start = (s - 12) * 16384; }
  else             { l = s - 13; start = 0; }   // 15->l2, 16->l3, 17->l4
  int n = c_LN[l];
  cnt = n - start; if (cnt > 16384) cnt = 16384;
}

// ---------- K1a: per-(b,l) 2048-bin histogram of key-high-11-bits ----------
__global__ void __launch_bounds__(1024)
k_hist(const float* __restrict__ obj, u32* __restrict__ hist)
{
  int b, l, start, cnt; seg_map(blockIdx.x, b, l, start, cnt);
  int bl = b * 5 + l;
  __shared__ u32 h[2048];
  for (int i = threadIdx.x; i < 2048; i += 1024) h[i] = 0;
  __syncthreads();
  const float* p = obj + (size_t)b * A_TOTAL + c_LOFF[l] + start;
  for (int i = threadIdx.x; i < cnt; i += 1024){
    u32 m = ~fmap(p[i]);           // ascending m == descending objectness
    atomicAdd(&h[m >> 21], 1u);
  }
  __syncthreads();
  for (int i = threadIdx.x; i < 2048; i += 1024){
    u32 v = h[i];
    if (v) atomicAdd(&hist[bl * 2048 + i], v);
  }
}

// ---------- K1b: find cutoff bin t and count_less ----------
__global__ void __launch_bounds__(256)
k_cutoff(const u32* __restrict__ hist, u32* __restrict__ tbin, u32* __restrict__ cless)
{
  int bl = blockIdx.x; int l = bl % 5;
  int K = c_LK[l], n = c_LN[l];
  int tid = threadIdx.x;
  if (K >= n){ if (tid == 0){ tbin[bl] = 2048u; cless[bl] = (u32)n; } return; }
  __shared__ u32 cum[2048];
  __shared__ u32 part[256];
  __shared__ int s_t;
  u32 vals[8]; u32 sum = 0;
  for (int q = 0; q < 8; ++q){ vals[q] = hist[bl * 2048 + tid * 8 + q]; sum += vals[q]; }
  part[tid] = sum;
  __syncthreads();
  for (int off = 1; off < 256; off <<= 1){
    u32 add = (tid >= off) ? part[tid - off] : 0u;
    __syncthreads();
    part[tid] += add;
    __syncthreads();
  }
  u32 run = (tid > 0) ? part[tid - 1] : 0u;
  for (int q = 0; q < 8; ++q){ run += vals[q]; cum[tid * 8 + q] = run; }
  if (tid == 0) s_t = 0;
  __syncthreads();
  for (int q = 0; q < 8; ++q){
    int i = tid * 8 + q;
    u32 c = cum[i], cp = (i > 0) ? cum[i - 1] : 0u;
    if (c >= (u32)K && cp < (u32)K) s_t = i;
  }
  __syncthreads();
  if (tid == 0){
    int t = s_t;
    tbin[bl] = (u32)t;
    cless[bl] = (t > 0) ? cum[t - 1] : 0u;
  }
}

// ---------- K1c: collect selected + boundary-bin candidates ----------
__global__ void __launch_bounds__(1024)
k_collect(const float* __restrict__ obj, const u32* __restrict__ tbin,
          u32* __restrict__ selcnt, u32* __restrict__ candcnt,
          u64* __restrict__ selg, u64* __restrict__ candg)
{
  int b, l, start, cnt; seg_map(blockIdx.x, b, l, start, cnt);
  int bl = b * 5 + l;
  u32 t = tbin[bl];
  const float* p = obj + (size_t)b * A_TOTAL + c_LOFF[l] + start;
  for (int i = threadIdx.x; i < cnt; i += 1024){
    u32 m = ~fmap(p[i]);
    u32 bin = m >> 21;
    u64 key = ((u64)m << 32) | (u32)(start + i);
    if (bin < t){
      u32 pos = atomicAdd(&selcnt[bl], 1u);
      selg[(size_t)bl * 1024 + pos] = key;
    } else if (bin == t){
      u32 pos = atomicAdd(&candcnt[bl], 1u);
      if (pos < 4096u) candg[(size_t)bl * 4096 + pos] = key;
    }
  }
}

// ---------- K1d: assemble exact top-K and sort descending-by-obj ----------
__global__ void __launch_bounds__(1024)
k_select(const u32* __restrict__ selcnt, const u32* __restrict__ candcnt,
         const u64* __restrict__ selg, const u64* __restrict__ candg,
         u64* __restrict__ keys)
{
  int bl = blockIdx.x; int b = bl / 5, l = bl % 5;
  int K = c_LK[l];
  int tid = threadIdx.x;
  __shared__ u64 cand[4096];
  __shared__ u64 sel[1024];
  u32 nc = candcnt[bl]; if (nc > 4096u) nc = 4096u;
  u32 ns = selcnt[bl];
  int R = K - (int)ns;
  for (int i = tid; i < 4096; i += 1024) cand[i] = (i < (int)nc) ? candg[(size_t)bl * 4096 + i] : ~0ULL;
  sel[tid] = ~0ULL;
  __syncthreads();
  if (R > 0){
    bitonic_sort<4096, 1024>(cand, tid);
  }
  for (int i = tid; i < (int)ns; i += 1024) sel[i] = selg[(size_t)bl * 1024 + i];
  for (int i = tid; i < R; i += 1024) sel[(int)ns + i] = cand[i];
  bitonic_sort<1024, 1024>(sel, tid);
  for (int i = tid; i < K; i += 1024) keys[(size_t)b * KTOT + l * 1000 + i] = sel[i];
}

// ---------- K2: gather + decode + clip + sigmoid + validity ----------
__global__ void __launch_bounds__(256)
k_decode(const u64* __restrict__ keys, const float* __restrict__ deltas,
         const float* __restrict__ anchors, float* __restrict__ boxes,
         float* __restrict__ scores, u32* __restrict__ valid)
{
  int g = blockIdx.x * 256 + threadIdx.x;
  if (g >= 8 * KTOT) return;
  int b = g / KTOT, kpos = g % KTOT;
  int l = kpos / 1000; if (l > 4) l = 4;
  u64 key = keys[g];
  u32 idx = (u32)key;
  float o = funmap(~(u32)(key >> 32));
  int ai = c_LOFF[l] + (int)idx;
  const float* a = anchors + (size_t)ai * 4;
  const float* d = deltas + ((size_t)b * A_TOTAL + ai) * 4;
  float a0 = a[0], a1 = a[1], a2 = a[2], a3 = a[3];
  float wa = __fsub_rn(a2, a0), ha = __fsub_rn(a3, a1);
  float cxa = __fadd_rn(a0, __fmul_rn(0.5f, wa));
  float cya = __fadd_rn(a1, __fmul_rn(0.5f, ha));
  float dx = d[0], dy = d[1];
  float dw = fminf(d[2], 4.135166556742356f);   // log(1000/16)
  float dh = fminf(d[3], 4.135166556742356f);
  float cx = __fadd_rn(__fmul_rn(dx, wa), cxa);
  float cy = __fadd_rn(__fmul_rn(dy, ha), cya);
  float w  = __fmul_rn(expf(dw), wa);
  float h  = __fmul_rn(expf(dh), ha);
  float hw = __fmul_rn(0.5f, w), hh = __fmul_rn(0.5f, h);
  float x1 = __fsub_rn(cx, hw), y1 = __fsub_rn(cy, hh);
  float x2 = __fadd_rn(cx, hw), y2 = __fadd_rn(cy, hh);
  x1 = fminf(fmaxf(x1, 0.0f), 1216.0f);
  x2 = fminf(fmaxf(x2, 0.0f), 1216.0f);
  y1 = fminf(fmaxf(y1, 0.0f), 800.0f);
  y2 = fminf(fmaxf(y2, 0.0f), 800.0f);
  float s = __fdiv_rn(1.0f, __fadd_rn(1.0f, expf(-o)));
  int v = (__fsub_rn(x2, x1) >= 0.001f) && (__fsub_rn(y2, y1) >= 0.001f) && (s >= 0.0f);
  float* bo = boxes + (size_t)g * 4;
  bo[0] = x1; bo[1] = y1; bo[2] = x2; bo[3] = y2;
  scores[g] = s;
  valid[g] = (u32)v;
}

// ---------- K3: per-level suppression bitmask, 256x256 upper-tri tiles ----------
__global__ void __launch_bounds__(256)
k_mask(const float* __restrict__ boxes, u64* __restrict__ mask)
{
  int b = blockIdx.x / 46, s = blockIdx.x % 46;
  int l = c_TL[s], it = c_TI[s], jt = c_TJ[s];
  int N = c_LK[l];
  int koff = l * 1000;
  float offv = (float)(l * 4096);   // exact
  __shared__ float4 sxy[256];
  __shared__ float  sar[256];
  int j0 = jt * 256;
  {
    int tj = j0 + (int)threadIdx.x;
    float4 q; float ar;
    if (tj < N){
      float4 p = ((const float4*)boxes)[(size_t)(b * KTOT + koff + tj)];
      q.x = __fadd_rn(p.x, offv); q.y = __fadd_rn(p.y, offv);
      q.z = __fadd_rn(p.z, offv); q.w = __fadd_rn(p.w, offv);
      ar = __fmul_rn(__fsub_rn(q.z, q.x), __fsub_rn(q.w, q.y));
    } else {
      q.x = 3e38f; q.y = 3e38f; q.z = -3e38f; q.w = -3e38f; ar = 0.f;
    }
    sxy[threadIdx.x] = q; sar[threadIdx.x] = ar;
  }
  __syncthreads();
  int i = it * 256 + (int)threadIdx.x;
  if (i >= N) return;
  float4 p = ((const float4*)boxes)[(size_t)(b * KTOT + koff + i)];
  float bx1 = __fadd_rn(p.x, offv), by1 = __fadd_rn(p.y, offv);
  float bx2 = __fadd_rn(p.z, offv), by2 = __fadd_rn(p.w, offv);
  float bar = __fmul_rn(__fsub_rn(bx2, bx1), __fsub_rn(by2, by1));
  u64* mb = mask + ((size_t)(b * 5 + l) * 16) * 1024;
  for (int w = 0; w < 4; ++w){
    int jbase = j0 + w * 64;
    if (jbase >= N) break;
    u64 bw = 0;
    #pragma unroll 16
    for (int jj = 0; jj < 64; ++jj){
      int j = jbase + jj;
      float4 q = sxy[w * 64 + jj];
      float aj = sar[w * 64 + jj];
      float ltx = fmaxf(bx1, q.x), lty = fmaxf(by1, q.y);
      float rbx = fminf(bx2, q.z), rby = fminf(by2, q.w);
      float wx = fmaxf(__fsub_rn(rbx, ltx), 0.0f);
      float wy = fmaxf(__fsub_rn(rby, lty), 0.0f);
      float inter = __fmul_rn(wx, wy);
      bool sup = false;
      if (inter > 0.0f && j > i){
        float den = __fsub_rn(__fadd_rn(bar, aj), inter);
        sup = __fdiv_rn(inter, den) > 0.7f;
      }
      bw |= ((u64)sup) << jj;
    }
    mb[(size_t)(jbase >> 6) * 1024 + i] = bw;
  }
}

// ---------- K4: exact greedy NMS scan, LDS-staged + readlane greedy chain ----------
// Word w consumes mask rows < (w+1)*64; words 0..14 staged in LDS (60 KiB).
// Greedy while-loop uses readfirstlane+v_readlane (scalar path, ~8 cy) instead of
// ds_bpermute __shfl (~120+ cy) -- ib is wave-uniform so both are exact; this cuts
// the serial per-kept-box chain ~5x. Semantics bit-identical to the R5 version.
__global__ void __launch_bounds__(256)
k_nms(const u64* __restrict__ mask, const u32* __restrict__ valid,
      const float* __restrict__ scores, u64* __restrict__ outk)
{
  int bl = blockIdx.x; int b = bl / 5, l = bl % 5;
  int N = c_LK[l], koff = l * 1000;
  int WN = (N + 63) >> 6;           // 16 (levels 0-3) or 12 (level 4)
  int tid = threadIdx.x;
  __shared__ u64 s_kw[16];
  __shared__ u64 s_m[7680];         // 60 KiB: word w at 64*w*(w+1)/2, rows <(w+1)*64
  const u64* mb = mask + (size_t)bl * 16 * 1024;
  int wstage = (WN < 15) ? WN : 15;
  for (int w = 0; w < wstage; ++w){
    int rows = (w + 1) * 64;
    int base = 32 * w * (w + 1);    // = 64*w*(w+1)/2
    for (int r = tid; r < rows; r += 256)
      s_m[base + r] = mb[(size_t)w * 1024 + r];
  }
  __syncthreads();
  if (tid < 64){
    int lane = tid;
    // keep init = valid
    for (int c = 0; c < WN; ++c){
      int i = c * 64 + lane;
      int pred = (i < N) && (valid[(size_t)b * KTOT + koff + i] != 0u);
      u64 bal = __ballot(pred);
      if (lane == 0) s_kw[c] = bal;
    }
    for (int w = 0; w < WN; ++w){
      // suppression of word w from finalized kept rows in words < w
      u64 supl = 0;
      if (w < 15){
        int base = 32 * w * (w + 1);
        for (int jb = 0; jb < w; ++jb){
          u64 kb = s_kw[jb];
          u64 m = s_m[base + jb * 64 + lane];            // unconditional ds_read
          supl |= (((kb >> lane) & 1ULL) ? m : 0ULL);
        }
      } else {
        for (int jb = 0; jb < w; ++jb){
          u64 kb = s_kw[jb];
          u64 m = mb[(size_t)w * 1024 + jb * 64 + lane]; // unconditional global
          supl |= (((kb >> lane) & 1ULL) ? m : 0ULL);
        }
      }
      for (int off = 32; off; off >>= 1) supl |= __shfl_xor(supl, off);
      // in-word rows held per-lane in registers (lane r owns row w*64+r's word w)
      int jr = w * 64 + lane;
      u64 rowl;
      if (w < 15) rowl = s_m[32 * w * (w + 1) + jr];     // diagonal rows staged
      else        rowl = (jr < N) ? mb[(size_t)w * 1024 + jr] : 0ULL;
      u32 rowl_lo = (u32)rowl, rowl_hi = (u32)(rowl >> 32);
      u64 cur = s_kw[w] & ~supl;
      u64 kept = 0;
      while (cur){
        int ib  = __ffsll((unsigned long long)cur) - 1;  // wave-uniform
        int ibs = __builtin_amdgcn_readfirstlane(ib);
        u32 rlo = (u32)__builtin_amdgcn_readlane((int)rowl_lo, ibs);
        u32 rhi = (u32)__builtin_amdgcn_readlane((int)rowl_hi, ibs);
        u64 r   = ((u64)rhi << 32) | rlo;
        u64 bit = 1ULL << ibs;
        kept |= bit;
        cur &= ~(r | bit);
      }
      if (lane == 0) s_kw[w] = kept;
    }
  }
  __syncthreads();
  // emit final-merge keys: (~fmap(score))<<32 | concat_pos ; suppressed -> ~0
  for (int i = tid; i < N; i += 256){
    u64 key = ~0ULL;
    if ((s_kw[i >> 6] >> (i & 63)) & 1ULL){
      float sc = scores[(size_t)b * KTOT + koff + i];
      key = ((u64)(~fmap(sc)) << 32) | (u32)(koff + i);
    }
    outk[(size_t)b * KTOT + koff + i] = key;
  }
}

// ---------- K5: rank-by-counting final selection ----------
#define KPAD 4744   // KTOT rounded up to multiple of 4; pad keys = ~0ULL (add 0 to ranks)
__global__ void __launch_bounds__(256)
k_rank(const u64* __restrict__ outk, const float* __restrict__ boxes,
       float* __restrict__ out)
{
  int b = blockIdx.x / 19, chunk = blockIdx.x % 19;
  int tid = threadIdx.x;
  __shared__ u64 sk[KPAD];
  for (int i = tid; i < KPAD; i += 256)
    sk[i] = (i < KTOT) ? outk[(size_t)b * KTOT + i] : ~0ULL;
  __syncthreads();
  int i = chunk * 256 + tid;
  if (i >= KTOT) return;
  u64 key = sk[i];
  if (key == ~0ULL) return;     // suppressed / invalid
  int rank = 0;
  #pragma unroll 4
  for (int j = 0; j < KPAD; j += 2){
    ulonglong2 v = *reinterpret_cast<const ulonglong2*>(&sk[j]);  // LDS broadcast
    rank += (v.x < key) + (v.y < key);
  }
  if (rank < 1000){
    float4 bx = ((const float4*)boxes)[(size_t)(b * KTOT + i)];
    ((float4*)out)[(size_t)(b * 1000 + rank)] = bx;
    out[32000 + b * 1000 + rank] = funmap(~(u32)(key >> 32));
  }
}

extern "C" void kernel_launch(void* const* d_in, const int* in_sizes, int n_in,
                              void* d_out, int out_size, void* d_ws, size_t ws_size,
                              hipStream_t stream)
{
  (void)in_sizes; (void)n_in; (void)ws_size; // needs ~8.73 MB ws
  const float* obj     = (const float*)d_in[0];
  const float* deltas  = (const float*)d_in[1];
  const float* anchors = (const float*)d_in[2];
  float* out = (float*)d_out;
  char* ws = (char*)d_ws;

  u32* hist    = (u32*)(ws + OFF_HIST);
  u32* selcnt  = (u32*)(ws + OFF_SELCNT);
  u32* candcnt = (u32*)(ws + OFF_CANDCNT);
  u32* tbin    = (u32*)(ws + OFF_TBIN);
  u32* cless   = (u32*)(ws + OFF_CLESS);
  u64* selg    = (u64*)(ws + OFF_SELG);
  u64* candg   = (u64*)(ws + OFF_CANDG);
  u64* keys    = (u64*)(ws + OFF_KEYS);
  float* boxes = (float*)(ws + OFF_BOX);
  float* score = (float*)(ws + OFF_SCORE);
  u32* valid   = (u32*)(ws + OFF_VALID);
  u64* mask    = (u64*)(ws + OFF_MASK);
  u64* outk    = (u64*)(ws + OFF_OUTK);

  hipMemsetAsync(ws, 0, MEMSET_BYTES, stream);
  hipMemsetAsync(d_out, 0, (size_t)out_size * sizeof(float), stream);
  hipLaunchKernelGGL(k_hist,    dim3(144), dim3(1024), 0, stream, obj, hist);
  hipLaunchKernelGGL(k_cutoff,  dim3(40),  dim3(256),  0, stream, hist, tbin, cless);
  hipLaunchKernelGGL(k_collect, dim3(144), dim3(1024), 0, stream, obj, tbin, selcnt, candcnt, selg, candg);
  hipLaunchKernelGGL(k_select,  dim3(40),  dim3(1024), 0, stream, selcnt, candcnt, selg, candg, keys);
  hipLaunchKernelGGL(k_decode,  dim3(149), dim3(256),  0, stream, keys, deltas, anchors, boxes, score, valid);
  hipLaunchKernelGGL(k_mask,    dim3(368), dim3(256),  0, stream, boxes, mask);
  hipLaunchKernelGGL(k_nms,     dim3(40),  dim3(256),  0, stream, mask, valid, score, outk);
  hipLaunchKernelGGL(k_rank,    dim3(152), dim3(256),  0, stream, outk, boxes, out);
}

// Round 8
// 301.485 us; speedup vs baseline: 1.8819x; 1.1995x over previous
//
#include <hip/hip_runtime.h>
#include <stdint.h>

#pragma clang fp contract(off)

typedef unsigned int u32;
typedef unsigned long long u64;

#define A_TOTAL 242991
#define KTOT    4741

// level tables
__constant__ int c_LN[5]   = {182400, 45600, 11400, 2850, 741};
__constant__ int c_LOFF[5] = {0, 182400, 228000, 239400, 242250};
__constant__ int c_LK[5]   = {1000, 1000, 1000, 1000, 741};

// k_mask tile tables: 46 upper-triangle (it<=jt) tiles per image
__constant__ int c_TL[46] = {0,0,0,0,0,0,0,0,0,0, 1,1,1,1,1,1,1,1,1,1,
                             2,2,2,2,2,2,2,2,2,2, 3,3,3,3,3,3,3,3,3,3,
                             4,4,4,4,4,4};
__constant__ int c_TI[46] = {0,0,0,0,1,1,1,2,2,3, 0,0,0,0,1,1,1,2,2,3,
                             0,0,0,0,1,1,1,2,2,3, 0,0,0,0,1,1,1,2,2,3,
                             0,0,0,1,1,2};
__constant__ int c_TJ[46] = {0,1,2,3,1,2,3,2,3,3, 0,1,2,3,1,2,3,2,3,3,
                             0,1,2,3,1,2,3,2,3,3, 0,1,2,3,1,2,3,2,3,3,
                             0,1,2,1,2,2};

// workspace byte offsets (total ~8.73 MB)
static const size_t OFF_HIST     = 0;        // 40*2048*4 = 327680
static const size_t OFF_SELCNT   = 327680;   // 40*4
static const size_t OFF_CANDCNT  = 327840;   // 40*4
static const size_t MEMSET_BYTES = 328000;
static const size_t OFF_TBIN     = 328000;   // 40*4
static const size_t OFF_CLESS    = 328160;   // 40*4
static const size_t OFF_SELG     = 328320;   // 40*1024*8  -> 656000
static const size_t OFF_CANDG    = 656000;   // 40*4096*8  -> 1966720
static const size_t OFF_KEYS     = 1966720;  // 8*4741*8   -> 2270144
static const size_t OFF_BOX      = 2270144;  // 8*4741*4*4 -> 2876992
static const size_t OFF_SCORE    = 2876992;  // 8*4741*4   -> 3028704
static const size_t OFF_VALID    = 3028704;  // 8*4741*4   -> 3180416
static const size_t OFF_MASK     = 3180416;  // 8*5*16*1024*8 -> 8423296
static const size_t OFF_OUTK     = 8423296;  // 8*4741*8   -> 8726720

// monotone float<->uint map: fmap ascending in float value
__device__ __forceinline__ u32 fmap(float f){
  u32 b = __float_as_uint(f);
  return (b & 0x80000000u) ? ~b : (b | 0x80000000u);
}
__device__ __forceinline__ float funmap(u32 m){
  return __uint_as_float((m & 0x80000000u) ? (m & 0x7FFFFFFFu) : ~m);
}

template<int N, int T>
__device__ __forceinline__ void bitonic_sort(u64* d, int tid){
  for (int k = 2; k <= N; k <<= 1){
    for (int j = k >> 1; j > 0; j >>= 1){
      __syncthreads();
      #pragma unroll 1
      for (int i = tid; i < N; i += T){
        int ixj = i ^ j;
        if (ixj > i){
          u64 a = d[i], b = d[ixj];
          bool sw = ((i & k) == 0) ? (a > b) : (a < b);
          if (sw){ d[i] = b; d[ixj] = a; }
        }
      }
    }
  }
  __syncthreads();
}

// block -> (b, level, segment) mapping for 16K-element scan segments:
// 18 blocks/image (12 for l0, 3 for l1, 1 each l2..l4)
__device__ __forceinline__ void seg_map(int blk, int& b, int& l, int& start, int& cnt){
  b = blk / 18; int s = blk % 18;
  if (s < 12)      { l = 0; start = s * 16384; }
  else if (s < 15) { l = 1; start = (s - 12) * 16384; }
  else             { l = s - 13; start = 0; }   // 15->l2, 16->l3, 17->l4
  int n = c_LN[l];
  cnt = n - start; if (cnt > 16384) cnt = 16384;
}

// ---------- K1a: per-(b,l) 2048-bin histogram of key-high-11-bits ----------
__global__ void __launch_bounds__(1024)
k_hist(const float* __restrict__ obj, u32* __restrict__ hist)
{
  int b, l, start, cnt; seg_map(blockIdx.x, b, l, start, cnt);
  int bl = b * 5 + l;
  __shared__ u32 h[2048];
  for (int i = threadIdx.x; i < 2048; i += 1024) h[i] = 0;
  __syncthreads();
  const float* p = obj + (size_t)b * A_TOTAL + c_LOFF[l] + start;
  for (int i = threadIdx.x; i < cnt; i += 1024){
    u32 m = ~fmap(p[i]);           // ascending m == descending objectness
    atomicAdd(&h[m >> 21], 1u);
  }
  __syncthreads();
  for (int i = threadIdx.x; i < 2048; i += 1024){
    u32 v = h[i];
    if (v) atomicAdd(&hist[bl * 2048 + i], v);
  }
}

// ---------- K1b: find cutoff bin t and count_less ----------
__global__ void __launch_bounds__(256)
k_cutoff(const u32* __restrict__ hist, u32* __restrict__ tbin, u32* __restrict__ cless)
{
  int bl = blockIdx.x; int l = bl % 5;
  int K = c_LK[l], n = c_LN[l];
  int tid = threadIdx.x;
  if (K >= n){ if (tid == 0){ tbin[bl] = 2048u; cless[bl] = (u32)n; } return; }
  __shared__ u32 cum[2048];
  __shared__ u32 part[256];
  __shared__ int s_t;
  u32 vals[8]; u32 sum = 0;
  for (int q = 0; q < 8; ++q){ vals[q] = hist[bl * 2048 + tid * 8 + q]; sum += vals[q]; }
  part[tid] = sum;
  __syncthreads();
  for (int off = 1; off < 256; off <<= 1){
    u32 add = (tid >= off) ? part[tid - off] : 0u;
    __syncthreads();
    part[tid] += add;
    __syncthreads();
  }
  u32 run = (tid > 0) ? part[tid - 1] : 0u;
  for (int q = 0; q < 8; ++q){ run += vals[q]; cum[tid * 8 + q] = run; }
  if (tid == 0) s_t = 0;
  __syncthreads();
  for (int q = 0; q < 8; ++q){
    int i = tid * 8 + q;
    u32 c = cum[i], cp = (i > 0) ? cum[i - 1] : 0u;
    if (c >= (u32)K && cp < (u32)K) s_t = i;
  }
  __syncthreads();
  if (tid == 0){
    int t = s_t;
    tbin[bl] = (u32)t;
    cless[bl] = (t > 0) ? cum[t - 1] : 0u;
  }
}

// ---------- K1c: collect selected + boundary-bin candidates ----------
__global__ void __launch_bounds__(1024)
k_collect(const float* __restrict__ obj, const u32* __restrict__ tbin,
          u32* __restrict__ selcnt, u32* __restrict__ candcnt,
          u64* __restrict__ selg, u64* __restrict__ candg)
{
  int b, l, start, cnt; seg_map(blockIdx.x, b, l, start, cnt);
  int bl = b * 5 + l;
  u32 t = tbin[bl];
  const float* p = obj + (size_t)b * A_TOTAL + c_LOFF[l] + start;
  for (int i = threadIdx.x; i < cnt; i += 1024){
    u32 m = ~fmap(p[i]);
    u32 bin = m >> 21;
    u64 key = ((u64)m << 32) | (u32)(start + i);
    if (bin < t){
      u32 pos = atomicAdd(&selcnt[bl], 1u);
      selg[(size_t)bl * 1024 + pos] = key;
    } else if (bin == t){
      u32 pos = atomicAdd(&candcnt[bl], 1u);
      if (pos < 4096u) candg[(size_t)bl * 4096 + pos] = key;
    }
  }
}

// ---------- K1d: assemble exact top-K and sort descending-by-obj ----------
__global__ void __launch_bounds__(1024)
k_select(const u32* __restrict__ selcnt, const u32* __restrict__ candcnt,
         const u64* __restrict__ selg, const u64* __restrict__ candg,
         u64* __restrict__ keys)
{
  int bl = blockIdx.x; int b = bl / 5, l = bl % 5;
  int K = c_LK[l];
  int tid = threadIdx.x;
  __shared__ u64 cand[4096];
  __shared__ u64 sel[1024];
  u32 nc = candcnt[bl]; if (nc > 4096u) nc = 4096u;
  u32 ns = selcnt[bl];
  int R = K - (int)ns;
  for (int i = tid; i < 4096; i += 1024) cand[i] = (i < (int)nc) ? candg[(size_t)bl * 4096 + i] : ~0ULL;
  sel[tid] = ~0ULL;
  __syncthreads();
  if (R > 0){
    bitonic_sort<4096, 1024>(cand, tid);
  }
  for (int i = tid; i < (int)ns; i += 1024) sel[i] = selg[(size_t)bl * 1024 + i];
  for (int i = tid; i < R; i += 1024) sel[(int)ns + i] = cand[i];
  bitonic_sort<1024, 1024>(sel, tid);
  for (int i = tid; i < K; i += 1024) keys[(size_t)b * KTOT + l * 1000 + i] = sel[i];
}

// ---------- K2: gather + decode + clip + sigmoid + validity ----------
__global__ void __launch_bounds__(256)
k_decode(const u64* __restrict__ keys, const float* __restrict__ deltas,
         const float* __restrict__ anchors, float* __restrict__ boxes,
         float* __restrict__ scores, u32* __restrict__ valid)
{
  int g = blockIdx.x * 256 + threadIdx.x;
  if (g >= 8 * KTOT) return;
  int b = g / KTOT, kpos = g % KTOT;
  int l = kpos / 1000; if (l > 4) l = 4;
  u64 key = keys[g];
  u32 idx = (u32)key;
  float o = funmap(~(u32)(key >> 32));
  int ai = c_LOFF[l] + (int)idx;
  const float* a = anchors + (size_t)ai * 4;
  const float* d = deltas + ((size_t)b * A_TOTAL + ai) * 4;
  float a0 = a[0], a1 = a[1], a2 = a[2], a3 = a[3];
  float wa = __fsub_rn(a2, a0), ha = __fsub_rn(a3, a1);
  float cxa = __fadd_rn(a0, __fmul_rn(0.5f, wa));
  float cya = __fadd_rn(a1, __fmul_rn(0.5f, ha));
  float dx = d[0], dy = d[1];
  float dw = fminf(d[2], 4.135166556742356f);   // log(1000/16)
  float dh = fminf(d[3], 4.135166556742356f);
  float cx = __fadd_rn(__fmul_rn(dx, wa), cxa);
  float cy = __fadd_rn(__fmul_rn(dy, ha), cya);
  float w  = __fmul_rn(expf(dw), wa);
  float h  = __fmul_rn(expf(dh), ha);
  float hw = __fmul_rn(0.5f, w), hh = __fmul_rn(0.5f, h);
  float x1 = __fsub_rn(cx, hw), y1 = __fsub_rn(cy, hh);
  float x2 = __fadd_rn(cx, hw), y2 = __fadd_rn(cy, hh);
  x1 = fminf(fmaxf(x1, 0.0f), 1216.0f);
  x2 = fminf(fmaxf(x2, 0.0f), 1216.0f);
  y1 = fminf(fmaxf(y1, 0.0f), 800.0f);
  y2 = fminf(fmaxf(y2, 0.0f), 800.0f);
  float s = __fdiv_rn(1.0f, __fadd_rn(1.0f, expf(-o)));
  int v = (__fsub_rn(x2, x1) >= 0.001f) && (__fsub_rn(y2, y1) >= 0.001f) && (s >= 0.0f);
  float* bo = boxes + (size_t)g * 4;
  bo[0] = x1; bo[1] = y1; bo[2] = x2; bo[3] = y2;
  scores[g] = s;
  valid[g] = (u32)v;
}

// ---------- K3: per-level suppression bitmask, 256x256 upper-tri tiles ----------
__global__ void __launch_bounds__(256)
k_mask(const float* __restrict__ boxes, u64* __restrict__ mask)
{
  int b = blockIdx.x / 46, s = blockIdx.x % 46;
  int l = c_TL[s], it = c_TI[s], jt = c_TJ[s];
  int N = c_LK[l];
  int koff = l * 1000;
  float offv = (float)(l * 4096);   // exact
  __shared__ float4 sxy[256];
  __shared__ float  sar[256];
  int j0 = jt * 256;
  {
    int tj = j0 + (int)threadIdx.x;
    float4 q; float ar;
    if (tj < N){
      float4 p = ((const float4*)boxes)[(size_t)(b * KTOT + koff + tj)];
      q.x = __fadd_rn(p.x, offv); q.y = __fadd_rn(p.y, offv);
      q.z = __fadd_rn(p.z, offv); q.w = __fadd_rn(p.w, offv);
      ar = __fmul_rn(__fsub_rn(q.z, q.x), __fsub_rn(q.w, q.y));
    } else {
      q.x = 3e38f; q.y = 3e38f; q.z = -3e38f; q.w = -3e38f; ar = 0.f;
    }
    sxy[threadIdx.x] = q; sar[threadIdx.x] = ar;
  }
  __syncthreads();
  int i = it * 256 + (int)threadIdx.x;
  if (i >= N) return;
  float4 p = ((const float4*)boxes)[(size_t)(b * KTOT + koff + i)];
  float bx1 = __fadd_rn(p.x, offv), by1 = __fadd_rn(p.y, offv);
  float bx2 = __fadd_rn(p.z, offv), by2 = __fadd_rn(p.w, offv);
  float bar = __fmul_rn(__fsub_rn(bx2, bx1), __fsub_rn(by2, by1));
  u64* mb = mask + ((size_t)(b * 5 + l) * 16) * 1024;
  for (int w = 0; w < 4; ++w){
    int jbase = j0 + w * 64;
    if (jbase >= N) break;
    u64 bw = 0;
    #pragma unroll 16
    for (int jj = 0; jj < 64; ++jj){
      int j = jbase + jj;
      float4 q = sxy[w * 64 + jj];
      float aj = sar[w * 64 + jj];
      float ltx = fmaxf(bx1, q.x), lty = fmaxf(by1, q.y);
      float rbx = fminf(bx2, q.z), rby = fminf(by2, q.w);
      float wx = fmaxf(__fsub_rn(rbx, ltx), 0.0f);
      float wy = fmaxf(__fsub_rn(rby, lty), 0.0f);
      float inter = __fmul_rn(wx, wy);
      bool sup = false;
      if (inter > 0.0f && j > i){
        float den = __fsub_rn(__fadd_rn(bar, aj), inter);
        sup = __fdiv_rn(inter, den) > 0.7f;
      }
      bw |= ((u64)sup) << jj;
    }
    mb[(size_t)(jbase >> 6) * 1024 + i] = bw;
  }
}

// ---------- K4: exact greedy NMS, sparse-conflict fast path ----------
// Cross-word suppression (supl) is computed in parallel via the jb-loop as before.
// In-word greedy: conflicts are rare for scattered top-k boxes, so each word first
// checks (via a conf/src reduce fused into the supl reduce) whether ANY candidate
// suppresses another candidate in-word; if not, kept = cur with ZERO serial
// iterations. Otherwise a serial loop runs over only the conflict-involved bits
// (act), which is exact: inert bits neither suppress nor get suppressed in-word.
__global__ void __launch_bounds__(256)
k_nms(const u64* __restrict__ mask, const u32* __restrict__ valid,
      const float* __restrict__ scores, u64* __restrict__ outk)
{
  int bl = blockIdx.x; int b = bl / 5, l = bl % 5;
  int N = c_LK[l], koff = l * 1000;
  int WN = (N + 63) >> 6;           // 16 (levels 0-3) or 12 (level 4)
  int tid = threadIdx.x;
  __shared__ u64 s_kw[16];
  __shared__ u64 s_m[7680];         // 60 KiB: word w at 64*w*(w+1)/2, rows <(w+1)*64
  const u64* mb = mask + (size_t)bl * 16 * 1024;
  int wstage = (WN < 15) ? WN : 15;
  for (int w = 0; w < wstage; ++w){
    int rows = (w + 1) * 64;
    int base = 32 * w * (w + 1);    // = 64*w*(w+1)/2
    for (int r = tid; r < rows; r += 256)
      s_m[base + r] = mb[(size_t)w * 1024 + r];
  }
  __syncthreads();
  if (tid < 64){
    int lane = tid;
    // keep init = valid
    for (int c = 0; c < WN; ++c){
      int i = c * 64 + lane;
      int pred = (i < N) && (valid[(size_t)b * KTOT + koff + i] != 0u);
      u64 bal = __ballot(pred);
      if (lane == 0) s_kw[c] = bal;
    }
    for (int w = 0; w < WN; ++w){
      u64 kwv = s_kw[w];            // broadcast read (uniform)
      // cross-word suppression of word w's columns from finalized kept rows
      u64 supl = 0;
      if (w < 15){
        int base = 32 * w * (w + 1);
        for (int jb = 0; jb < w; ++jb){
          u64 kb = s_kw[jb];
          u64 m = s_m[base + jb * 64 + lane];            // unconditional ds_read
          supl |= (((kb >> lane) & 1ULL) ? m : 0ULL);
        }
      } else {
        for (int jb = 0; jb < w; ++jb){
          u64 kb = s_kw[jb];
          u64 m = mb[(size_t)w * 1024 + jb * 64 + lane]; // unconditional global
          supl |= (((kb >> lane) & 1ULL) ? m : 0ULL);
        }
      }
      // in-word rows (lane r owns row w*64+r's word-w column bits)
      int jr = w * 64 + lane;
      u64 rowl;
      if (w < 15) rowl = s_m[32 * w * (w + 1) + jr];     // diagonal rows staged
      else        rowl = (jr < N) ? mb[(size_t)w * 1024 + jr] : 0ULL;
      // per-lane in-word conflict contribution (candidates only)
      bool inC = ((kwv >> lane) & 1ULL) != 0ULL;
      u64 rkw = rowl & kwv;
      u64 confl = inC ? rkw : 0ULL;
      // fused OR-reduce of (supl, conf) across 64 lanes
      u32 a0 = (u32)supl, a1 = (u32)(supl >> 32);
      u32 a2 = (u32)confl, a3 = (u32)(confl >> 32);
      for (int off = 32; off; off >>= 1){
        a0 |= __shfl_xor(a0, off);
        a1 |= __shfl_xor(a1, off);
        a2 |= __shfl_xor(a2, off);
        a3 |= __shfl_xor(a3, off);
      }
      supl = ((u64)a1 << 32) | a0;
      u64 conf = ((u64)a3 << 32) | a2;          // union of in-word targets
      u64 srcb = __ballot(inC && (rkw != 0ULL)); // in-word source lanes
      u64 cur = kwv & ~supl;
      u64 kept = cur;
      if (((srcb & cur) != 0ULL) && ((conf & cur) != 0ULL)){
        // serial greedy over conflict-involved bits only
        u32 rowl_lo = (u32)rowl, rowl_hi = (u32)(rowl >> 32);
        u64 act = cur & (srcb | conf);
        while (act){
          int ib  = __ffsll((unsigned long long)act) - 1;  // wave-uniform
          int ibs = __builtin_amdgcn_readfirstlane(ib);
          u64 bit = 1ULL << ibs;
          act &= ~bit;
          if (kept & bit){
            u32 rlo = (u32)__builtin_amdgcn_readlane((int)rowl_lo, ibs);
            u32 rhi = (u32)__builtin_amdgcn_readlane((int)rowl_hi, ibs);
            u64 r   = ((u64)rhi << 32) | rlo;
            kept &= ~r;
            act  &= ~r;
          }
        }
      }
      if (lane == 0) s_kw[w] = kept;
    }
  }
  __syncthreads();
  // emit final-merge keys: (~fmap(score))<<32 | concat_pos ; suppressed -> ~0
  for (int i = tid; i < N; i += 256){
    u64 key = ~0ULL;
    if ((s_kw[i >> 6] >> (i & 63)) & 1ULL){
      float sc = scores[(size_t)b * KTOT + koff + i];
      key = ((u64)(~fmap(sc)) << 32) | (u32)(koff + i);
    }
    outk[(size_t)b * KTOT + koff + i] = key;
  }
}

// ---------- K5: rank-by-counting final selection ----------
#define KPAD 4744   // KTOT rounded up to multiple of 4; pad keys = ~0ULL (add 0 to ranks)
__global__ void __launch_bounds__(256)
k_rank(const u64* __restrict__ outk, const float* __restrict__ boxes,
       float* __restrict__ out)
{
  int b = blockIdx.x / 19, chunk = blockIdx.x % 19;
  int tid = threadIdx.x;
  __shared__ u64 sk[KPAD];
  for (int i = tid; i < KPAD; i += 256)
    sk[i] = (i < KTOT) ? outk[(size_t)b * KTOT + i] : ~0ULL;
  __syncthreads();
  int i = chunk * 256 + tid;
  if (i >= KTOT) return;
  u64 key = sk[i];
  if (key == ~0ULL) return;     // suppressed / invalid
  int rank = 0;
  #pragma unroll 4
  for (int j = 0; j < KPAD; j += 2){
    ulonglong2 v = *reinterpret_cast<const ulonglong2*>(&sk[j]);  // LDS broadcast
    rank += (v.x < key) + (v.y < key);
  }
  if (rank < 1000){
    float4 bx = ((const float4*)boxes)[(size_t)(b * KTOT + i)];
    ((float4*)out)[(size_t)(b * 1000 + rank)] = bx;
    out[32000 + b * 1000 + rank] = funmap(~(u32)(key >> 32));
  }
}

extern "C" void kernel_launch(void* const* d_in, const int* in_sizes, int n_in,
                              void* d_out, int out_size, void* d_ws, size_t ws_size,
                              hipStream_t stream)
{
  (void)in_sizes; (void)n_in; (void)ws_size; // needs ~8.73 MB ws
  const float* obj     = (const float*)d_in[0];
  const float* deltas  = (const float*)d_in[1];
  const float* anchors = (const float*)d_in[2];
  float* out = (float*)d_out;
  char* ws = (char*)d_ws;

  u32* hist    = (u32*)(ws + OFF_HIST);
  u32* selcnt  = (u32*)(ws + OFF_SELCNT);
  u32* candcnt = (u32*)(ws + OFF_CANDCNT);
  u32* tbin    = (u32*)(ws + OFF_TBIN);
  u32* cless   = (u32*)(ws + OFF_CLESS);
  u64* selg    = (u64*)(ws + OFF_SELG);
  u64* candg   = (u64*)(ws + OFF_CANDG);
  u64* keys    = (u64*)(ws + OFF_KEYS);
  float* boxes = (float*)(ws + OFF_BOX);
  float* score = (float*)(ws + OFF_SCORE);
  u32* valid   = (u32*)(ws + OFF_VALID);
  u64* mask    = (u64*)(ws + OFF_MASK);
  u64* outk    = (u64*)(ws + OFF_OUTK);

  hipMemsetAsync(ws, 0, MEMSET_BYTES, stream);
  hipMemsetAsync(d_out, 0, (size_t)out_size * sizeof(float), stream);
  hipLaunchKernelGGL(k_hist,    dim3(144), dim3(1024), 0, stream, obj, hist);
  hipLaunchKernelGGL(k_cutoff,  dim3(40),  dim3(256),  0, stream, hist, tbin, cless);
  hipLaunchKernelGGL(k_collect, dim3(144), dim3(1024), 0, stream, obj, tbin, selcnt, candcnt, selg, candg);
  hipLaunchKernelGGL(k_select,  dim3(40),  dim3(1024), 0, stream, selcnt, candcnt, selg, candg, keys);
  hipLaunchKernelGGL(k_decode,  dim3(149), dim3(256),  0, stream, keys, deltas, anchors, boxes, score, valid);
  hipLaunchKernelGGL(k_mask,    dim3(368), dim3(256),  0, stream, boxes, mask);
  hipLaunchKernelGGL(k_nms,     dim3(40),  dim3(256),  0, stream, mask, valid, score, outk);
  hipLaunchKernelGGL(k_rank,    dim3(152), dim3(256),  0, stream, outk, boxes, out);
}

// Round 10
// 247.817 us; speedup vs baseline: 2.2894x; 1.2166x over previous
//
#include <hip/hip_runtime.h>
#include <stdint.h>

#pragma clang fp contract(off)

typedef unsigned int u32;
typedef unsigned long long u64;

#define A_TOTAL 242991
#define KTOT    4741

// level tables
__constant__ int c_LN[5]   = {182400, 45600, 11400, 2850, 741};
__constant__ int c_LOFF[5] = {0, 182400, 228000, 239400, 242250};
__constant__ int c_LK[5]   = {1000, 1000, 1000, 1000, 741};

// k_mask tile tables: 46 upper-triangle (it<=jt) tiles per image
__constant__ int c_TL[46] = {0,0,0,0,0,0,0,0,0,0, 1,1,1,1,1,1,1,1,1,1,
                             2,2,2,2,2,2,2,2,2,2, 3,3,3,3,3,3,3,3,3,3,
                             4,4,4,4,4,4};
__constant__ int c_TI[46] = {0,0,0,0,1,1,1,2,2,3, 0,0,0,0,1,1,1,2,2,3,
                             0,0,0,0,1,1,1,2,2,3, 0,0,0,0,1,1,1,2,2,3,
                             0,0,0,1,1,2};
__constant__ int c_TJ[46] = {0,1,2,3,1,2,3,2,3,3, 0,1,2,3,1,2,3,2,3,3,
                             0,1,2,3,1,2,3,2,3,3, 0,1,2,3,1,2,3,2,3,3,
                             0,1,2,1,2,2};

// workspace byte offsets (total ~8.73 MB)
// keepw (40*16*8 = 5120 B) ALIASES the hist region: hist is dead after k_cutoff,
// and k_nms (writer) runs strictly before k_rank (reader) every launch.
static const size_t OFF_KEEPW    = 0;
static const size_t OFF_HIST     = 0;        // 40*2048*4 = 327680
static const size_t OFF_SELCNT   = 327680;   // 40*4
static const size_t OFF_CANDCNT  = 327840;   // 40*4
static const size_t MEMSET_BYTES = 328000;
static const size_t OFF_TBIN     = 328000;   // 40*4
static const size_t OFF_CLESS    = 328160;   // 40*4
static const size_t OFF_SELG     = 328320;   // 40*1024*8  -> 656000
static const size_t OFF_CANDG    = 656000;   // 40*4096*8  -> 1966720
static const size_t OFF_KEYS     = 1966720;  // 8*4741*8   -> 2270144
static const size_t OFF_BOX      = 2270144;  // 8*4741*4*4 -> 2876992
static const size_t OFF_SCORE    = 2876992;  // 8*4741*4   -> 3028704
static const size_t OFF_VALID    = 3028704;  // 8*4741*4   -> 3180416
static const size_t OFF_MASK     = 3180416;  // 8*5*16*1024*8 -> 8423296
static const size_t OFF_OUTK     = 8423296;  // 8*4741*8   -> 8726720

// monotone float<->uint map: fmap ascending in float value
__device__ __forceinline__ u32 fmap(float f){
  u32 b = __float_as_uint(f);
  return (b & 0x80000000u) ? ~b : (b | 0x80000000u);
}
__device__ __forceinline__ float funmap(u32 m){
  return __uint_as_float((m & 0x80000000u) ? (m & 0x7FFFFFFFu) : ~m);
}

template<int N, int T>
__device__ __forceinline__ void bitonic_sort(u64* d, int tid){
  for (int k = 2; k <= N; k <<= 1){
    for (int j = k >> 1; j > 0; j >>= 1){
      __syncthreads();
      #pragma unroll 1
      for (int i = tid; i < N; i += T){
        int ixj = i ^ j;
        if (ixj > i){
          u64 a = d[i], b = d[ixj];
          bool sw = ((i & k) == 0) ? (a > b) : (a < b);
          if (sw){ d[i] = b; d[ixj] = a; }
        }
      }
    }
  }
  __syncthreads();
}

// block -> (b, level, segment) mapping for 16K-element scan segments:
// 18 blocks/image (12 for l0, 3 for l1, 1 each l2..l4)
__device__ __forceinline__ void seg_map(int blk, int& b, int& l, int& start, int& cnt){
  b = blk / 18; int s = blk % 18;
  if (s < 12)      { l = 0; start = s * 16384; }
  else if (s < 15) { l = 1; start = (s - 12) * 16384; }
  else             { l = s - 13; start = 0; }   // 15->l2, 16->l3, 17->l4
  int n = c_LN[l];
  cnt = n - start; if (cnt > 16384) cnt = 16384;
}

// ---------- K1a: per-(b,l) 2048-bin histogram of key-high-11-bits ----------
__global__ void __launch_bounds__(1024)
k_hist(const float* __restrict__ obj, u32* __restrict__ hist)
{
  int b, l, start, cnt; seg_map(blockIdx.x, b, l, start, cnt);
  int bl = b * 5 + l;
  __shared__ u32 h[2048];
  for (int i = threadIdx.x; i < 2048; i += 1024) h[i] = 0;
  __syncthreads();
  const float* p = obj + (size_t)b * A_TOTAL + c_LOFF[l] + start;
  for (int i = threadIdx.x; i < cnt; i += 1024){
    u32 m = ~fmap(p[i]);           // ascending m == descending objectness
    atomicAdd(&h[m >> 21], 1u);
  }
  __syncthreads();
  for (int i = threadIdx.x; i < 2048; i += 1024){
    u32 v = h[i];
    if (v) atomicAdd(&hist[bl * 2048 + i], v);
  }
}

// ---------- K1b: find cutoff bin t and count_less ----------
__global__ void __launch_bounds__(256)
k_cutoff(const u32* __restrict__ hist, u32* __restrict__ tbin, u32* __restrict__ cless)
{
  int bl = blockIdx.x; int l = bl % 5;
  int K = c_LK[l], n = c_LN[l];
  int tid = threadIdx.x;
  if (K >= n){ if (tid == 0){ tbin[bl] = 2048u; cless[bl] = (u32)n; } return; }
  __shared__ u32 cum[2048];
  __shared__ u32 part[256];
  __shared__ int s_t;
  u32 vals[8]; u32 sum = 0;
  for (int q = 0; q < 8; ++q){ vals[q] = hist[bl * 2048 + tid * 8 + q]; sum += vals[q]; }
  part[tid] = sum;
  __syncthreads();
  for (int off = 1; off < 256; off <<= 1){
    u32 add = (tid >= off) ? part[tid - off] : 0u;
    __syncthreads();
    part[tid] += add;
    __syncthreads();
  }
  u32 run = (tid > 0) ? part[tid - 1] : 0u;
  for (int q = 0; q < 8; ++q){ run += vals[q]; cum[tid * 8 + q] = run; }
  if (tid == 0) s_t = 0;
  __syncthreads();
  for (int q = 0; q < 8; ++q){
    int i = tid * 8 + q;
    u32 c = cum[i], cp = (i > 0) ? cum[i - 1] : 0u;
    if (c >= (u32)K && cp < (u32)K) s_t = i;
  }
  __syncthreads();
  if (tid == 0){
    int t = s_t;
    tbin[bl] = (u32)t;
    cless[bl] = (t > 0) ? cum[t - 1] : 0u;
  }
}

// ---------- K1c: collect selected + boundary-bin candidates ----------
__global__ void __launch_bounds__(1024)
k_collect(const float* __restrict__ obj, const u32* __restrict__ tbin,
          u32* __restrict__ selcnt, u32* __restrict__ candcnt,
          u64* __restrict__ selg, u64* __restrict__ candg)
{
  int b, l, start, cnt; seg_map(blockIdx.x, b, l, start, cnt);
  int bl = b * 5 + l;
  u32 t = tbin[bl];
  const float* p = obj + (size_t)b * A_TOTAL + c_LOFF[l] + start;
  for (int i = threadIdx.x; i < cnt; i += 1024){
    u32 m = ~fmap(p[i]);
    u32 bin = m >> 21;
    u64 key = ((u64)m << 32) | (u32)(start + i);
    if (bin < t){
      u32 pos = atomicAdd(&selcnt[bl], 1u);
      selg[(size_t)bl * 1024 + pos] = key;
    } else if (bin == t){
      u32 pos = atomicAdd(&candcnt[bl], 1u);
      if (pos < 4096u) candg[(size_t)bl * 4096 + pos] = key;
    }
  }
}

// ---------- K1d: assemble exact top-K and sort descending-by-obj ----------
__global__ void __launch_bounds__(1024)
k_select(const u32* __restrict__ selcnt, const u32* __restrict__ candcnt,
         const u64* __restrict__ selg, const u64* __restrict__ candg,
         u64* __restrict__ keys)
{
  int bl = blockIdx.x; int b = bl / 5, l = bl % 5;
  int K = c_LK[l];
  int tid = threadIdx.x;
  __shared__ u64 cand[4096];
  __shared__ u64 sel[1024];
  u32 nc = candcnt[bl]; if (nc > 4096u) nc = 4096u;
  u32 ns = selcnt[bl];
  int R = K - (int)ns;
  for (int i = tid; i < 4096; i += 1024) cand[i] = (i < (int)nc) ? candg[(size_t)bl * 4096 + i] : ~0ULL;
  sel[tid] = ~0ULL;
  __syncthreads();
  if (R > 0){
    bitonic_sort<4096, 1024>(cand, tid);
  }
  for (int i = tid; i < (int)ns; i += 1024) sel[i] = selg[(size_t)bl * 1024 + i];
  for (int i = tid; i < R; i += 1024) sel[(int)ns + i] = cand[i];
  bitonic_sort<1024, 1024>(sel, tid);
  for (int i = tid; i < K; i += 1024) keys[(size_t)b * KTOT + l * 1000 + i] = sel[i];
}

// ---------- K2: gather + decode + clip + sigmoid + validity ----------
__global__ void __launch_bounds__(256)
k_decode(const u64* __restrict__ keys, const float* __restrict__ deltas,
         const float* __restrict__ anchors, float* __restrict__ boxes,
         float* __restrict__ scores, u32* __restrict__ valid)
{
  int g = blockIdx.x * 256 + threadIdx.x;
  if (g >= 8 * KTOT) return;
  int b = g / KTOT, kpos = g % KTOT;
  int l = kpos / 1000; if (l > 4) l = 4;
  u64 key = keys[g];
  u32 idx = (u32)key;
  float o = funmap(~(u32)(key >> 32));
  int ai = c_LOFF[l] + (int)idx;
  const float* a = anchors + (size_t)ai * 4;
  const float* d = deltas + ((size_t)b * A_TOTAL + ai) * 4;
  float a0 = a[0], a1 = a[1], a2 = a[2], a3 = a[3];
  float wa = __fsub_rn(a2, a0), ha = __fsub_rn(a3, a1);
  float cxa = __fadd_rn(a0, __fmul_rn(0.5f, wa));
  float cya = __fadd_rn(a1, __fmul_rn(0.5f, ha));
  float dx = d[0], dy = d[1];
  float dw = fminf(d[2], 4.135166556742356f);   // log(1000/16)
  float dh = fminf(d[3], 4.135166556742356f);
  float cx = __fadd_rn(__fmul_rn(dx, wa), cxa);
  float cy = __fadd_rn(__fmul_rn(dy, ha), cya);
  float w  = __fmul_rn(expf(dw), wa);
  float h  = __fmul_rn(expf(dh), ha);
  float hw = __fmul_rn(0.5f, w), hh = __fmul_rn(0.5f, h);
  float x1 = __fsub_rn(cx, hw), y1 = __fsub_rn(cy, hh);
  float x2 = __fadd_rn(cx, hw), y2 = __fadd_rn(cy, hh);
  x1 = fminf(fmaxf(x1, 0.0f), 1216.0f);
  x2 = fminf(fmaxf(x2, 0.0f), 1216.0f);
  y1 = fminf(fmaxf(y1, 0.0f), 800.0f);
  y2 = fminf(fmaxf(y2, 0.0f), 800.0f);
  float s = __fdiv_rn(1.0f, __fadd_rn(1.0f, expf(-o)));
  int v = (__fsub_rn(x2, x1) >= 0.001f) && (__fsub_rn(y2, y1) >= 0.001f) && (s >= 0.0f);
  float* bo = boxes + (size_t)g * 4;
  bo[0] = x1; bo[1] = y1; bo[2] = x2; bo[3] = y2;
  scores[g] = s;
  valid[g] = (u32)v;
}

// ---------- K3: per-level suppression bitmask, 256x256 upper-tri tiles ----------
__global__ void __launch_bounds__(256)
k_mask(const float* __restrict__ boxes, u64* __restrict__ mask)
{
  int b = blockIdx.x / 46, s = blockIdx.x % 46;
  int l = c_TL[s], it = c_TI[s], jt = c_TJ[s];
  int N = c_LK[l];
  int koff = l * 1000;
  float offv = (float)(l * 4096);   // exact
  __shared__ float4 sxy[256];
  __shared__ float  sar[256];
  int j0 = jt * 256;
  {
    int tj = j0 + (int)threadIdx.x;
    float4 q; float ar;
    if (tj < N){
      float4 p = ((const float4*)boxes)[(size_t)(b * KTOT + koff + tj)];
      q.x = __fadd_rn(p.x, offv); q.y = __fadd_rn(p.y, offv);
      q.z = __fadd_rn(p.z, offv); q.w = __fadd_rn(p.w, offv);
      ar = __fmul_rn(__fsub_rn(q.z, q.x), __fsub_rn(q.w, q.y));
    } else {
      q.x = 3e38f; q.y = 3e38f; q.z = -3e38f; q.w = -3e38f; ar = 0.f;
    }
    sxy[threadIdx.x] = q; sar[threadIdx.x] = ar;
  }
  __syncthreads();
  int i = it * 256 + (int)threadIdx.x;
  if (i >= N) return;
  float4 p = ((const float4*)boxes)[(size_t)(b * KTOT + koff + i)];
  float bx1 = __fadd_rn(p.x, offv), by1 = __fadd_rn(p.y, offv);
  float bx2 = __fadd_rn(p.z, offv), by2 = __fadd_rn(p.w, offv);
  float bar = __fmul_rn(__fsub_rn(bx2, bx1), __fsub_rn(by2, by1));
  u64* mb = mask + ((size_t)(b * 5 + l) * 16) * 1024;
  for (int w = 0; w < 4; ++w){
    int jbase = j0 + w * 64;
    if (jbase >= N) break;
    u64 bw = 0;
    #pragma unroll 16
    for (int jj = 0; jj < 64; ++jj){
      int j = jbase + jj;
      float4 q = sxy[w * 64 + jj];
      float aj = sar[w * 64 + jj];
      float ltx = fmaxf(bx1, q.x), lty = fmaxf(by1, q.y);
      float rbx = fminf(bx2, q.z), rby = fminf(by2, q.w);
      float wx = fmaxf(__fsub_rn(rbx, ltx), 0.0f);
      float wy = fmaxf(__fsub_rn(rby, lty), 0.0f);
      float inter = __fmul_rn(wx, wy);
      bool sup = false;
      if (inter > 0.0f && j > i){
        float den = __fsub_rn(__fadd_rn(bar, aj), inter);
        sup = __fdiv_rn(inter, den) > 0.7f;
      }
      bw |= ((u64)sup) << jj;
    }
    mb[(size_t)(jbase >> 6) * 1024 + i] = bw;
  }
}

// ---------- K4: exact greedy NMS, sparse-conflict fast path ----------
// Also exports the final keep bitmask words (keepw[bl][16]) for k_rank.
__global__ void __launch_bounds__(256)
k_nms(const u64* __restrict__ mask, const u32* __restrict__ valid,
      const float* __restrict__ scores, u64* __restrict__ outk,
      u64* __restrict__ keepw)
{
  int bl = blockIdx.x; int b = bl / 5, l = bl % 5;
  int N = c_LK[l], koff = l * 1000;
  int WN = (N + 63) >> 6;           // 16 (levels 0-3) or 12 (level 4)
  int tid = threadIdx.x;
  __shared__ u64 s_kw[16];
  __shared__ u64 s_m[7680];         // 60 KiB: word w at 64*w*(w+1)/2, rows <(w+1)*64
  const u64* mb = mask + (size_t)bl * 16 * 1024;
  int wstage = (WN < 15) ? WN : 15;
  for (int w = 0; w < wstage; ++w){
    int rows = (w + 1) * 64;
    int base = 32 * w * (w + 1);    // = 64*w*(w+1)/2
    for (int r = tid; r < rows; r += 256)
      s_m[base + r] = mb[(size_t)w * 1024 + r];
  }
  __syncthreads();
  if (tid < 64){
    int lane = tid;
    // keep init = valid
    for (int c = 0; c < WN; ++c){
      int i = c * 64 + lane;
      int pred = (i < N) && (valid[(size_t)b * KTOT + koff + i] != 0u);
      u64 bal = __ballot(pred);
      if (lane == 0) s_kw[c] = bal;
    }
    for (int w = 0; w < WN; ++w){
      u64 kwv = s_kw[w];            // broadcast read (uniform)
      // cross-word suppression of word w's columns from finalized kept rows
      u64 supl = 0;
      if (w < 15){
        int base = 32 * w * (w + 1);
        for (int jb = 0; jb < w; ++jb){
          u64 kb = s_kw[jb];
          u64 m = s_m[base + jb * 64 + lane];            // unconditional ds_read
          supl |= (((kb >> lane) & 1ULL) ? m : 0ULL);
        }
      } else {
        for (int jb = 0; jb < w; ++jb){
          u64 kb = s_kw[jb];
          u64 m = mb[(size_t)w * 1024 + jb * 64 + lane]; // unconditional global
          supl |= (((kb >> lane) & 1ULL) ? m : 0ULL);
        }
      }
      // in-word rows (lane r owns row w*64+r's word-w column bits)
      int jr = w * 64 + lane;
      u64 rowl;
      if (w < 15) rowl = s_m[32 * w * (w + 1) + jr];     // diagonal rows staged
      else        rowl = (jr < N) ? mb[(size_t)w * 1024 + jr] : 0ULL;
      // per-lane in-word conflict contribution (candidates only)
      bool inC = ((kwv >> lane) & 1ULL) != 0ULL;
      u64 rkw = rowl & kwv;
      u64 confl = inC ? rkw : 0ULL;
      // fused OR-reduce of (supl, conf) across 64 lanes
      u32 a0 = (u32)supl, a1 = (u32)(supl >> 32);
      u32 a2 = (u32)confl, a3 = (u32)(confl >> 32);
      for (int off = 32; off; off >>= 1){
        a0 |= __shfl_xor(a0, off);
        a1 |= __shfl_xor(a1, off);
        a2 |= __shfl_xor(a2, off);
        a3 |= __shfl_xor(a3, off);
      }
      supl = ((u64)a1 << 32) | a0;
      u64 conf = ((u64)a3 << 32) | a2;          // union of in-word targets
      u64 srcb = __ballot(inC && (rkw != 0ULL)); // in-word source lanes
      u64 cur = kwv & ~supl;
      u64 kept = cur;
      if (((srcb & cur) != 0ULL) && ((conf & cur) != 0ULL)){
        // serial greedy over conflict-involved bits only
        u32 rowl_lo = (u32)rowl, rowl_hi = (u32)(rowl >> 32);
        u64 act = cur & (srcb | conf);
        while (act){
          int ib  = __ffsll((unsigned long long)act) - 1;  // wave-uniform
          int ibs = __builtin_amdgcn_readfirstlane(ib);
          u64 bit = 1ULL << ibs;
          act &= ~bit;
          if (kept & bit){
            u32 rlo = (u32)__builtin_amdgcn_readlane((int)rowl_lo, ibs);
            u32 rhi = (u32)__builtin_amdgcn_readlane((int)rowl_hi, ibs);
            u64 r   = ((u64)rhi << 32) | rlo;
            kept &= ~r;
            act  &= ~r;
          }
        }
      }
      if (lane == 0) s_kw[w] = kept;
    }
  }
  __syncthreads();
  // export keep words (zero beyond WN so popcounts are exact)
  if (tid < 16) keepw[(size_t)bl * 16 + tid] = (tid < WN) ? s_kw[tid] : 0ULL;
  // emit final-merge keys: (~fmap(score))<<32 | concat_pos ; suppressed -> ~0
  for (int i = tid; i < N; i += 256){
    u64 key = ~0ULL;
    if ((s_kw[i >> 6] >> (i & 63)) & 1ULL){
      float sc = scores[(size_t)b * KTOT + koff + i];
      key = ((u64)(~fmap(sc)) << 32) | (u32)(koff + i);
    }
    outk[(size_t)b * KTOT + koff + i] = key;
  }
}

// ---------- K5: 5-way merge-rank final selection (O(K log K)) ----------
// Within each level, kept keys at increasing index are strictly increasing
// (index order = (obj desc, idx asc); sigmoid monotone; ties -> concat-pos order).
// So: own-level rank = popcount prefix of the keep bitmask; cross-level count-less
// = branchless lower_bound on that level's compacted (sorted) kept list.
// rank(i) = own_rank + sum over other levels. Exact: all keys distinct.
#define CMPN 1024   // per-level compacted list, padded with ~0ULL (kept count <= 1000)
__global__ void __launch_bounds__(256)
k_rank(const u64* __restrict__ outk, const u64* __restrict__ keepw,
       const float* __restrict__ boxes, float* __restrict__ out)
{
  int b = blockIdx.x / 19, chunk = blockIdx.x % 19;
  int tid = threadIdx.x;
  __shared__ u64 cmp[5 * CMPN];   // 40 KiB
  __shared__ u64 kw[80];          // keep words for this image's 5 levels
  for (int i = tid; i < 5 * CMPN; i += 256) cmp[i] = ~0ULL;
  if (tid < 80) kw[tid] = keepw[(size_t)b * 80 + tid];
  __syncthreads();
  // scatter-compact kept keys per level (rank via popcount prefix; no atomics)
  for (int i = tid; i < KTOT; i += 256){
    u64 key = outk[(size_t)b * KTOT + i];
    if (key != ~0ULL){
      int l = i / 1000; if (l > 4) l = 4;
      int li = i - l * 1000;
      int wi = li >> 6, bit = li & 63;
      const u64* kwl = &kw[l * 16];
      int r = __popcll(kwl[wi] & ((1ULL << bit) - 1ULL));
      for (int w = 0; w < wi; ++w) r += __popcll(kwl[w]);
      cmp[l * CMPN + r] = key;
    }
  }
  __syncthreads();
  int i = chunk * 256 + tid;
  if (i >= KTOT) return;
  u64 key = outk[(size_t)b * KTOT + i];
  if (key == ~0ULL) return;     // suppressed / invalid
  int l = i / 1000; if (l > 4) l = 4;
  int li = i - l * 1000;
  int wi = li >> 6, bit = li & 63;
  const u64* kwl = &kw[l * 16];
  int rank = __popcll(kwl[wi] & ((1ULL << bit) - 1ULL));
  for (int w = 0; w < wi; ++w) rank += __popcll(kwl[w]);
  #pragma unroll
  for (int lo = 0; lo < 5; ++lo){
    if (lo == l) continue;
    int pos = 0;
    #pragma unroll
    for (int s = 512; s > 0; s >>= 1)
      if (cmp[lo * CMPN + pos + s - 1] < key) pos += s;
    rank += pos;   // count of kept keys in level lo that are < key
  }
  if (rank < 1000){
    float4 bx = ((const float4*)boxes)[(size_t)(b * KTOT + i)];
    ((float4*)out)[(size_t)(b * 1000 + rank)] = bx;
    out[32000 + b * 1000 + rank] = funmap(~(u32)(key >> 32));
  }
}

extern "C" void kernel_launch(void* const* d_in, const int* in_sizes, int n_in,
                              void* d_out, int out_size, void* d_ws, size_t ws_size,
                              hipStream_t stream)
{
  (void)in_sizes; (void)n_in; (void)ws_size; // needs ~8.73 MB ws
  const float* obj     = (const float*)d_in[0];
  const float* deltas  = (const float*)d_in[1];
  const float* anchors = (const float*)d_in[2];
  float* out = (float*)d_out;
  char* ws = (char*)d_ws;

  u32* hist    = (u32*)(ws + OFF_HIST);
  u64* keepw   = (u64*)(ws + OFF_KEEPW);   // aliases hist (dead by k_nms time)
  u32* selcnt  = (u32*)(ws + OFF_SELCNT);
  u32* candcnt = (u32*)(ws + OFF_CANDCNT);
  u32* tbin    = (u32*)(ws + OFF_TBIN);
  u32* cless   = (u32*)(ws + OFF_CLESS);
  u64* selg    = (u64*)(ws + OFF_SELG);
  u64* candg   = (u64*)(ws + OFF_CANDG);
  u64* keys    = (u64*)(ws + OFF_KEYS);
  float* boxes = (float*)(ws + OFF_BOX);
  float* score = (float*)(ws + OFF_SCORE);
  u32* valid   = (u32*)(ws + OFF_VALID);
  u64* mask    = (u64*)(ws + OFF_MASK);
  u64* outk    = (u64*)(ws + OFF_OUTK);

  hipMemsetAsync(ws, 0, MEMSET_BYTES, stream);
  hipMemsetAsync(d_out, 0, (size_t)out_size * sizeof(float), stream);
  hipLaunchKernelGGL(k_hist,    dim3(144), dim3(1024), 0, stream, obj, hist);
  hipLaunchKernelGGL(k_cutoff,  dim3(40),  dim3(256),  0, stream, hist, tbin, cless);
  hipLaunchKernelGGL(k_collect, dim3(144), dim3(1024), 0, stream, obj, tbin, selcnt, candcnt, selg, candg);
  hipLaunchKernelGGL(k_select,  dim3(40),  dim3(1024), 0, stream, selcnt, candcnt, selg, candg, keys);
  hipLaunchKernelGGL(k_decode,  dim3(149), dim3(256),  0, stream, keys, deltas, anchors, boxes, score, valid);
  hipLaunchKernelGGL(k_mask,    dim3(368), dim3(256),  0, stream, boxes, mask);
  hipLaunchKernelGGL(k_nms,     dim3(40),  dim3(256),  0, stream, mask, valid, score, outk, keepw);
  hipLaunchKernelGGL(k_rank,    dim3(152), dim3(256),  0, stream, outk, keepw, boxes, out);
}

// Round 11
// 245.090 us; speedup vs baseline: 2.3149x; 1.0111x over previous
//
#include <hip/hip_runtime.h>
#include <stdint.h>

#pragma clang fp contract(off)

typedef unsigned int u32;
typedef unsigned long long u64;

#define A_TOTAL 242991
#define KTOT    4741

// level tables
__constant__ int c_LN[5]   = {182400, 45600, 11400, 2850, 741};
__constant__ int c_LOFF[5] = {0, 182400, 228000, 239400, 242250};
__constant__ int c_LK[5]   = {1000, 1000, 1000, 1000, 741};

// scan segment tables: 33 segments/image of <=8192 elements (23 l0, 6 l1, 2 l2, 1 l3, 1 l4)
__constant__ int c_SL[33] = {0,0,0,0,0,0,0,0,0,0,0,0,0,0,0,0,0,0,0,0,0,0,0,
                             1,1,1,1,1,1, 2,2, 3, 4};
__constant__ int c_SS[33] = {0,8192,16384,24576,32768,40960,49152,57344,65536,
                             73728,81920,90112,98304,106496,114688,122880,131072,
                             139264,147456,155648,163840,172032,180224,
                             0,8192,16384,24576,32768,40960, 0,8192, 0, 0};

// k_mask tile tables: 46 upper-triangle (it<=jt) tiles per image
__constant__ int c_TL[46] = {0,0,0,0,0,0,0,0,0,0, 1,1,1,1,1,1,1,1,1,1,
                             2,2,2,2,2,2,2,2,2,2, 3,3,3,3,3,3,3,3,3,3,
                             4,4,4,4,4,4};
__constant__ int c_TI[46] = {0,0,0,0,1,1,1,2,2,3, 0,0,0,0,1,1,1,2,2,3,
                             0,0,0,0,1,1,1,2,2,3, 0,0,0,0,1,1,1,2,2,3,
                             0,0,0,1,1,2};
__constant__ int c_TJ[46] = {0,1,2,3,1,2,3,2,3,3, 0,1,2,3,1,2,3,2,3,3,
                             0,1,2,3,1,2,3,2,3,3, 0,1,2,3,1,2,3,2,3,3,
                             0,1,2,1,2,2};

// workspace byte offsets (total ~8.73 MB)
// keepw (40*16*8 = 5120 B) ALIASES the hist region: hist is dead after k_cutoff,
// and k_nms (writer) runs strictly before k_rank (reader) every launch.
static const size_t OFF_KEEPW    = 0;
static const size_t OFF_HIST     = 0;        // 40*2048*4 = 327680
static const size_t OFF_SELCNT   = 327680;   // 40*4
static const size_t OFF_CANDCNT  = 327840;   // 40*4
static const size_t MEMSET_BYTES = 328000;
static const size_t OFF_TBIN     = 328000;   // 40*4
static const size_t OFF_CLESS    = 328160;   // 40*4
static const size_t OFF_SELG     = 328320;   // 40*1024*8  -> 656000
static const size_t OFF_CANDG    = 656000;   // 40*4096*8  -> 1966720
static const size_t OFF_KEYS     = 1966720;  // 8*4741*8   -> 2270144
static const size_t OFF_BOX      = 2270144;  // 8*4741*4*4 -> 2876992
static const size_t OFF_SCORE    = 2876992;  // 8*4741*4   -> 3028704
static const size_t OFF_VALID    = 3028704;  // 8*4741*4   -> 3180416
static const size_t OFF_MASK     = 3180416;  // 8*5*16*1024*8 -> 8423296
static const size_t OFF_OUTK     = 8423296;  // 8*4741*8   -> 8726720

// monotone float<->uint map: fmap ascending in float value
__device__ __forceinline__ u32 fmap(float f){
  u32 b = __float_as_uint(f);
  return (b & 0x80000000u) ? ~b : (b | 0x80000000u);
}
__device__ __forceinline__ float funmap(u32 m){
  return __uint_as_float((m & 0x80000000u) ? (m & 0x7FFFFFFFu) : ~m);
}

template<int N, int T>
__device__ __forceinline__ void bitonic_sort(u64* d, int tid){
  for (int k = 2; k <= N; k <<= 1){
    for (int j = k >> 1; j > 0; j >>= 1){
      __syncthreads();
      #pragma unroll 1
      for (int i = tid; i < N; i += T){
        int ixj = i ^ j;
        if (ixj > i){
          u64 a = d[i], b = d[ixj];
          bool sw = ((i & k) == 0) ? (a > b) : (a < b);
          if (sw){ d[i] = b; d[ixj] = a; }
        }
      }
    }
  }
  __syncthreads();
}

// ---------- K1a: per-(b,l) 2048-bin histogram, float4-vectorized ----------
__global__ void __launch_bounds__(1024)
k_hist(const float* __restrict__ obj, u32* __restrict__ hist)
{
  int b = blockIdx.x / 33, s = blockIdx.x % 33;
  int l = c_SL[s], start = c_SS[s];
  int cnt = c_LN[l] - start; if (cnt > 8192) cnt = 8192;
  int bl = b * 5 + l;
  __shared__ u32 h[2048];
  for (int i = threadIdx.x; i < 2048; i += 1024) h[i] = 0;
  __syncthreads();
  const float* p = obj + (size_t)b * A_TOTAL + c_LOFF[l] + start;
  int head = (4 - (int)(((size_t)p >> 2) & 3)) & 3;
  if (head > cnt) head = cnt;
  if ((int)threadIdx.x < head) atomicAdd(&h[(~fmap(p[threadIdx.x])) >> 21], 1u);
  int nvec = (cnt - head) >> 2;
  const float4* pv = (const float4*)(p + head);
  for (int i = threadIdx.x; i < nvec; i += 1024){
    float4 v = pv[i];
    atomicAdd(&h[(~fmap(v.x)) >> 21], 1u);
    atomicAdd(&h[(~fmap(v.y)) >> 21], 1u);
    atomicAdd(&h[(~fmap(v.z)) >> 21], 1u);
    atomicAdd(&h[(~fmap(v.w)) >> 21], 1u);
  }
  int tail0 = head + (nvec << 2);
  int ntail = cnt - tail0;
  if ((int)threadIdx.x < ntail) atomicAdd(&h[(~fmap(p[tail0 + threadIdx.x])) >> 21], 1u);
  __syncthreads();
  for (int i = threadIdx.x; i < 2048; i += 1024){
    u32 v = h[i];
    if (v) atomicAdd(&hist[bl * 2048 + i], v);
  }
}

// ---------- K1b: find cutoff bin t and count_less ----------
__global__ void __launch_bounds__(256)
k_cutoff(const u32* __restrict__ hist, u32* __restrict__ tbin, u32* __restrict__ cless)
{
  int bl = blockIdx.x; int l = bl % 5;
  int K = c_LK[l], n = c_LN[l];
  int tid = threadIdx.x;
  if (K >= n){ if (tid == 0){ tbin[bl] = 2048u; cless[bl] = (u32)n; } return; }
  __shared__ u32 cum[2048];
  __shared__ u32 part[256];
  __shared__ int s_t;
  u32 vals[8]; u32 sum = 0;
  for (int q = 0; q < 8; ++q){ vals[q] = hist[bl * 2048 + tid * 8 + q]; sum += vals[q]; }
  part[tid] = sum;
  __syncthreads();
  for (int off = 1; off < 256; off <<= 1){
    u32 add = (tid >= off) ? part[tid - off] : 0u;
    __syncthreads();
    part[tid] += add;
    __syncthreads();
  }
  u32 run = (tid > 0) ? part[tid - 1] : 0u;
  for (int q = 0; q < 8; ++q){ run += vals[q]; cum[tid * 8 + q] = run; }
  if (tid == 0) s_t = 0;
  __syncthreads();
  for (int q = 0; q < 8; ++q){
    int i = tid * 8 + q;
    u32 c = cum[i], cp = (i > 0) ? cum[i - 1] : 0u;
    if (c >= (u32)K && cp < (u32)K) s_t = i;
  }
  __syncthreads();
  if (tid == 0){
    int t = s_t;
    tbin[bl] = (u32)t;
    cless[bl] = (t > 0) ? cum[t - 1] : 0u;
  }
}

// ---------- K1c: collect with wave-aggregated atomics + float4 loads ----------
// One atomicAdd per wave per predicate (G12) instead of per-lane same-address
// RMWs; lanes scatter at base + popcount-prefix. Collection ORDER changes vs
// the per-lane version, but k_select fully sorts, so output is unchanged.
__device__ __forceinline__ void push_keys(int bl, u32 t, u32 bin, u64 key,
    int lane, u64 ltmask, u32* selcnt, u32* candcnt, u64* selg, u64* candg)
{
  bool ps = bin < t;
  bool pc = bin == t;
  u64 bs = __ballot(ps);
  u64 bc = __ballot(pc);
  int nS = __popcll(bs), nC = __popcll(bc);
  u32 baseS = 0, baseC = 0;
  if (lane == 0){
    if (nS) baseS = atomicAdd(&selcnt[bl], (u32)nS);
    if (nC) baseC = atomicAdd(&candcnt[bl], (u32)nC);
  }
  baseS = __shfl(baseS, 0);
  baseC = __shfl(baseC, 0);
  if (ps){
    u32 pos = baseS + (u32)__popcll(bs & ltmask);
    selg[(size_t)bl * 1024 + pos] = key;
  } else if (pc){
    u32 pos = baseC + (u32)__popcll(bc & ltmask);
    if (pos < 4096u) candg[(size_t)bl * 4096 + pos] = key;
  }
}

__global__ void __launch_bounds__(1024)
k_collect(const float* __restrict__ obj, const u32* __restrict__ tbin,
          u32* __restrict__ selcnt, u32* __restrict__ candcnt,
          u64* __restrict__ selg, u64* __restrict__ candg)
{
  int b = blockIdx.x / 33, s = blockIdx.x % 33;
  int l = c_SL[s], start = c_SS[s];
  int cnt = c_LN[l] - start; if (cnt > 8192) cnt = 8192;
  int bl = b * 5 + l;
  u32 t = tbin[bl];
  const float* p = obj + (size_t)b * A_TOTAL + c_LOFF[l] + start;
  int lane = threadIdx.x & 63;
  u64 ltmask = (1ULL << lane) - 1ULL;
  int head = (4 - (int)(((size_t)p >> 2) & 3)) & 3;
  if (head > cnt) head = cnt;
  // head (scalar, uniform wave control flow; dead lanes get bin=0xFFFF)
  {
    bool liv = (int)threadIdx.x < head;
    u32 m = liv ? ~fmap(p[threadIdx.x]) : 0u;
    u32 bin = liv ? (m >> 21) : 0xFFFFu;
    u64 key = ((u64)m << 32) | (u32)(start + (int)threadIdx.x);
    push_keys(bl, t, bin, key, lane, ltmask, selcnt, candcnt, selg, candg);
  }
  int nvec = (cnt - head) >> 2;
  const float4* pv = (const float4*)(p + head);
  int nIter = (nvec + 1023) >> 10;
  for (int it = 0; it < nIter; ++it){
    int i = (it << 10) + (int)threadIdx.x;
    bool liv = i < nvec;
    float4 v = liv ? pv[i] : make_float4(0.f, 0.f, 0.f, 0.f);
    int ebase = start + head + (i << 2);
    #pragma unroll
    for (int q = 0; q < 4; ++q){
      float x = (q == 0) ? v.x : (q == 1) ? v.y : (q == 2) ? v.z : v.w;
      u32 m = liv ? ~fmap(x) : 0u;
      u32 bin = liv ? (m >> 21) : 0xFFFFu;
      u64 key = ((u64)m << 32) | (u32)(ebase + q);
      push_keys(bl, t, bin, key, lane, ltmask, selcnt, candcnt, selg, candg);
    }
  }
  int tail0 = head + (nvec << 2);
  int ntail = cnt - tail0;
  {
    bool liv = (int)threadIdx.x < ntail;
    u32 m = liv ? ~fmap(p[tail0 + threadIdx.x]) : 0u;
    u32 bin = liv ? (m >> 21) : 0xFFFFu;
    u64 key = ((u64)m << 32) | (u32)(start + tail0 + (int)threadIdx.x);
    push_keys(bl, t, bin, key, lane, ltmask, selcnt, candcnt, selg, candg);
  }
}

// ---------- K1d: assemble exact top-K and sort descending-by-obj ----------
__global__ void __launch_bounds__(1024)
k_select(const u32* __restrict__ selcnt, const u32* __restrict__ candcnt,
         const u64* __restrict__ selg, const u64* __restrict__ candg,
         u64* __restrict__ keys)
{
  int bl = blockIdx.x; int b = bl / 5, l = bl % 5;
  int K = c_LK[l];
  int tid = threadIdx.x;
  __shared__ u64 cand[4096];
  __shared__ u64 sel[1024];
  u32 nc = candcnt[bl]; if (nc > 4096u) nc = 4096u;
  u32 ns = selcnt[bl];
  int R = K - (int)ns;
  for (int i = tid; i < 4096; i += 1024) cand[i] = (i < (int)nc) ? candg[(size_t)bl * 4096 + i] : ~0ULL;
  sel[tid] = ~0ULL;
  __syncthreads();
  if (R > 0){
    bitonic_sort<4096, 1024>(cand, tid);
  }
  for (int i = tid; i < (int)ns; i += 1024) sel[i] = selg[(size_t)bl * 1024 + i];
  for (int i = tid; i < R; i += 1024) sel[(int)ns + i] = cand[i];
  bitonic_sort<1024, 1024>(sel, tid);
  for (int i = tid; i < K; i += 1024) keys[(size_t)b * KTOT + l * 1000 + i] = sel[i];
}

// ---------- K2: gather + decode + clip + sigmoid + validity ----------
__global__ void __launch_bounds__(256)
k_decode(const u64* __restrict__ keys, const float* __restrict__ deltas,
         const float* __restrict__ anchors, float* __restrict__ boxes,
         float* __restrict__ scores, u32* __restrict__ valid)
{
  int g = blockIdx.x * 256 + threadIdx.x;
  if (g >= 8 * KTOT) return;
  int b = g / KTOT, kpos = g % KTOT;
  int l = kpos / 1000; if (l > 4) l = 4;
  u64 key = keys[g];
  u32 idx = (u32)key;
  float o = funmap(~(u32)(key >> 32));
  int ai = c_LOFF[l] + (int)idx;
  const float* a = anchors + (size_t)ai * 4;
  const float* d = deltas + ((size_t)b * A_TOTAL + ai) * 4;
  float a0 = a[0], a1 = a[1], a2 = a[2], a3 = a[3];
  float wa = __fsub_rn(a2, a0), ha = __fsub_rn(a3, a1);
  float cxa = __fadd_rn(a0, __fmul_rn(0.5f, wa));
  float cya = __fadd_rn(a1, __fmul_rn(0.5f, ha));
  float dx = d[0], dy = d[1];
  float dw = fminf(d[2], 4.135166556742356f);   // log(1000/16)
  float dh = fminf(d[3], 4.135166556742356f);
  float cx = __fadd_rn(__fmul_rn(dx, wa), cxa);
  float cy = __fadd_rn(__fmul_rn(dy, ha), cya);
  float w  = __fmul_rn(expf(dw), wa);
  float h  = __fmul_rn(expf(dh), ha);
  float hw = __fmul_rn(0.5f, w), hh = __fmul_rn(0.5f, h);
  float x1 = __fsub_rn(cx, hw), y1 = __fsub_rn(cy, hh);
  float x2 = __fadd_rn(cx, hw), y2 = __fadd_rn(cy, hh);
  x1 = fminf(fmaxf(x1, 0.0f), 1216.0f);
  x2 = fminf(fmaxf(x2, 0.0f), 1216.0f);
  y1 = fminf(fmaxf(y1, 0.0f), 800.0f);
  y2 = fminf(fmaxf(y2, 0.0f), 800.0f);
  float s = __fdiv_rn(1.0f, __fadd_rn(1.0f, expf(-o)));
  int v = (__fsub_rn(x2, x1) >= 0.001f) && (__fsub_rn(y2, y1) >= 0.001f) && (s >= 0.0f);
  float* bo = boxes + (size_t)g * 4;
  bo[0] = x1; bo[1] = y1; bo[2] = x2; bo[3] = y2;
  scores[g] = s;
  valid[g] = (u32)v;
}

// ---------- K3: per-level suppression bitmask, 256x256 upper-tri tiles ----------
__global__ void __launch_bounds__(256)
k_mask(const float* __restrict__ boxes, u64* __restrict__ mask)
{
  int b = blockIdx.x / 46, s = blockIdx.x % 46;
  int l = c_TL[s], it = c_TI[s], jt = c_TJ[s];
  int N = c_LK[l];
  int koff = l * 1000;
  float offv = (float)(l * 4096);   // exact
  __shared__ float4 sxy[256];
  __shared__ float  sar[256];
  int j0 = jt * 256;
  {
    int tj = j0 + (int)threadIdx.x;
    float4 q; float ar;
    if (tj < N){
      float4 p = ((const float4*)boxes)[(size_t)(b * KTOT + koff + tj)];
      q.x = __fadd_rn(p.x, offv); q.y = __fadd_rn(p.y, offv);
      q.z = __fadd_rn(p.z, offv); q.w = __fadd_rn(p.w, offv);
      ar = __fmul_rn(__fsub_rn(q.z, q.x), __fsub_rn(q.w, q.y));
    } else {
      q.x = 3e38f; q.y = 3e38f; q.z = -3e38f; q.w = -3e38f; ar = 0.f;
    }
    sxy[threadIdx.x] = q; sar[threadIdx.x] = ar;
  }
  __syncthreads();
  int i = it * 256 + (int)threadIdx.x;
  if (i >= N) return;
  float4 p = ((const float4*)boxes)[(size_t)(b * KTOT + koff + i)];
  float bx1 = __fadd_rn(p.x, offv), by1 = __fadd_rn(p.y, offv);
  float bx2 = __fadd_rn(p.z, offv), by2 = __fadd_rn(p.w, offv);
  float bar = __fmul_rn(__fsub_rn(bx2, bx1), __fsub_rn(by2, by1));
  u64* mb = mask + ((size_t)(b * 5 + l) * 16) * 1024;
  for (int w = 0; w < 4; ++w){
    int jbase = j0 + w * 64;
    if (jbase >= N) break;
    u64 bw = 0;
    #pragma unroll 16
    for (int jj = 0; jj < 64; ++jj){
      int j = jbase + jj;
      float4 q = sxy[w * 64 + jj];
      float aj = sar[w * 64 + jj];
      float ltx = fmaxf(bx1, q.x), lty = fmaxf(by1, q.y);
      float rbx = fminf(bx2, q.z), rby = fminf(by2, q.w);
      float wx = fmaxf(__fsub_rn(rbx, ltx), 0.0f);
      float wy = fmaxf(__fsub_rn(rby, lty), 0.0f);
      float inter = __fmul_rn(wx, wy);
      bool sup = false;
      if (inter > 0.0f && j > i){
        float den = __fsub_rn(__fadd_rn(bar, aj), inter);
        sup = __fdiv_rn(inter, den) > 0.7f;
      }
      bw |= ((u64)sup) << jj;
    }
    mb[(size_t)(jbase >> 6) * 1024 + i] = bw;
  }
}

// ---------- K4: exact greedy NMS, sparse-conflict fast path ----------
// Also exports the final keep bitmask words (keepw[bl][16]) for k_rank.
__global__ void __launch_bounds__(256)
k_nms(const u64* __restrict__ mask, const u32* __restrict__ valid,
      const float* __restrict__ scores, u64* __restrict__ outk,
      u64* __restrict__ keepw)
{
  int bl = blockIdx.x; int b = bl / 5, l = bl % 5;
  int N = c_LK[l], koff = l * 1000;
  int WN = (N + 63) >> 6;           // 16 (levels 0-3) or 12 (level 4)
  int tid = threadIdx.x;
  __shared__ u64 s_kw[16];
  __shared__ u64 s_m[7680];         // 60 KiB: word w at 64*w*(w+1)/2, rows <(w+1)*64
  const u64* mb = mask + (size_t)bl * 16 * 1024;
  int wstage = (WN < 15) ? WN : 15;
  for (int w = 0; w < wstage; ++w){
    int rows = (w + 1) * 64;
    int base = 32 * w * (w + 1);    // = 64*w*(w+1)/2
    for (int r = tid; r < rows; r += 256)
      s_m[base + r] = mb[(size_t)w * 1024 + r];
  }
  __syncthreads();
  if (tid < 64){
    int lane = tid;
    // keep init = valid
    for (int c = 0; c < WN; ++c){
      int i = c * 64 + lane;
      int pred = (i < N) && (valid[(size_t)b * KTOT + koff + i] != 0u);
      u64 bal = __ballot(pred);
      if (lane == 0) s_kw[c] = bal;
    }
    for (int w = 0; w < WN; ++w){
      u64 kwv = s_kw[w];            // broadcast read (uniform)
      // cross-word suppression of word w's columns from finalized kept rows
      u64 supl = 0;
      if (w < 15){
        int base = 32 * w * (w + 1);
        for (int jb = 0; jb < w; ++jb){
          u64 kb = s_kw[jb];
          u64 m = s_m[base + jb * 64 + lane];            // unconditional ds_read
          supl |= (((kb >> lane) & 1ULL) ? m : 0ULL);
        }
      } else {
        for (int jb = 0; jb < w; ++jb){
          u64 kb = s_kw[jb];
          u64 m = mb[(size_t)w * 1024 + jb * 64 + lane]; // unconditional global
          supl |= (((kb >> lane) & 1ULL) ? m : 0ULL);
        }
      }
      // in-word rows (lane r owns row w*64+r's word-w column bits)
      int jr = w * 64 + lane;
      u64 rowl;
      if (w < 15) rowl = s_m[32 * w * (w + 1) + jr];     // diagonal rows staged
      else        rowl = (jr < N) ? mb[(size_t)w * 1024 + jr] : 0ULL;
      // per-lane in-word conflict contribution (candidates only)
      bool inC = ((kwv >> lane) & 1ULL) != 0ULL;
      u64 rkw = rowl & kwv;
      u64 confl = inC ? rkw : 0ULL;
      // fused OR-reduce of (supl, conf) across 64 lanes
      u32 a0 = (u32)supl, a1 = (u32)(supl >> 32);
      u32 a2 = (u32)confl, a3 = (u32)(confl >> 32);
      for (int off = 32; off; off >>= 1){
        a0 |= __shfl_xor(a0, off);
        a1 |= __shfl_xor(a1, off);
        a2 |= __shfl_xor(a2, off);
        a3 |= __shfl_xor(a3, off);
      }
      supl = ((u64)a1 << 32) | a0;
      u64 conf = ((u64)a3 << 32) | a2;          // union of in-word targets
      u64 srcb = __ballot(inC && (rkw != 0ULL)); // in-word source lanes
      u64 cur = kwv & ~supl;
      u64 kept = cur;
      if (((srcb & cur) != 0ULL) && ((conf & cur) != 0ULL)){
        // serial greedy over conflict-involved bits only
        u32 rowl_lo = (u32)rowl, rowl_hi = (u32)(rowl >> 32);
        u64 act = cur & (srcb | conf);
        while (act){
          int ib  = __ffsll((unsigned long long)act) - 1;  // wave-uniform
          int ibs = __builtin_amdgcn_readfirstlane(ib);
          u64 bit = 1ULL << ibs;
          act &= ~bit;
          if (kept & bit){
            u32 rlo = (u32)__builtin_amdgcn_readlane((int)rowl_lo, ibs);
            u32 rhi = (u32)__builtin_amdgcn_readlane((int)rowl_hi, ibs);
            u64 r   = ((u64)rhi << 32) | rlo;
            kept &= ~r;
            act  &= ~r;
          }
        }
      }
      if (lane == 0) s_kw[w] = kept;
    }
  }
  __syncthreads();
  // export keep words (zero beyond WN so popcounts are exact)
  if (tid < 16) keepw[(size_t)bl * 16 + tid] = (tid < WN) ? s_kw[tid] : 0ULL;
  // emit final-merge keys: (~fmap(score))<<32 | concat_pos ; suppressed -> ~0
  for (int i = tid; i < N; i += 256){
    u64 key = ~0ULL;
    if ((s_kw[i >> 6] >> (i & 63)) & 1ULL){
      float sc = scores[(size_t)b * KTOT + koff + i];
      key = ((u64)(~fmap(sc)) << 32) | (u32)(koff + i);
    }
    outk[(size_t)b * KTOT + koff + i] = key;
  }
}

// ---------- K5: 5-way merge-rank final selection (O(K log K)) ----------
#define CMPN 1024   // per-level compacted list, padded with ~0ULL (kept count <= 1000)
__global__ void __launch_bounds__(256)
k_rank(const u64* __restrict__ outk, const u64* __restrict__ keepw,
       const float* __restrict__ boxes, float* __restrict__ out)
{
  int b = blockIdx.x / 19, chunk = blockIdx.x % 19;
  int tid = threadIdx.x;
  __shared__ u64 cmp[5 * CMPN];   // 40 KiB
  __shared__ u64 kw[80];          // keep words for this image's 5 levels
  for (int i = tid; i < 5 * CMPN; i += 256) cmp[i] = ~0ULL;
  if (tid < 80) kw[tid] = keepw[(size_t)b * 80 + tid];
  __syncthreads();
  // scatter-compact kept keys per level (rank via popcount prefix; no atomics)
  for (int i = tid; i < KTOT; i += 256){
    u64 key = outk[(size_t)b * KTOT + i];
    if (key != ~0ULL){
      int l = i / 1000; if (l > 4) l = 4;
      int li = i - l * 1000;
      int wi = li >> 6, bit = li & 63;
      const u64* kwl = &kw[l * 16];
      int r = __popcll(kwl[wi] & ((1ULL << bit) - 1ULL));
      for (int w = 0; w < wi; ++w) r += __popcll(kwl[w]);
      cmp[l * CMPN + r] = key;
    }
  }
  __syncthreads();
  int i = chunk * 256 + tid;
  if (i >= KTOT) return;
  u64 key = outk[(size_t)b * KTOT + i];
  if (key == ~0ULL) return;     // suppressed / invalid
  int l = i / 1000; if (l > 4) l = 4;
  int li = i - l * 1000;
  int wi = li >> 6, bit = li & 63;
  const u64* kwl = &kw[l * 16];
  int rank = __popcll(kwl[wi] & ((1ULL << bit) - 1ULL));
  for (int w = 0; w < wi; ++w) rank += __popcll(kwl[w]);
  #pragma unroll
  for (int lo = 0; lo < 5; ++lo){
    if (lo == l) continue;
    int pos = 0;
    #pragma unroll
    for (int s = 512; s > 0; s >>= 1)
      if (cmp[lo * CMPN + pos + s - 1] < key) pos += s;
    rank += pos;   // count of kept keys in level lo that are < key
  }
  if (rank < 1000){
    float4 bx = ((const float4*)boxes)[(size_t)(b * KTOT + i)];
    ((float4*)out)[(size_t)(b * 1000 + rank)] = bx;
    out[32000 + b * 1000 + rank] = funmap(~(u32)(key >> 32));
  }
}

extern "C" void kernel_launch(void* const* d_in, const int* in_sizes, int n_in,
                              void* d_out, int out_size, void* d_ws, size_t ws_size,
                              hipStream_t stream)
{
  (void)in_sizes; (void)n_in; (void)ws_size; // needs ~8.73 MB ws
  const float* obj     = (const float*)d_in[0];
  const float* deltas  = (const float*)d_in[1];
  const float* anchors = (const float*)d_in[2];
  float* out = (float*)d_out;
  char* ws = (char*)d_ws;

  u32* hist    = (u32*)(ws + OFF_HIST);
  u64* keepw   = (u64*)(ws + OFF_KEEPW);   // aliases hist (dead by k_nms time)
  u32* selcnt  = (u32*)(ws + OFF_SELCNT);
  u32* candcnt = (u32*)(ws + OFF_CANDCNT);
  u32* tbin    = (u32*)(ws + OFF_TBIN);
  u32* cless   = (u32*)(ws + OFF_CLESS);
  u64* selg    = (u64*)(ws + OFF_SELG);
  u64* candg   = (u64*)(ws + OFF_CANDG);
  u64* keys    = (u64*)(ws + OFF_KEYS);
  float* boxes = (float*)(ws + OFF_BOX);
  float* score = (float*)(ws + OFF_SCORE);
  u32* valid   = (u32*)(ws + OFF_VALID);
  u64* mask    = (u64*)(ws + OFF_MASK);
  u64* outk    = (u64*)(ws + OFF_OUTK);

  hipMemsetAsync(ws, 0, MEMSET_BYTES, stream);
  hipMemsetAsync(d_out, 0, (size_t)out_size * sizeof(float), stream);
  hipLaunchKernelGGL(k_hist,    dim3(264), dim3(1024), 0, stream, obj, hist);
  hipLaunchKernelGGL(k_cutoff,  dim3(40),  dim3(256),  0, stream, hist, tbin, cless);
  hipLaunchKernelGGL(k_collect, dim3(264), dim3(1024), 0, stream, obj, tbin, selcnt, candcnt, selg, candg);
  hipLaunchKernelGGL(k_select,  dim3(40),  dim3(1024), 0, stream, selcnt, candcnt, selg, candg, keys);
  hipLaunchKernelGGL(k_decode,  dim3(149), dim3(256),  0, stream, keys, deltas, anchors, boxes, score, valid);
  hipLaunchKernelGGL(k_mask,    dim3(368), dim3(256),  0, stream, boxes, mask);
  hipLaunchKernelGGL(k_nms,     dim3(40),  dim3(256),  0, stream, mask, valid, score, outk, keepw);
  hipLaunchKernelGGL(k_rank,    dim3(152), dim3(256),  0, stream, outk, keepw, boxes, out);
}

// Round 12
// 186.767 us; speedup vs baseline: 3.0378x; 1.3123x over previous
//
#include <hip/hip_runtime.h>
#include <stdint.h>

#pragma clang fp contract(off)

typedef unsigned int u32;
typedef unsigned long long u64;

#define A_TOTAL 242991
#define KTOT    4741

// level tables
__constant__ int c_LN[5]   = {182400, 45600, 11400, 2850, 741};
__constant__ int c_LOFF[5] = {0, 182400, 228000, 239400, 242250};
__constant__ int c_LK[5]   = {1000, 1000, 1000, 1000, 741};

// scan segment tables: 33 segments/image of <=8192 elements (23 l0, 6 l1, 2 l2, 1 l3, 1 l4)
__constant__ int c_SL[33] = {0,0,0,0,0,0,0,0,0,0,0,0,0,0,0,0,0,0,0,0,0,0,0,
                             1,1,1,1,1,1, 2,2, 3, 4};
__constant__ int c_SS[33] = {0,8192,16384,24576,32768,40960,49152,57344,65536,
                             73728,81920,90112,98304,106496,114688,122880,131072,
                             139264,147456,155648,163840,172032,180224,
                             0,8192,16384,24576,32768,40960, 0,8192, 0, 0};

// k_mask tile tables: 46 upper-triangle (it<=jt) tiles per image
__constant__ int c_TL[46] = {0,0,0,0,0,0,0,0,0,0, 1,1,1,1,1,1,1,1,1,1,
                             2,2,2,2,2,2,2,2,2,2, 3,3,3,3,3,3,3,3,3,3,
                             4,4,4,4,4,4};
__constant__ int c_TI[46] = {0,0,0,0,1,1,1,2,2,3, 0,0,0,0,1,1,1,2,2,3,
                             0,0,0,0,1,1,1,2,2,3, 0,0,0,0,1,1,1,2,2,3,
                             0,0,0,1,1,2};
__constant__ int c_TJ[46] = {0,1,2,3,1,2,3,2,3,3, 0,1,2,3,1,2,3,2,3,3,
                             0,1,2,3,1,2,3,2,3,3, 0,1,2,3,1,2,3,2,3,3,
                             0,1,2,1,2,2};

// workspace byte offsets (total ~8.73 MB)
// keepw (40*16*8 = 5120 B) ALIASES the hist region: hist is dead after k_cutoff,
// and k_nms (writer) runs strictly before k_rank (reader) every launch.
static const size_t OFF_KEEPW    = 0;
static const size_t OFF_HIST     = 0;        // 40*2048*4 = 327680
static const size_t OFF_SELCNT   = 327680;   // 40*4
static const size_t OFF_CANDCNT  = 327840;   // 40*4
static const size_t MEMSET_BYTES = 328000;
static const size_t OFF_TBIN     = 328000;   // 40*4
static const size_t OFF_CLESS    = 328160;   // 40*4
static const size_t OFF_SELG     = 328320;   // 40*1024*8  -> 656000
static const size_t OFF_CANDG    = 656000;   // 40*4096*8  -> 1966720
static const size_t OFF_KEYS     = 1966720;  // 8*4741*8   -> 2270144
static const size_t OFF_BOX      = 2270144;  // 8*4741*4*4 -> 2876992
static const size_t OFF_SCORE    = 2876992;  // 8*4741*4   -> 3028704
static const size_t OFF_VALID    = 3028704;  // 8*4741*4   -> 3180416
static const size_t OFF_MASK     = 3180416;  // 8*5*16*1024*8 -> 8423296
static const size_t OFF_OUTK     = 8423296;  // 8*4741*8   -> 8726720

// monotone float<->uint map: fmap ascending in float value
__device__ __forceinline__ u32 fmap(float f){
  u32 b = __float_as_uint(f);
  return (b & 0x80000000u) ? ~b : (b | 0x80000000u);
}
__device__ __forceinline__ float funmap(u32 m){
  return __uint_as_float((m & 0x80000000u) ? (m & 0x7FFFFFFFu) : ~m);
}

template<int N, int T>
__device__ __forceinline__ void bitonic_sort(u64* d, int tid){
  for (int k = 2; k <= N; k <<= 1){
    for (int j = k >> 1; j > 0; j >>= 1){
      __syncthreads();
      #pragma unroll 1
      for (int i = tid; i < N; i += T){
        int ixj = i ^ j;
        if (ixj > i){
          u64 a = d[i], b = d[ixj];
          bool sw = ((i & k) == 0) ? (a > b) : (a < b);
          if (sw){ d[i] = b; d[ixj] = a; }
        }
      }
    }
  }
  __syncthreads();
}

// ---------- K1a: per-(b,l) 2048-bin histogram, float4-vectorized ----------
__global__ void __launch_bounds__(1024)
k_hist(const float* __restrict__ obj, u32* __restrict__ hist)
{
  int b = blockIdx.x / 33, s = blockIdx.x % 33;
  int l = c_SL[s], start = c_SS[s];
  int cnt = c_LN[l] - start; if (cnt > 8192) cnt = 8192;
  int bl = b * 5 + l;
  __shared__ u32 h[2048];
  for (int i = threadIdx.x; i < 2048; i += 1024) h[i] = 0;
  __syncthreads();
  const float* p = obj + (size_t)b * A_TOTAL + c_LOFF[l] + start;
  int head = (4 - (int)(((size_t)p >> 2) & 3)) & 3;
  if (head > cnt) head = cnt;
  if ((int)threadIdx.x < head) atomicAdd(&h[(~fmap(p[threadIdx.x])) >> 21], 1u);
  int nvec = (cnt - head) >> 2;
  const float4* pv = (const float4*)(p + head);
  for (int i = threadIdx.x; i < nvec; i += 1024){
    float4 v = pv[i];
    atomicAdd(&h[(~fmap(v.x)) >> 21], 1u);
    atomicAdd(&h[(~fmap(v.y)) >> 21], 1u);
    atomicAdd(&h[(~fmap(v.z)) >> 21], 1u);
    atomicAdd(&h[(~fmap(v.w)) >> 21], 1u);
  }
  int tail0 = head + (nvec << 2);
  int ntail = cnt - tail0;
  if ((int)threadIdx.x < ntail) atomicAdd(&h[(~fmap(p[tail0 + threadIdx.x])) >> 21], 1u);
  __syncthreads();
  for (int i = threadIdx.x; i < 2048; i += 1024){
    u32 v = h[i];
    if (v) atomicAdd(&hist[bl * 2048 + i], v);
  }
}

// ---------- K1b: find cutoff bin t and count_less ----------
__global__ void __launch_bounds__(256)
k_cutoff(const u32* __restrict__ hist, u32* __restrict__ tbin, u32* __restrict__ cless)
{
  int bl = blockIdx.x; int l = bl % 5;
  int K = c_LK[l], n = c_LN[l];
  int tid = threadIdx.x;
  if (K >= n){ if (tid == 0){ tbin[bl] = 2048u; cless[bl] = (u32)n; } return; }
  __shared__ u32 cum[2048];
  __shared__ u32 part[256];
  __shared__ int s_t;
  u32 vals[8]; u32 sum = 0;
  for (int q = 0; q < 8; ++q){ vals[q] = hist[bl * 2048 + tid * 8 + q]; sum += vals[q]; }
  part[tid] = sum;
  __syncthreads();
  for (int off = 1; off < 256; off <<= 1){
    u32 add = (tid >= off) ? part[tid - off] : 0u;
    __syncthreads();
    part[tid] += add;
    __syncthreads();
  }
  u32 run = (tid > 0) ? part[tid - 1] : 0u;
  for (int q = 0; q < 8; ++q){ run += vals[q]; cum[tid * 8 + q] = run; }
  if (tid == 0) s_t = 0;
  __syncthreads();
  for (int q = 0; q < 8; ++q){
    int i = tid * 8 + q;
    u32 c = cum[i], cp = (i > 0) ? cum[i - 1] : 0u;
    if (c >= (u32)K && cp < (u32)K) s_t = i;
  }
  __syncthreads();
  if (tid == 0){
    int t = s_t;
    tbin[bl] = (u32)t;
    cless[bl] = (t > 0) ? cum[t - 1] : 0u;
  }
}

// ---------- K1c: collect via LDS-staged compaction ----------
// Hot loop has NO global atomics and NO cross-lane ops: selected/boundary keys
// go to LDS via fast LDS atomics (~45 winners/block expected). One global
// atomicAdd per block per counter reserves the output range (latency paid once,
// behind a barrier), then a coalesced LDS->global copy. Overflow guards keep
// exactness for any input (spill path does a direct global push; ranges from
// atomics are disjoint, and k_select fully sorts, so order is irrelevant).
#define SELCAP 2048
#define CANDCAP 1024
__global__ void __launch_bounds__(1024)
k_collect(const float* __restrict__ obj, const u32* __restrict__ tbin,
          u32* __restrict__ selcnt, u32* __restrict__ candcnt,
          u64* __restrict__ selg, u64* __restrict__ candg)
{
  int b = blockIdx.x / 33, s = blockIdx.x % 33;
  int l = c_SL[s], start = c_SS[s];
  int cnt = c_LN[l] - start; if (cnt > 8192) cnt = 8192;
  int bl = b * 5 + l;
  u32 t = tbin[bl];
  __shared__ u64 lsel[SELCAP];    // 16 KiB
  __shared__ u64 lcand[CANDCAP];  //  8 KiB
  __shared__ u32 lcs, lcc, gbs, gbc;
  if (threadIdx.x == 0){ lcs = 0u; lcc = 0u; }
  __syncthreads();
  const float* p = obj + (size_t)b * A_TOTAL + c_LOFF[l] + start;

  auto push = [&](u32 m, int idx){
    u32 bin = m >> 21;
    u64 key = ((u64)m << 32) | (u32)idx;
    if (bin < t){
      u32 pos = atomicAdd(&lcs, 1u);                       // LDS atomic
      if (pos < SELCAP) lsel[pos] = key;
      else { u32 gp = atomicAdd(&selcnt[bl], 1u); selg[(size_t)bl * 1024 + gp] = key; }
    } else if (bin == t){
      u32 pos = atomicAdd(&lcc, 1u);                       // LDS atomic
      if (pos < CANDCAP) lcand[pos] = key;
      else { u32 gp = atomicAdd(&candcnt[bl], 1u); if (gp < 4096u) candg[(size_t)bl * 4096 + gp] = key; }
    }
  };

  int head = (4 - (int)(((size_t)p >> 2) & 3)) & 3;
  if (head > cnt) head = cnt;
  if ((int)threadIdx.x < head) push(~fmap(p[threadIdx.x]), start + (int)threadIdx.x);
  int nvec = (cnt - head) >> 2;
  const float4* pv = (const float4*)(p + head);
  for (int i = threadIdx.x; i < nvec; i += 1024){
    float4 v = pv[i];
    int e = start + head + (i << 2);
    push(~fmap(v.x), e);
    push(~fmap(v.y), e + 1);
    push(~fmap(v.z), e + 2);
    push(~fmap(v.w), e + 3);
  }
  int tail0 = head + (nvec << 2);
  int ntail = cnt - tail0;
  if ((int)threadIdx.x < ntail) push(~fmap(p[tail0 + threadIdx.x]), start + tail0 + (int)threadIdx.x);
  __syncthreads();
  u32 ns = lcs;  if (ns > SELCAP) ns = SELCAP;
  u32 ncd = lcc; if (ncd > CANDCAP) ncd = CANDCAP;
  if (threadIdx.x == 0){
    gbs = ns  ? atomicAdd(&selcnt[bl],  ns)  : 0u;
    gbc = ncd ? atomicAdd(&candcnt[bl], ncd) : 0u;
  }
  __syncthreads();
  u32 bs = gbs, bc = gbc;
  for (u32 i = threadIdx.x; i < ns; i += 1024)
    selg[(size_t)bl * 1024 + bs + i] = lsel[i];
  for (u32 i = threadIdx.x; i < ncd; i += 1024){
    u32 gp = bc + i;
    if (gp < 4096u) candg[(size_t)bl * 4096 + gp] = lcand[i];
  }
}

// ---------- K1d: assemble exact top-K and sort descending-by-obj ----------
__global__ void __launch_bounds__(1024)
k_select(const u32* __restrict__ selcnt, const u32* __restrict__ candcnt,
         const u64* __restrict__ selg, const u64* __restrict__ candg,
         u64* __restrict__ keys)
{
  int bl = blockIdx.x; int b = bl / 5, l = bl % 5;
  int K = c_LK[l];
  int tid = threadIdx.x;
  __shared__ u64 cand[4096];
  __shared__ u64 sel[1024];
  u32 nc = candcnt[bl]; if (nc > 4096u) nc = 4096u;
  u32 ns = selcnt[bl];
  int R = K - (int)ns;
  for (int i = tid; i < 4096; i += 1024) cand[i] = (i < (int)nc) ? candg[(size_t)bl * 4096 + i] : ~0ULL;
  sel[tid] = ~0ULL;
  __syncthreads();
  if (R > 0){
    bitonic_sort<4096, 1024>(cand, tid);
  }
  for (int i = tid; i < (int)ns; i += 1024) sel[i] = selg[(size_t)bl * 1024 + i];
  for (int i = tid; i < R; i += 1024) sel[(int)ns + i] = cand[i];
  bitonic_sort<1024, 1024>(sel, tid);
  for (int i = tid; i < K; i += 1024) keys[(size_t)b * KTOT + l * 1000 + i] = sel[i];
}

// ---------- K2: gather + decode + clip + sigmoid + validity ----------
__global__ void __launch_bounds__(256)
k_decode(const u64* __restrict__ keys, const float* __restrict__ deltas,
         const float* __restrict__ anchors, float* __restrict__ boxes,
         float* __restrict__ scores, u32* __restrict__ valid)
{
  int g = blockIdx.x * 256 + threadIdx.x;
  if (g >= 8 * KTOT) return;
  int b = g / KTOT, kpos = g % KTOT;
  int l = kpos / 1000; if (l > 4) l = 4;
  u64 key = keys[g];
  u32 idx = (u32)key;
  float o = funmap(~(u32)(key >> 32));
  int ai = c_LOFF[l] + (int)idx;
  const float* a = anchors + (size_t)ai * 4;
  const float* d = deltas + ((size_t)b * A_TOTAL + ai) * 4;
  float a0 = a[0], a1 = a[1], a2 = a[2], a3 = a[3];
  float wa = __fsub_rn(a2, a0), ha = __fsub_rn(a3, a1);
  float cxa = __fadd_rn(a0, __fmul_rn(0.5f, wa));
  float cya = __fadd_rn(a1, __fmul_rn(0.5f, ha));
  float dx = d[0], dy = d[1];
  float dw = fminf(d[2], 4.135166556742356f);   // log(1000/16)
  float dh = fminf(d[3], 4.135166556742356f);
  float cx = __fadd_rn(__fmul_rn(dx, wa), cxa);
  float cy = __fadd_rn(__fmul_rn(dy, ha), cya);
  float w  = __fmul_rn(expf(dw), wa);
  float h  = __fmul_rn(expf(dh), ha);
  float hw = __fmul_rn(0.5f, w), hh = __fmul_rn(0.5f, h);
  float x1 = __fsub_rn(cx, hw), y1 = __fsub_rn(cy, hh);
  float x2 = __fadd_rn(cx, hw), y2 = __fadd_rn(cy, hh);
  x1 = fminf(fmaxf(x1, 0.0f), 1216.0f);
  x2 = fminf(fmaxf(x2, 0.0f), 1216.0f);
  y1 = fminf(fmaxf(y1, 0.0f), 800.0f);
  y2 = fminf(fmaxf(y2, 0.0f), 800.0f);
  float s = __fdiv_rn(1.0f, __fadd_rn(1.0f, expf(-o)));
  int v = (__fsub_rn(x2, x1) >= 0.001f) && (__fsub_rn(y2, y1) >= 0.001f) && (s >= 0.0f);
  float* bo = boxes + (size_t)g * 4;
  bo[0] = x1; bo[1] = y1; bo[2] = x2; bo[3] = y2;
  scores[g] = s;
  valid[g] = (u32)v;
}

// ---------- K3: per-level suppression bitmask, 256x256 upper-tri tiles ----------
__global__ void __launch_bounds__(256)
k_mask(const float* __restrict__ boxes, u64* __restrict__ mask)
{
  int b = blockIdx.x / 46, s = blockIdx.x % 46;
  int l = c_TL[s], it = c_TI[s], jt = c_TJ[s];
  int N = c_LK[l];
  int koff = l * 1000;
  float offv = (float)(l * 4096);   // exact
  __shared__ float4 sxy[256];
  __shared__ float  sar[256];
  int j0 = jt * 256;
  {
    int tj = j0 + (int)threadIdx.x;
    float4 q; float ar;
    if (tj < N){
      float4 p = ((const float4*)boxes)[(size_t)(b * KTOT + koff + tj)];
      q.x = __fadd_rn(p.x, offv); q.y = __fadd_rn(p.y, offv);
      q.z = __fadd_rn(p.z, offv); q.w = __fadd_rn(p.w, offv);
      ar = __fmul_rn(__fsub_rn(q.z, q.x), __fsub_rn(q.w, q.y));
    } else {
      q.x = 3e38f; q.y = 3e38f; q.z = -3e38f; q.w = -3e38f; ar = 0.f;
    }
    sxy[threadIdx.x] = q; sar[threadIdx.x] = ar;
  }
  __syncthreads();
  int i = it * 256 + (int)threadIdx.x;
  if (i >= N) return;
  float4 p = ((const float4*)boxes)[(size_t)(b * KTOT + koff + i)];
  float bx1 = __fadd_rn(p.x, offv), by1 = __fadd_rn(p.y, offv);
  float bx2 = __fadd_rn(p.z, offv), by2 = __fadd_rn(p.w, offv);
  float bar = __fmul_rn(__fsub_rn(bx2, bx1), __fsub_rn(by2, by1));
  u64* mb = mask + ((size_t)(b * 5 + l) * 16) * 1024;
  for (int w = 0; w < 4; ++w){
    int jbase = j0 + w * 64;
    if (jbase >= N) break;
    u64 bw = 0;
    #pragma unroll 16
    for (int jj = 0; jj < 64; ++jj){
      int j = jbase + jj;
      float4 q = sxy[w * 64 + jj];
      float aj = sar[w * 64 + jj];
      float ltx = fmaxf(bx1, q.x), lty = fmaxf(by1, q.y);
      float rbx = fminf(bx2, q.z), rby = fminf(by2, q.w);
      float wx = fmaxf(__fsub_rn(rbx, ltx), 0.0f);
      float wy = fmaxf(__fsub_rn(rby, lty), 0.0f);
      float inter = __fmul_rn(wx, wy);
      bool sup = false;
      if (inter > 0.0f && j > i){
        float den = __fsub_rn(__fadd_rn(bar, aj), inter);
        sup = __fdiv_rn(inter, den) > 0.7f;
      }
      bw |= ((u64)sup) << jj;
    }
    mb[(size_t)(jbase >> 6) * 1024 + i] = bw;
  }
}

// ---------- K4: exact greedy NMS, sparse-conflict fast path ----------
// Also exports the final keep bitmask words (keepw[bl][16]) for k_rank.
__global__ void __launch_bounds__(256)
k_nms(const u64* __restrict__ mask, const u32* __restrict__ valid,
      const float* __restrict__ scores, u64* __restrict__ outk,
      u64* __restrict__ keepw)
{
  int bl = blockIdx.x; int b = bl / 5, l = bl % 5;
  int N = c_LK[l], koff = l * 1000;
  int WN = (N + 63) >> 6;           // 16 (levels 0-3) or 12 (level 4)
  int tid = threadIdx.x;
  __shared__ u64 s_kw[16];
  __shared__ u64 s_m[7680];         // 60 KiB: word w at 64*w*(w+1)/2, rows <(w+1)*64
  const u64* mb = mask + (size_t)bl * 16 * 1024;
  int wstage = (WN < 15) ? WN : 15;
  for (int w = 0; w < wstage; ++w){
    int rows = (w + 1) * 64;
    int base = 32 * w * (w + 1);    // = 64*w*(w+1)/2
    for (int r = tid; r < rows; r += 256)
      s_m[base + r] = mb[(size_t)w * 1024 + r];
  }
  __syncthreads();
  if (tid < 64){
    int lane = tid;
    // keep init = valid
    for (int c = 0; c < WN; ++c){
      int i = c * 64 + lane;
      int pred = (i < N) && (valid[(size_t)b * KTOT + koff + i] != 0u);
      u64 bal = __ballot(pred);
      if (lane == 0) s_kw[c] = bal;
    }
    for (int w = 0; w < WN; ++w){
      u64 kwv = s_kw[w];            // broadcast read (uniform)
      // cross-word suppression of word w's columns from finalized kept rows
      u64 supl = 0;
      if (w < 15){
        int base = 32 * w * (w + 1);
        for (int jb = 0; jb < w; ++jb){
          u64 kb = s_kw[jb];
          u64 m = s_m[base + jb * 64 + lane];            // unconditional ds_read
          supl |= (((kb >> lane) & 1ULL) ? m : 0ULL);
        }
      } else {
        for (int jb = 0; jb < w; ++jb){
          u64 kb = s_kw[jb];
          u64 m = mb[(size_t)w * 1024 + jb * 64 + lane]; // unconditional global
          supl |= (((kb >> lane) & 1ULL) ? m : 0ULL);
        }
      }
      // in-word rows (lane r owns row w*64+r's word-w column bits)
      int jr = w * 64 + lane;
      u64 rowl;
      if (w < 15) rowl = s_m[32 * w * (w + 1) + jr];     // diagonal rows staged
      else        rowl = (jr < N) ? mb[(size_t)w * 1024 + jr] : 0ULL;
      // per-lane in-word conflict contribution (candidates only)
      bool inC = ((kwv >> lane) & 1ULL) != 0ULL;
      u64 rkw = rowl & kwv;
      u64 confl = inC ? rkw : 0ULL;
      // fused OR-reduce of (supl, conf) across 64 lanes
      u32 a0 = (u32)supl, a1 = (u32)(supl >> 32);
      u32 a2 = (u32)confl, a3 = (u32)(confl >> 32);
      for (int off = 32; off; off >>= 1){
        a0 |= __shfl_xor(a0, off);
        a1 |= __shfl_xor(a1, off);
        a2 |= __shfl_xor(a2, off);
        a3 |= __shfl_xor(a3, off);
      }
      supl = ((u64)a1 << 32) | a0;
      u64 conf = ((u64)a3 << 32) | a2;          // union of in-word targets
      u64 srcb = __ballot(inC && (rkw != 0ULL)); // in-word source lanes
      u64 cur = kwv & ~supl;
      u64 kept = cur;
      if (((srcb & cur) != 0ULL) && ((conf & cur) != 0ULL)){
        // serial greedy over conflict-involved bits only
        u32 rowl_lo = (u32)rowl, rowl_hi = (u32)(rowl >> 32);
        u64 act = cur & (srcb | conf);
        while (act){
          int ib  = __ffsll((unsigned long long)act) - 1;  // wave-uniform
          int ibs = __builtin_amdgcn_readfirstlane(ib);
          u64 bit = 1ULL << ibs;
          act &= ~bit;
          if (kept & bit){
            u32 rlo = (u32)__builtin_amdgcn_readlane((int)rowl_lo, ibs);
            u32 rhi = (u32)__builtin_amdgcn_readlane((int)rowl_hi, ibs);
            u64 r   = ((u64)rhi << 32) | rlo;
            kept &= ~r;
            act  &= ~r;
          }
        }
      }
      if (lane == 0) s_kw[w] = kept;
    }
  }
  __syncthreads();
  // export keep words (zero beyond WN so popcounts are exact)
  if (tid < 16) keepw[(size_t)bl * 16 + tid] = (tid < WN) ? s_kw[tid] : 0ULL;
  // emit final-merge keys: (~fmap(score))<<32 | concat_pos ; suppressed -> ~0
  for (int i = tid; i < N; i += 256){
    u64 key = ~0ULL;
    if ((s_kw[i >> 6] >> (i & 63)) & 1ULL){
      float sc = scores[(size_t)b * KTOT + koff + i];
      key = ((u64)(~fmap(sc)) << 32) | (u32)(koff + i);
    }
    outk[(size_t)b * KTOT + koff + i] = key;
  }
}

// ---------- K5: 5-way merge-rank final selection (O(K log K)) ----------
#define CMPN 1024   // per-level compacted list, padded with ~0ULL (kept count <= 1000)
__global__ void __launch_bounds__(256)
k_rank(const u64* __restrict__ outk, const u64* __restrict__ keepw,
       const float* __restrict__ boxes, float* __restrict__ out)
{
  int b = blockIdx.x / 19, chunk = blockIdx.x % 19;
  int tid = threadIdx.x;
  __shared__ u64 cmp[5 * CMPN];   // 40 KiB
  __shared__ u64 kw[80];          // keep words for this image's 5 levels
  for (int i = tid; i < 5 * CMPN; i += 256) cmp[i] = ~0ULL;
  if (tid < 80) kw[tid] = keepw[(size_t)b * 80 + tid];
  __syncthreads();
  // scatter-compact kept keys per level (rank via popcount prefix; no atomics)
  for (int i = tid; i < KTOT; i += 256){
    u64 key = outk[(size_t)b * KTOT + i];
    if (key != ~0ULL){
      int l = i / 1000; if (l > 4) l = 4;
      int li = i - l * 1000;
      int wi = li >> 6, bit = li & 63;
      const u64* kwl = &kw[l * 16];
      int r = __popcll(kwl[wi] & ((1ULL << bit) - 1ULL));
      for (int w = 0; w < wi; ++w) r += __popcll(kwl[w]);
      cmp[l * CMPN + r] = key;
    }
  }
  __syncthreads();
  int i = chunk * 256 + tid;
  if (i >= KTOT) return;
  u64 key = outk[(size_t)b * KTOT + i];
  if (key == ~0ULL) return;     // suppressed / invalid
  int l = i / 1000; if (l > 4) l = 4;
  int li = i - l * 1000;
  int wi = li >> 6, bit = li & 63;
  const u64* kwl = &kw[l * 16];
  int rank = __popcll(kwl[wi] & ((1ULL << bit) - 1ULL));
  for (int w = 0; w < wi; ++w) rank += __popcll(kwl[w]);
  #pragma unroll
  for (int lo = 0; lo < 5; ++lo){
    if (lo == l) continue;
    int pos = 0;
    #pragma unroll
    for (int s = 512; s > 0; s >>= 1)
      if (cmp[lo * CMPN + pos + s - 1] < key) pos += s;
    rank += pos;   // count of kept keys in level lo that are < key
  }
  if (rank < 1000){
    float4 bx = ((const float4*)boxes)[(size_t)(b * KTOT + i)];
    ((float4*)out)[(size_t)(b * 1000 + rank)] = bx;
    out[32000 + b * 1000 + rank] = funmap(~(u32)(key >> 32));
  }
}

extern "C" void kernel_launch(void* const* d_in, const int* in_sizes, int n_in,
                              void* d_out, int out_size, void* d_ws, size_t ws_size,
                              hipStream_t stream)
{
  (void)in_sizes; (void)n_in; (void)ws_size; // needs ~8.73 MB ws
  const float* obj     = (const float*)d_in[0];
  const float* deltas  = (const float*)d_in[1];
  const float* anchors = (const float*)d_in[2];
  float* out = (float*)d_out;
  char* ws = (char*)d_ws;

  u32* hist    = (u32*)(ws + OFF_HIST);
  u64* keepw   = (u64*)(ws + OFF_KEEPW);   // aliases hist (dead by k_nms time)
  u32* selcnt  = (u32*)(ws + OFF_SELCNT);
  u32* candcnt = (u32*)(ws + OFF_CANDCNT);
  u32* tbin    = (u32*)(ws + OFF_TBIN);
  u32* cless   = (u32*)(ws + OFF_CLESS);
  u64* selg    = (u64*)(ws + OFF_SELG);
  u64* candg   = (u64*)(ws + OFF_CANDG);
  u64* keys    = (u64*)(ws + OFF_KEYS);
  float* boxes = (float*)(ws + OFF_BOX);
  float* score = (float*)(ws + OFF_SCORE);
  u32* valid   = (u32*)(ws + OFF_VALID);
  u64* mask    = (u64*)(ws + OFF_MASK);
  u64* outk    = (u64*)(ws + OFF_OUTK);

  hipMemsetAsync(ws, 0, MEMSET_BYTES, stream);
  hipMemsetAsync(d_out, 0, (size_t)out_size * sizeof(float), stream);
  hipLaunchKernelGGL(k_hist,    dim3(264), dim3(1024), 0, stream, obj, hist);
  hipLaunchKernelGGL(k_cutoff,  dim3(40),  dim3(256),  0, stream, hist, tbin, cless);
  hipLaunchKernelGGL(k_collect, dim3(264), dim3(1024), 0, stream, obj, tbin, selcnt, candcnt, selg, candg);
  hipLaunchKernelGGL(k_select,  dim3(40),  dim3(1024), 0, stream, selcnt, candcnt, selg, candg, keys);
  hipLaunchKernelGGL(k_decode,  dim3(149), dim3(256),  0, stream, keys, deltas, anchors, boxes, score, valid);
  hipLaunchKernelGGL(k_mask,    dim3(368), dim3(256),  0, stream, boxes, mask);
  hipLaunchKernelGGL(k_nms,     dim3(40),  dim3(256),  0, stream, mask, valid, score, outk, keepw);
  hipLaunchKernelGGL(k_rank,    dim3(152), dim3(256),  0, stream, outk, keepw, boxes, out);
}

// Round 15
// 163.492 us; speedup vs baseline: 3.4703x; 1.1424x over previous
//
#include <hip/hip_runtime.h>
#include <stdint.h>

#pragma clang fp contract(off)

typedef unsigned int u32;
typedef unsigned long long u64;

#define A_TOTAL 242991
#define KTOT    4741

// level tables
__constant__ int c_LN[5]   = {182400, 45600, 11400, 2850, 741};
__constant__ int c_LOFF[5] = {0, 182400, 228000, 239400, 242250};
__constant__ int c_LK[5]   = {1000, 1000, 1000, 1000, 741};

// scan segment tables: 33 segments/image of <=8192 elements (23 l0, 6 l1, 2 l2, 1 l3, 1 l4)
__constant__ int c_SL[33] = {0,0,0,0,0,0,0,0,0,0,0,0,0,0,0,0,0,0,0,0,0,0,0,
                             1,1,1,1,1,1, 2,2, 3, 4};
__constant__ int c_SS[33] = {0,8192,16384,24576,32768,40960,49152,57344,65536,
                             73728,81920,90112,98304,106496,114688,122880,131072,
                             139264,147456,155648,163840,172032,180224,
                             0,8192,16384,24576,32768,40960, 0,8192, 0, 0};

// k_mask tile tables: 46 upper-triangle (it<=jt) tiles per image
__constant__ int c_TL[46] = {0,0,0,0,0,0,0,0,0,0, 1,1,1,1,1,1,1,1,1,1,
                             2,2,2,2,2,2,2,2,2,2, 3,3,3,3,3,3,3,3,3,3,
                             4,4,4,4,4,4};
__constant__ int c_TI[46] = {0,0,0,0,1,1,1,2,2,3, 0,0,0,0,1,1,1,2,2,3,
                             0,0,0,0,1,1,1,2,2,3, 0,0,0,0,1,1,1,2,2,3,
                             0,0,0,1,1,2};
__constant__ int c_TJ[46] = {0,1,2,3,1,2,3,2,3,3, 0,1,2,3,1,2,3,2,3,3,
                             0,1,2,3,1,2,3,2,3,3, 0,1,2,3,1,2,3,2,3,3,
                             0,1,2,1,2,2};

// workspace byte offsets (total ~8.73 MB)
// keepw (40*16*8 = 5120 B) ALIASES the hist region: hist (as cum) is dead after
// k_select, and k_nms (writer) runs strictly before k_rank (reader) every launch.
static const size_t OFF_KEEPW    = 0;
static const size_t OFF_HIST     = 0;        // 40*2048*4 = 327680 (hist, then cum in-place)
static const size_t OFF_SELCNT   = 327680;   // 40*4
static const size_t OFF_CANDCNT  = 327840;   // 40*4
static const size_t MEMSET_BYTES = 328000;
static const size_t OFF_TBIN     = 328000;   // 40*4
static const size_t OFF_CLESS    = 328160;   // 40*4
static const size_t OFF_SELG     = 328320;   // 40*1024*8  -> 656000
static const size_t OFF_CANDG    = 656000;   // 40*4096*8  -> 1966720
static const size_t OFF_KEYS     = 1966720;  // 8*4741*8   -> 2270144
static const size_t OFF_BOX      = 2270144;  // 8*4741*4*4 -> 2876992
static const size_t OFF_SCORE    = 2876992;  // 8*4741*4   -> 3028704
static const size_t OFF_VALID    = 3028704;  // 8*4741*4   -> 3180416
static const size_t OFF_MASK     = 3180416;  // 8*5*16*1024*8 -> 8423296
static const size_t OFF_OUTK     = 8423296;  // 8*4741*8   -> 8726720

// monotone float<->uint map: fmap ascending in float value
__device__ __forceinline__ u32 fmap(float f){
  u32 b = __float_as_uint(f);
  return (b & 0x80000000u) ? ~b : (b | 0x80000000u);
}
__device__ __forceinline__ float funmap(u32 m){
  return __uint_as_float((m & 0x80000000u) ? (m & 0x7FFFFFFFu) : ~m);
}

// ---------- K1a: per-(b,l) 2048-bin histogram, float4 + 4-way privatized ----------
// 4 LDS histogram copies (one per wave-pair) cut same-address atomic
// serialization 4x for the hot N(0,1) bins; merged once at the end.
__global__ void __launch_bounds__(1024)
k_hist(const float* __restrict__ obj, u32* __restrict__ hist)
{
  int b = blockIdx.x / 33, s = blockIdx.x % 33;
  int l = c_SL[s], start = c_SS[s];
  int cnt = c_LN[l] - start; if (cnt > 8192) cnt = 8192;
  int bl = b * 5 + l;
  __shared__ u32 h[4][2048];   // 32 KiB
  for (int i = threadIdx.x; i < 8192; i += 1024) ((u32*)h)[i] = 0;
  __syncthreads();
  u32* hw = h[(threadIdx.x >> 6) & 3];
  const float* p = obj + (size_t)b * A_TOTAL + c_LOFF[l] + start;
  int head = (4 - (int)(((size_t)p >> 2) & 3)) & 3;
  if (head > cnt) head = cnt;
  if ((int)threadIdx.x < head) atomicAdd(&hw[(~fmap(p[threadIdx.x])) >> 21], 1u);
  int nvec = (cnt - head) >> 2;
  const float4* pv = (const float4*)(p + head);
  for (int i = threadIdx.x; i < nvec; i += 1024){
    float4 v = pv[i];
    atomicAdd(&hw[(~fmap(v.x)) >> 21], 1u);
    atomicAdd(&hw[(~fmap(v.y)) >> 21], 1u);
    atomicAdd(&hw[(~fmap(v.z)) >> 21], 1u);
    atomicAdd(&hw[(~fmap(v.w)) >> 21], 1u);
  }
  int tail0 = head + (nvec << 2);
  int ntail = cnt - tail0;
  if ((int)threadIdx.x < ntail) atomicAdd(&hw[(~fmap(p[tail0 + threadIdx.x])) >> 21], 1u);
  __syncthreads();
  for (int i = threadIdx.x; i < 2048; i += 1024){
    u32 v = h[0][i] + h[1][i] + h[2][i] + h[3][i];
    if (v) atomicAdd(&hist[bl * 2048 + i], v);
  }
}

// ---------- K1b: cutoff bin + IN-PLACE inclusive prefix (hist -> cum) ----------
__global__ void __launch_bounds__(256)
k_cutoff(u32* __restrict__ hist, u32* __restrict__ tbin, u32* __restrict__ cless)
{
  int bl = blockIdx.x; int l = bl % 5;
  int K = c_LK[l], n = c_LN[l];
  int tid = threadIdx.x;
  __shared__ u32 cum[2048];
  __shared__ u32 part[256];
  __shared__ int s_t;
  u32 vals[8]; u32 sum = 0;
  for (int q = 0; q < 8; ++q){ vals[q] = hist[bl * 2048 + tid * 8 + q]; sum += vals[q]; }
  part[tid] = sum;
  __syncthreads();
  for (int off = 1; off < 256; off <<= 1){
    u32 add = (tid >= off) ? part[tid - off] : 0u;
    __syncthreads();
    part[tid] += add;
    __syncthreads();
  }
  u32 run = (tid > 0) ? part[tid - 1] : 0u;
  for (int q = 0; q < 8; ++q){ run += vals[q]; cum[tid * 8 + q] = run; }
  __syncthreads();
  // write cum back over hist (in place; each block owns its slice)
  for (int q = 0; q < 8; ++q) hist[bl * 2048 + tid * 8 + q] = cum[tid * 8 + q];
  if (K >= n){ if (tid == 0){ tbin[bl] = 2048u; cless[bl] = (u32)n; } return; }
  if (tid == 0) s_t = 0;
  __syncthreads();
  for (int q = 0; q < 8; ++q){
    int i = tid * 8 + q;
    u32 c = cum[i], cp = (i > 0) ? cum[i - 1] : 0u;
    if (c >= (u32)K && cp < (u32)K) s_t = i;
  }
  __syncthreads();
  if (tid == 0){
    int t = s_t;
    tbin[bl] = (u32)t;
    cless[bl] = (t > 0) ? cum[t - 1] : 0u;
  }
}

// ---------- K1c: collect via LDS-staged compaction (unchanged from R12) ----------
#define SELCAP 2048
#define CANDCAP 1024
__global__ void __launch_bounds__(1024)
k_collect(const float* __restrict__ obj, const u32* __restrict__ tbin,
          u32* __restrict__ selcnt, u32* __restrict__ candcnt,
          u64* __restrict__ selg, u64* __restrict__ candg)
{
  int b = blockIdx.x / 33, s = blockIdx.x % 33;
  int l = c_SL[s], start = c_SS[s];
  int cnt = c_LN[l] - start; if (cnt > 8192) cnt = 8192;
  int bl = b * 5 + l;
  u32 t = tbin[bl];
  __shared__ u64 lsel[SELCAP];    // 16 KiB
  __shared__ u64 lcand[CANDCAP];  //  8 KiB
  __shared__ u32 lcs, lcc, gbs, gbc;
  if (threadIdx.x == 0){ lcs = 0u; lcc = 0u; }
  __syncthreads();
  const float* p = obj + (size_t)b * A_TOTAL + c_LOFF[l] + start;

  auto push = [&](u32 m, int idx){
    u32 bin = m >> 21;
    u64 key = ((u64)m << 32) | (u32)idx;
    if (bin < t){
      u32 pos = atomicAdd(&lcs, 1u);                       // LDS atomic
      if (pos < SELCAP) lsel[pos] = key;
      else { u32 gp = atomicAdd(&selcnt[bl], 1u); selg[(size_t)bl * 1024 + gp] = key; }
    } else if (bin == t){
      u32 pos = atomicAdd(&lcc, 1u);                       // LDS atomic
      if (pos < CANDCAP) lcand[pos] = key;
      else { u32 gp = atomicAdd(&candcnt[bl], 1u); if (gp < 4096u) candg[(size_t)bl * 4096 + gp] = key; }
    }
  };

  int head = (4 - (int)(((size_t)p >> 2) & 3)) & 3;
  if (head > cnt) head = cnt;
  if ((int)threadIdx.x < head) push(~fmap(p[threadIdx.x]), start + (int)threadIdx.x);
  int nvec = (cnt - head) >> 2;
  const float4* pv = (const float4*)(p + head);
  for (int i = threadIdx.x; i < nvec; i += 1024){
    float4 v = pv[i];
    int e = start + head + (i << 2);
    push(~fmap(v.x), e);
    push(~fmap(v.y), e + 1);
    push(~fmap(v.z), e + 2);
    push(~fmap(v.w), e + 3);
  }
  int tail0 = head + (nvec << 2);
  int ntail = cnt - tail0;
  if ((int)threadIdx.x < ntail) push(~fmap(p[tail0 + threadIdx.x]), start + tail0 + (int)threadIdx.x);
  __syncthreads();
  u32 ns = lcs;  if (ns > SELCAP) ns = SELCAP;
  u32 ncd = lcc; if (ncd > CANDCAP) ncd = CANDCAP;
  if (threadIdx.x == 0){
    gbs = ns  ? atomicAdd(&selcnt[bl],  ns)  : 0u;
    gbc = ncd ? atomicAdd(&candcnt[bl], ncd) : 0u;
  }
  __syncthreads();
  u32 bs = gbs, bc = gbc;
  for (u32 i = threadIdx.x; i < ns; i += 1024)
    selg[(size_t)bl * 1024 + bs + i] = lsel[i];
  for (u32 i = threadIdx.x; i < ncd; i += 1024){
    u32 gp = bc + i;
    if (gp < 4096u) candg[(size_t)bl * 4096 + gp] = lcand[i];
  }
}

// ---------- K1d: histogram-scatter exact top-K (replaces bitonic sorts) ----------
// sel keys (bin < t): global sorted slot = cum[bin-1] + in-bin rank. In-bin rank
// via arrival-scatter into segment-grouped LDS + counting among the segment
// (distinct keys -> bijection). cand keys (bin == t): second-level 11-bit
// sub-histogram + prefix + same scheme -> sorted position among cand; keep the
// first R = K - ns. Output order identical to a full sort.
__global__ void __launch_bounds__(1024)
k_select(const u32* __restrict__ selcnt, const u32* __restrict__ candcnt,
         const u64* __restrict__ selg, const u64* __restrict__ candg,
         const u32* __restrict__ cum_g, u64* __restrict__ keys)
{
  int bl = blockIdx.x; int b = bl / 5, l = bl % 5;
  int K = c_LK[l];
  int tid = threadIdx.x;
  __shared__ u32 cumL[2048];   // 8 KiB
  __shared__ u32 cnt[2048];    // 8 KiB (sel arrivals, then cand sub-cum)
  __shared__ u32 part[256];
  __shared__ u64 selU[1024];   // 8 KiB (later reused as cand arrival counters)
  __shared__ u64 candU[4096];  // 32 KiB
  for (int i = tid; i < 2048; i += 1024){ cumL[i] = cum_g[bl * 2048 + i]; cnt[i] = 0u; }
  __syncthreads();
  u32 ns = selcnt[bl]; if (ns > 1024u) ns = 1024u;
  u32 nc = candcnt[bl]; if (nc > 4096u) nc = 4096u;
  int R = K - (int)ns;
  u64* kout = keys + (size_t)b * KTOT + l * 1000;
  // sel: arrival-scatter into segment-grouped selU
  if (tid < (int)ns){
    u64 key = selg[(size_t)bl * 1024 + tid];
    u32 bin = (u32)(key >> 53);
    u32 lo = bin ? cumL[bin - 1] : 0u;
    u32 a = atomicAdd(&cnt[bin], 1u);
    selU[lo + a] = key;
  }
  __syncthreads();
  // sel: in-segment counting rank -> exact sorted global slot
  if (tid < (int)ns){
    u64 key = selU[tid];
    u32 bin = (u32)(key >> 53);
    u32 lo = bin ? cumL[bin - 1] : 0u;
    u32 hi = cumL[bin];
    u32 r = 0;
    for (u32 j = lo; j < hi; ++j) r += (selU[j] < key) ? 1u : 0u;
    kout[lo + r] = key;
  }
  if (R > 0){
    __syncthreads();
    for (int i = tid; i < 2048; i += 1024) cnt[i] = 0u;
    __syncthreads();
    // pass A: sub-histogram of cand keys' bits [52:42]
    for (u32 i = tid; i < nc; i += 1024){
      u64 key = candg[(size_t)bl * 4096 + i];
      atomicAdd(&cnt[(u32)(key >> 42) & 2047u], 1u);
    }
    __syncthreads();
    // inclusive prefix of cnt in place (256-thread scan; barriers hit by all)
    u32 vals[8]; u32 sum = 0;
    if (tid < 256){
      for (int q = 0; q < 8; ++q){ vals[q] = cnt[tid * 8 + q]; sum += vals[q]; }
      part[tid] = sum;
    }
    __syncthreads();
    for (int off = 1; off < 256; off <<= 1){
      u32 add = (tid < 256 && tid >= off) ? part[tid - off] : 0u;
      __syncthreads();
      if (tid < 256) part[tid] += add;
      __syncthreads();
    }
    if (tid < 256){
      u32 run = tid ? part[tid - 1] : 0u;
      for (int q = 0; q < 8; ++q){ run += vals[q]; cnt[tid * 8 + q] = run; }
    }
    __syncthreads();
    // pass B: arrival scatter into sub-segment-grouped candU (selU reused as counters)
    u32* arr2 = (u32*)selU;
    for (int i = tid; i < 2048; i += 1024) arr2[i] = 0u;
    __syncthreads();
    for (u32 i = tid; i < nc; i += 1024){
      u64 key = candg[(size_t)bl * 4096 + i];
      u32 sb = (u32)(key >> 42) & 2047u;
      u32 lo = sb ? cnt[sb - 1] : 0u;
      u32 a = atomicAdd(&arr2[sb], 1u);
      candU[lo + a] = key;
    }
    __syncthreads();
    // counting rank within sub-segment -> keep positions < R
    for (u32 s = tid; s < nc; s += 1024){
      u64 key = candU[s];
      u32 sb = (u32)(key >> 42) & 2047u;
      u32 lo = sb ? cnt[sb - 1] : 0u;
      u32 hi = cnt[sb];
      u32 r = 0;
      for (u32 j = lo; j < hi; ++j) r += (candU[j] < key) ? 1u : 0u;
      u32 pos = lo + r;
      if (pos < (u32)R) kout[ns + pos] = key;
    }
  }
}

// ---------- K2: gather + decode + clip + sigmoid + validity ----------
__global__ void __launch_bounds__(256)
k_decode(const u64* __restrict__ keys, const float* __restrict__ deltas,
         const float* __restrict__ anchors, float* __restrict__ boxes,
         float* __restrict__ scores, u32* __restrict__ valid)
{
  int g = blockIdx.x * 256 + threadIdx.x;
  if (g >= 8 * KTOT) return;
  int b = g / KTOT, kpos = g % KTOT;
  int l = kpos / 1000; if (l > 4) l = 4;
  u64 key = keys[g];
  u32 idx = (u32)key;
  float o = funmap(~(u32)(key >> 32));
  int ai = c_LOFF[l] + (int)idx;
  const float* a = anchors + (size_t)ai * 4;
  const float* d = deltas + ((size_t)b * A_TOTAL + ai) * 4;
  float a0 = a[0], a1 = a[1], a2 = a[2], a3 = a[3];
  float wa = __fsub_rn(a2, a0), ha = __fsub_rn(a3, a1);
  float cxa = __fadd_rn(a0, __fmul_rn(0.5f, wa));
  float cya = __fadd_rn(a1, __fmul_rn(0.5f, ha));
  float dx = d[0], dy = d[1];
  float dw = fminf(d[2], 4.135166556742356f);   // log(1000/16)
  float dh = fminf(d[3], 4.135166556742356f);
  float cx = __fadd_rn(__fmul_rn(dx, wa), cxa);
  float cy = __fadd_rn(__fmul_rn(dy, ha), cya);
  float w  = __fmul_rn(expf(dw), wa);
  float h  = __fmul_rn(expf(dh), ha);
  float hw = __fmul_rn(0.5f, w), hh = __fmul_rn(0.5f, h);
  float x1 = __fsub_rn(cx, hw), y1 = __fsub_rn(cy, hh);
  float x2 = __fadd_rn(cx, hw), y2 = __fadd_rn(cy, hh);
  x1 = fminf(fmaxf(x1, 0.0f), 1216.0f);
  x2 = fminf(fmaxf(x2, 0.0f), 1216.0f);
  y1 = fminf(fmaxf(y1, 0.0f), 800.0f);
  y2 = fminf(fmaxf(y2, 0.0f), 800.0f);
  float s = __fdiv_rn(1.0f, __fadd_rn(1.0f, expf(-o)));
  int v = (__fsub_rn(x2, x1) >= 0.001f) && (__fsub_rn(y2, y1) >= 0.001f) && (s >= 0.0f);
  float* bo = boxes + (size_t)g * 4;
  bo[0] = x1; bo[1] = y1; bo[2] = x2; bo[3] = y2;
  scores[g] = s;
  valid[g] = (u32)v;
}

// ---------- K3: per-level suppression bitmask, 256x256 upper-tri tiles ----------
__global__ void __launch_bounds__(256)
k_mask(const float* __restrict__ boxes, u64* __restrict__ mask)
{
  int b = blockIdx.x / 46, s = blockIdx.x % 46;
  int l = c_TL[s], it = c_TI[s], jt = c_TJ[s];
  int N = c_LK[l];
  int koff = l * 1000;
  float offv = (float)(l * 4096);   // exact
  __shared__ float4 sxy[256];
  __shared__ float  sar[256];
  int j0 = jt * 256;
  {
    int tj = j0 + (int)threadIdx.x;
    float4 q; float ar;
    if (tj < N){
      float4 p = ((const float4*)boxes)[(size_t)(b * KTOT + koff + tj)];
      q.x = __fadd_rn(p.x, offv); q.y = __fadd_rn(p.y, offv);
      q.z = __fadd_rn(p.z, offv); q.w = __fadd_rn(p.w, offv);
      ar = __fmul_rn(__fsub_rn(q.z, q.x), __fsub_rn(q.w, q.y));
    } else {
      q.x = 3e38f; q.y = 3e38f; q.z = -3e38f; q.w = -3e38f; ar = 0.f;
    }
    sxy[threadIdx.x] = q; sar[threadIdx.x] = ar;
  }
  __syncthreads();
  int i = it * 256 + (int)threadIdx.x;
  if (i >= N) return;
  float4 p = ((const float4*)boxes)[(size_t)(b * KTOT + koff + i)];
  float bx1 = __fadd_rn(p.x, offv), by1 = __fadd_rn(p.y, offv);
  float bx2 = __fadd_rn(p.z, offv), by2 = __fadd_rn(p.w, offv);
  float bar = __fmul_rn(__fsub_rn(bx2, bx1), __fsub_rn(by2, by1));
  u64* mb = mask + ((size_t)(b * 5 + l) * 16) * 1024;
  for (int w = 0; w < 4; ++w){
    int jbase = j0 + w * 64;
    if (jbase >= N) break;
    u64 bw = 0;
    #pragma unroll 16
    for (int jj = 0; jj < 64; ++jj){
      int j = jbase + jj;
      float4 q = sxy[w * 64 + jj];
      float aj = sar[w * 64 + jj];
      float ltx = fmaxf(bx1, q.x), lty = fmaxf(by1, q.y);
      float rbx = fminf(bx2, q.z), rby = fminf(by2, q.w);
      float wx = fmaxf(__fsub_rn(rbx, ltx), 0.0f);
      float wy = fmaxf(__fsub_rn(rby, lty), 0.0f);
      float inter = __fmul_rn(wx, wy);
      bool sup = false;
      if (inter > 0.0f && j > i){
        float den = __fsub_rn(__fadd_rn(bar, aj), inter);
        sup = __fdiv_rn(inter, den) > 0.7f;
      }
      bw |= ((u64)sup) << jj;
    }
    mb[(size_t)(jbase >> 6) * 1024 + i] = bw;
  }
}

// ---------- K4: exact greedy NMS, sparse-conflict fast path ----------
// Also exports the final keep bitmask words (keepw[bl][16]) for k_rank.
__global__ void __launch_bounds__(256)
k_nms(const u64* __restrict__ mask, const u32* __restrict__ valid,
      const float* __restrict__ scores, u64* __restrict__ outk,
      u64* __restrict__ keepw)
{
  int bl = blockIdx.x; int b = bl / 5, l = bl % 5;
  int N = c_LK[l], koff = l * 1000;
  int WN = (N + 63) >> 6;           // 16 (levels 0-3) or 12 (level 4)
  int tid = threadIdx.x;
  __shared__ u64 s_kw[16];
  __shared__ u64 s_m[7680];         // 60 KiB: word w at 64*w*(w+1)/2, rows <(w+1)*64
  const u64* mb = mask + (size_t)bl * 16 * 1024;
  int wstage = (WN < 15) ? WN : 15;
  for (int w = 0; w < wstage; ++w){
    int rows = (w + 1) * 64;
    int base = 32 * w * (w + 1);    // = 64*w*(w+1)/2
    for (int r = tid; r < rows; r += 256)
      s_m[base + r] = mb[(size_t)w * 1024 + r];
  }
  __syncthreads();
  if (tid < 64){
    int lane = tid;
    // keep init = valid
    for (int c = 0; c < WN; ++c){
      int i = c * 64 + lane;
      int pred = (i < N) && (valid[(size_t)b * KTOT + koff + i] != 0u);
      u64 bal = __ballot(pred);
      if (lane == 0) s_kw[c] = bal;
    }
    for (int w = 0; w < WN; ++w){
      u64 kwv = s_kw[w];            // broadcast read (uniform)
      // cross-word suppression of word w's columns from finalized kept rows
      u64 supl = 0;
      if (w < 15){
        int base = 32 * w * (w + 1);
        for (int jb = 0; jb < w; ++jb){
          u64 kb = s_kw[jb];
          u64 m = s_m[base + jb * 64 + lane];            // unconditional ds_read
          supl |= (((kb >> lane) & 1ULL) ? m : 0ULL);
        }
      } else {
        for (int jb = 0; jb < w; ++jb){
          u64 kb = s_kw[jb];
          u64 m = mb[(size_t)w * 1024 + jb * 64 + lane]; // unconditional global
          supl |= (((kb >> lane) & 1ULL) ? m : 0ULL);
        }
      }
      // in-word rows (lane r owns row w*64+r's word-w column bits)
      int jr = w * 64 + lane;
      u64 rowl;
      if (w < 15) rowl = s_m[32 * w * (w + 1) + jr];     // diagonal rows staged
      else        rowl = (jr < N) ? mb[(size_t)w * 1024 + jr] : 0ULL;
      // per-lane in-word conflict contribution (candidates only)
      bool inC = ((kwv >> lane) & 1ULL) != 0ULL;
      u64 rkw = rowl & kwv;
      u64 confl = inC ? rkw : 0ULL;
      // fused OR-reduce of (supl, conf) across 64 lanes
      u32 a0 = (u32)supl, a1 = (u32)(supl >> 32);
      u32 a2 = (u32)confl, a3 = (u32)(confl >> 32);
      for (int off = 32; off; off >>= 1){
        a0 |= __shfl_xor(a0, off);
        a1 |= __shfl_xor(a1, off);
        a2 |= __shfl_xor(a2, off);
        a3 |= __shfl_xor(a3, off);
      }
      supl = ((u64)a1 << 32) | a0;
      u64 conf = ((u64)a3 << 32) | a2;          // union of in-word targets
      u64 srcb = __ballot(inC && (rkw != 0ULL)); // in-word source lanes
      u64 cur = kwv & ~supl;
      u64 kept = cur;
      if (((srcb & cur) != 0ULL) && ((conf & cur) != 0ULL)){
        // serial greedy over conflict-involved bits only
        u32 rowl_lo = (u32)rowl, rowl_hi = (u32)(rowl >> 32);
        u64 act = cur & (srcb | conf);
        while (act){
          int ib  = __ffsll((unsigned long long)act) - 1;  // wave-uniform
          int ibs = __builtin_amdgcn_readfirstlane(ib);
          u64 bit = 1ULL << ibs;
          act &= ~bit;
          if (kept & bit){
            u32 rlo = (u32)__builtin_amdgcn_readlane((int)rowl_lo, ibs);
            u32 rhi = (u32)__builtin_amdgcn_readlane((int)rowl_hi, ibs);
            u64 r   = ((u64)rhi << 32) | rlo;
            kept &= ~r;
            act  &= ~r;
          }
        }
      }
      if (lane == 0) s_kw[w] = kept;
    }
  }
  __syncthreads();
  // export keep words (zero beyond WN so popcounts are exact)
  if (tid < 16) keepw[(size_t)bl * 16 + tid] = (tid < WN) ? s_kw[tid] : 0ULL;
  // emit final-merge keys: (~fmap(score))<<32 | concat_pos ; suppressed -> ~0
  for (int i = tid; i < N; i += 256){
    u64 key = ~0ULL;
    if ((s_kw[i >> 6] >> (i & 63)) & 1ULL){
      float sc = scores[(size_t)b * KTOT + koff + i];
      key = ((u64)(~fmap(sc)) << 32) | (u32)(koff + i);
    }
    outk[(size_t)b * KTOT + koff + i] = key;
  }
}

// ---------- K5: 5-way merge-rank final selection (O(K log K)) ----------
#define CMPN 1024   // per-level compacted list, padded with ~0ULL (kept count <= 1000)
__global__ void __launch_bounds__(256)
k_rank(const u64* __restrict__ outk, const u64* __restrict__ keepw,
       const float* __restrict__ boxes, float* __restrict__ out)
{
  int b = blockIdx.x / 19, chunk = blockIdx.x % 19;
  int tid = threadIdx.x;
  __shared__ u64 cmp[5 * CMPN];   // 40 KiB
  __shared__ u64 kw[80];          // keep words for this image's 5 levels
  for (int i = tid; i < 5 * CMPN; i += 256) cmp[i] = ~0ULL;
  if (tid < 80) kw[tid] = keepw[(size_t)b * 80 + tid];
  __syncthreads();
  // scatter-compact kept keys per level (rank via popcount prefix; no atomics)
  for (int i = tid; i < KTOT; i += 256){
    u64 key = outk[(size_t)b * KTOT + i];
    if (key != ~0ULL){
      int l = i / 1000; if (l > 4) l = 4;
      int li = i - l * 1000;
      int wi = li >> 6, bit = li & 63;
      const u64* kwl = &kw[l * 16];
      int r = __popcll(kwl[wi] & ((1ULL << bit) - 1ULL));
      for (int w = 0; w < wi; ++w) r += __popcll(kwl[w]);
      cmp[l * CMPN + r] = key;
    }
  }
  __syncthreads();
  int i = chunk * 256 + tid;
  if (i >= KTOT) return;
  u64 key = outk[(size_t)b * KTOT + i];
  if (key == ~0ULL) return;     // suppressed / invalid
  int l = i / 1000; if (l > 4) l = 4;
  int li = i - l * 1000;
  int wi = li >> 6, bit = li & 63;
  const u64* kwl = &kw[l * 16];
  int rank = __popcll(kwl[wi] & ((1ULL << bit) - 1ULL));
  for (int w = 0; w < wi; ++w) rank += __popcll(kwl[w]);
  #pragma unroll
  for (int lo = 0; lo < 5; ++lo){
    if (lo == l) continue;
    int pos = 0;
    #pragma unroll
    for (int s = 512; s > 0; s >>= 1)
      if (cmp[lo * CMPN + pos + s - 1] < key) pos += s;
    rank += pos;   // count of kept keys in level lo that are < key
  }
  if (rank < 1000){
    float4 bx = ((const float4*)boxes)[(size_t)(b * KTOT + i)];
    ((float4*)out)[(size_t)(b * 1000 + rank)] = bx;
    out[32000 + b * 1000 + rank] = funmap(~(u32)(key >> 32));
  }
}

extern "C" void kernel_launch(void* const* d_in, const int* in_sizes, int n_in,
                              void* d_out, int out_size, void* d_ws, size_t ws_size,
                              hipStream_t stream)
{
  (void)in_sizes; (void)n_in; (void)ws_size; // needs ~8.73 MB ws
  const float* obj     = (const float*)d_in[0];
  const float* deltas  = (const float*)d_in[1];
  const float* anchors = (const float*)d_in[2];
  float* out = (float*)d_out;
  char* ws = (char*)d_ws;

  u32* hist    = (u32*)(ws + OFF_HIST);    // hist, then cum (in-place)
  u64* keepw   = (u64*)(ws + OFF_KEEPW);   // aliases hist (dead by k_nms time)
  u32* selcnt  = (u32*)(ws + OFF_SELCNT);
  u32* candcnt = (u32*)(ws + OFF_CANDCNT);
  u32* tbin    = (u32*)(ws + OFF_TBIN);
  u32* cless   = (u32*)(ws + OFF_CLESS);
  u64* selg    = (u64*)(ws + OFF_SELG);
  u64* candg   = (u64*)(ws + OFF_CANDG);
  u64* keys    = (u64*)(ws + OFF_KEYS);
  float* boxes = (float*)(ws + OFF_BOX);
  float* score = (float*)(ws + OFF_SCORE);
  u32* valid   = (u32*)(ws + OFF_VALID);
  u64* mask    = (u64*)(ws + OFF_MASK);
  u64* outk    = (u64*)(ws + OFF_OUTK);

  hipMemsetAsync(ws, 0, MEMSET_BYTES, stream);
  hipMemsetAsync(d_out, 0, (size_t)out_size * sizeof(float), stream);
  hipLaunchKernelGGL(k_hist,    dim3(264), dim3(1024), 0, stream, obj, hist);
  hipLaunchKernelGGL(k_cutoff,  dim3(40),  dim3(256),  0, stream, hist, tbin, cless);
  hipLaunchKernelGGL(k_collect, dim3(264), dim3(1024), 0, stream, obj, tbin, selcnt, candcnt, selg, candg);
  hipLaunchKernelGGL(k_select,  dim3(40),  dim3(1024), 0, stream, selcnt, candcnt, selg, candg, hist, keys);
  hipLaunchKernelGGL(k_decode,  dim3(149), dim3(256),  0, stream, keys, deltas, anchors, boxes, score, valid);
  hipLaunchKernelGGL(k_mask,    dim3(368), dim3(256),  0, stream, boxes, mask);
  hipLaunchKernelGGL(k_nms,     dim3(40),  dim3(256),  0, stream, mask, valid, score, outk, keepw);
  hipLaunchKernelGGL(k_rank,    dim3(152), dim3(256),  0, stream, outk, keepw, boxes, out);
}

// Round 16
// 142.795 us; speedup vs baseline: 3.9732x; 1.1449x over previous
//
#include <hip/hip_runtime.h>
#include <stdint.h>

#pragma clang fp contract(off)

typedef unsigned int u32;
typedef unsigned long long u64;

#define A_TOTAL 242991
#define KTOT    4741

// level tables
__constant__ int c_LN[5]   = {182400, 45600, 11400, 2850, 741};
__constant__ int c_LOFF[5] = {0, 182400, 228000, 239400, 242250};
__constant__ int c_LK[5]   = {1000, 1000, 1000, 1000, 741};

// scan segment tables: 33 segments/image of <=8192 elements (23 l0, 6 l1, 2 l2, 1 l3, 1 l4)
__constant__ int c_SL[33] = {0,0,0,0,0,0,0,0,0,0,0,0,0,0,0,0,0,0,0,0,0,0,0,
                             1,1,1,1,1,1, 2,2, 3, 4};
__constant__ int c_SS[33] = {0,8192,16384,24576,32768,40960,49152,57344,65536,
                             73728,81920,90112,98304,106496,114688,122880,131072,
                             139264,147456,155648,163840,172032,180224,
                             0,8192,16384,24576,32768,40960, 0,8192, 0, 0};

// k_mask word-slab tables: per level, for word w the mask rows needed are
// < min(N,(w+1)*64); blocks of 256 rows. (w, rowblock) pairs in order:
// levels 0-3 use all 40 entries; level 4 (WN=12) uses the first 24.
__constant__ int c_MW[40] = {0,1,2,3, 4,4, 5,5, 6,6, 7,7, 8,8,8, 9,9,9,
                             10,10,10, 11,11,11, 12,12,12,12, 13,13,13,13,
                             14,14,14,14, 15,15,15,15};
__constant__ int c_MR[40] = {0,0,0,0, 0,1, 0,1, 0,1, 0,1, 0,1,2, 0,1,2,
                             0,1,2, 0,1,2, 0,1,2,3, 0,1,2,3,
                             0,1,2,3, 0,1,2,3};

// workspace byte offsets (total ~8.73 MB)
// keepw (40*16*8 = 5120 B) ALIASES the hist region: hist (as cum) is dead after
// k_select, and k_nms (writer) runs strictly before k_rank (reader) every launch.
static const size_t OFF_KEEPW    = 0;
static const size_t OFF_HIST     = 0;        // 40*2048*4 = 327680 (hist, then cum in-place)
static const size_t OFF_SELCNT   = 327680;   // 40*4
static const size_t OFF_CANDCNT  = 327840;   // 40*4
static const size_t MEMSET_BYTES = 328000;
static const size_t OFF_TBIN     = 328000;   // 40*4
static const size_t OFF_CLESS    = 328160;   // 40*4
static const size_t OFF_SELG     = 328320;   // 40*1024*8  -> 656000
static const size_t OFF_CANDG    = 656000;   // 40*4096*8  -> 1966720
static const size_t OFF_KEYS     = 1966720;  // 8*4741*8   -> 2270144
static const size_t OFF_BOX      = 2270144;  // 8*4741*4*4 -> 2876992
static const size_t OFF_SCORE    = 2876992;  // 8*4741*4   -> 3028704
static const size_t OFF_VALID    = 3028704;  // 8*4741*4   -> 3180416
static const size_t OFF_MASK     = 3180416;  // 8*5*16*1024*8 -> 8423296
static const size_t OFF_OUTK     = 8423296;  // 8*4741*8   -> 8726720

// monotone float<->uint map: fmap ascending in float value
__device__ __forceinline__ u32 fmap(float f){
  u32 b = __float_as_uint(f);
  return (b & 0x80000000u) ? ~b : (b | 0x80000000u);
}
__device__ __forceinline__ float funmap(u32 m){
  return __uint_as_float((m & 0x80000000u) ? (m & 0x7FFFFFFFu) : ~m);
}

// ---------- K1a: per-(b,l) 2048-bin histogram, float4 + 4-way privatized ----------
__global__ void __launch_bounds__(1024)
k_hist(const float* __restrict__ obj, u32* __restrict__ hist)
{
  int b = blockIdx.x / 33, s = blockIdx.x % 33;
  int l = c_SL[s], start = c_SS[s];
  int cnt = c_LN[l] - start; if (cnt > 8192) cnt = 8192;
  int bl = b * 5 + l;
  __shared__ u32 h[4][2048];   // 32 KiB
  for (int i = threadIdx.x; i < 8192; i += 1024) ((u32*)h)[i] = 0;
  __syncthreads();
  u32* hw = h[(threadIdx.x >> 6) & 3];
  const float* p = obj + (size_t)b * A_TOTAL + c_LOFF[l] + start;
  int head = (4 - (int)(((size_t)p >> 2) & 3)) & 3;
  if (head > cnt) head = cnt;
  if ((int)threadIdx.x < head) atomicAdd(&hw[(~fmap(p[threadIdx.x])) >> 21], 1u);
  int nvec = (cnt - head) >> 2;
  const float4* pv = (const float4*)(p + head);
  for (int i = threadIdx.x; i < nvec; i += 1024){
    float4 v = pv[i];
    atomicAdd(&hw[(~fmap(v.x)) >> 21], 1u);
    atomicAdd(&hw[(~fmap(v.y)) >> 21], 1u);
    atomicAdd(&hw[(~fmap(v.z)) >> 21], 1u);
    atomicAdd(&hw[(~fmap(v.w)) >> 21], 1u);
  }
  int tail0 = head + (nvec << 2);
  int ntail = cnt - tail0;
  if ((int)threadIdx.x < ntail) atomicAdd(&hw[(~fmap(p[tail0 + threadIdx.x])) >> 21], 1u);
  __syncthreads();
  for (int i = threadIdx.x; i < 2048; i += 1024){
    u32 v = h[0][i] + h[1][i] + h[2][i] + h[3][i];
    if (v) atomicAdd(&hist[bl * 2048 + i], v);
  }
}

// ---------- K1b: cutoff bin + IN-PLACE inclusive prefix (hist -> cum) ----------
__global__ void __launch_bounds__(256)
k_cutoff(u32* __restrict__ hist, u32* __restrict__ tbin, u32* __restrict__ cless)
{
  int bl = blockIdx.x; int l = bl % 5;
  int K = c_LK[l], n = c_LN[l];
  int tid = threadIdx.x;
  __shared__ u32 cum[2048];
  __shared__ u32 part[256];
  __shared__ int s_t;
  u32 vals[8]; u32 sum = 0;
  for (int q = 0; q < 8; ++q){ vals[q] = hist[bl * 2048 + tid * 8 + q]; sum += vals[q]; }
  part[tid] = sum;
  __syncthreads();
  for (int off = 1; off < 256; off <<= 1){
    u32 add = (tid >= off) ? part[tid - off] : 0u;
    __syncthreads();
    part[tid] += add;
    __syncthreads();
  }
  u32 run = (tid > 0) ? part[tid - 1] : 0u;
  for (int q = 0; q < 8; ++q){ run += vals[q]; cum[tid * 8 + q] = run; }
  __syncthreads();
  // write cum back over hist (in place; each block owns its slice)
  for (int q = 0; q < 8; ++q) hist[bl * 2048 + tid * 8 + q] = cum[tid * 8 + q];
  if (K >= n){ if (tid == 0){ tbin[bl] = 2048u; cless[bl] = (u32)n; } return; }
  if (tid == 0) s_t = 0;
  __syncthreads();
  for (int q = 0; q < 8; ++q){
    int i = tid * 8 + q;
    u32 c = cum[i], cp = (i > 0) ? cum[i - 1] : 0u;
    if (c >= (u32)K && cp < (u32)K) s_t = i;
  }
  __syncthreads();
  if (tid == 0){
    int t = s_t;
    tbin[bl] = (u32)t;
    cless[bl] = (t > 0) ? cum[t - 1] : 0u;
  }
}

// ---------- K1c: collect via LDS-staged compaction ----------
#define SELCAP 2048
#define CANDCAP 1024
__global__ void __launch_bounds__(1024)
k_collect(const float* __restrict__ obj, const u32* __restrict__ tbin,
          u32* __restrict__ selcnt, u32* __restrict__ candcnt,
          u64* __restrict__ selg, u64* __restrict__ candg)
{
  int b = blockIdx.x / 33, s = blockIdx.x % 33;
  int l = c_SL[s], start = c_SS[s];
  int cnt = c_LN[l] - start; if (cnt > 8192) cnt = 8192;
  int bl = b * 5 + l;
  u32 t = tbin[bl];
  __shared__ u64 lsel[SELCAP];    // 16 KiB
  __shared__ u64 lcand[CANDCAP];  //  8 KiB
  __shared__ u32 lcs, lcc, gbs, gbc;
  if (threadIdx.x == 0){ lcs = 0u; lcc = 0u; }
  __syncthreads();
  const float* p = obj + (size_t)b * A_TOTAL + c_LOFF[l] + start;

  auto push = [&](u32 m, int idx){
    u32 bin = m >> 21;
    u64 key = ((u64)m << 32) | (u32)idx;
    if (bin < t){
      u32 pos = atomicAdd(&lcs, 1u);                       // LDS atomic
      if (pos < SELCAP) lsel[pos] = key;
      else { u32 gp = atomicAdd(&selcnt[bl], 1u); selg[(size_t)bl * 1024 + gp] = key; }
    } else if (bin == t){
      u32 pos = atomicAdd(&lcc, 1u);                       // LDS atomic
      if (pos < CANDCAP) lcand[pos] = key;
      else { u32 gp = atomicAdd(&candcnt[bl], 1u); if (gp < 4096u) candg[(size_t)bl * 4096 + gp] = key; }
    }
  };

  int head = (4 - (int)(((size_t)p >> 2) & 3)) & 3;
  if (head > cnt) head = cnt;
  if ((int)threadIdx.x < head) push(~fmap(p[threadIdx.x]), start + (int)threadIdx.x);
  int nvec = (cnt - head) >> 2;
  const float4* pv = (const float4*)(p + head);
  for (int i = threadIdx.x; i < nvec; i += 1024){
    float4 v = pv[i];
    int e = start + head + (i << 2);
    push(~fmap(v.x), e);
    push(~fmap(v.y), e + 1);
    push(~fmap(v.z), e + 2);
    push(~fmap(v.w), e + 3);
  }
  int tail0 = head + (nvec << 2);
  int ntail = cnt - tail0;
  if ((int)threadIdx.x < ntail) push(~fmap(p[tail0 + threadIdx.x]), start + tail0 + (int)threadIdx.x);
  __syncthreads();
  u32 ns = lcs;  if (ns > SELCAP) ns = SELCAP;
  u32 ncd = lcc; if (ncd > CANDCAP) ncd = CANDCAP;
  if (threadIdx.x == 0){
    gbs = ns  ? atomicAdd(&selcnt[bl],  ns)  : 0u;
    gbc = ncd ? atomicAdd(&candcnt[bl], ncd) : 0u;
  }
  __syncthreads();
  u32 bs = gbs, bc = gbc;
  for (u32 i = threadIdx.x; i < ns; i += 1024)
    selg[(size_t)bl * 1024 + bs + i] = lsel[i];
  for (u32 i = threadIdx.x; i < ncd; i += 1024){
    u32 gp = bc + i;
    if (gp < 4096u) candg[(size_t)bl * 4096 + gp] = lcand[i];
  }
}

// ---------- K1d: histogram-scatter exact top-K ----------
__global__ void __launch_bounds__(1024)
k_select(const u32* __restrict__ selcnt, const u32* __restrict__ candcnt,
         const u64* __restrict__ selg, const u64* __restrict__ candg,
         const u32* __restrict__ cum_g, u64* __restrict__ keys)
{
  int bl = blockIdx.x; int b = bl / 5, l = bl % 5;
  int K = c_LK[l];
  int tid = threadIdx.x;
  __shared__ u32 cumL[2048];   // 8 KiB
  __shared__ u32 cnt[2048];    // 8 KiB (sel arrivals, then cand sub-cum)
  __shared__ u32 part[256];
  __shared__ u64 selU[1024];   // 8 KiB (later reused as cand arrival counters)
  __shared__ u64 candU[4096];  // 32 KiB
  for (int i = tid; i < 2048; i += 1024){ cumL[i] = cum_g[bl * 2048 + i]; cnt[i] = 0u; }
  __syncthreads();
  u32 ns = selcnt[bl]; if (ns > 1024u) ns = 1024u;
  u32 nc = candcnt[bl]; if (nc > 4096u) nc = 4096u;
  int R = K - (int)ns;
  u64* kout = keys + (size_t)b * KTOT + l * 1000;
  // sel: arrival-scatter into segment-grouped selU
  if (tid < (int)ns){
    u64 key = selg[(size_t)bl * 1024 + tid];
    u32 bin = (u32)(key >> 53);
    u32 lo = bin ? cumL[bin - 1] : 0u;
    u32 a = atomicAdd(&cnt[bin], 1u);
    selU[lo + a] = key;
  }
  __syncthreads();
  // sel: in-segment counting rank -> exact sorted global slot
  if (tid < (int)ns){
    u64 key = selU[tid];
    u32 bin = (u32)(key >> 53);
    u32 lo = bin ? cumL[bin - 1] : 0u;
    u32 hi = cumL[bin];
    u32 r = 0;
    for (u32 j = lo; j < hi; ++j) r += (selU[j] < key) ? 1u : 0u;
    kout[lo + r] = key;
  }
  if (R > 0){
    __syncthreads();
    for (int i = tid; i < 2048; i += 1024) cnt[i] = 0u;
    __syncthreads();
    // pass A: sub-histogram of cand keys' bits [52:42]
    for (u32 i = tid; i < nc; i += 1024){
      u64 key = candg[(size_t)bl * 4096 + i];
      atomicAdd(&cnt[(u32)(key >> 42) & 2047u], 1u);
    }
    __syncthreads();
    // inclusive prefix of cnt in place (256-thread scan; barriers hit by all)
    u32 vals[8]; u32 sum = 0;
    if (tid < 256){
      for (int q = 0; q < 8; ++q){ vals[q] = cnt[tid * 8 + q]; sum += vals[q]; }
      part[tid] = sum;
    }
    __syncthreads();
    for (int off = 1; off < 256; off <<= 1){
      u32 add = (tid < 256 && tid >= off) ? part[tid - off] : 0u;
      __syncthreads();
      if (tid < 256) part[tid] += add;
      __syncthreads();
    }
    if (tid < 256){
      u32 run = tid ? part[tid - 1] : 0u;
      for (int q = 0; q < 8; ++q){ run += vals[q]; cnt[tid * 8 + q] = run; }
    }
    __syncthreads();
    // pass B: arrival scatter into sub-segment-grouped candU (selU reused as counters)
    u32* arr2 = (u32*)selU;
    for (int i = tid; i < 2048; i += 1024) arr2[i] = 0u;
    __syncthreads();
    for (u32 i = tid; i < nc; i += 1024){
      u64 key = candg[(size_t)bl * 4096 + i];
      u32 sb = (u32)(key >> 42) & 2047u;
      u32 lo = sb ? cnt[sb - 1] : 0u;
      u32 a = atomicAdd(&arr2[sb], 1u);
      candU[lo + a] = key;
    }
    __syncthreads();
    // counting rank within sub-segment -> keep positions < R
    for (u32 s = tid; s < nc; s += 1024){
      u64 key = candU[s];
      u32 sb = (u32)(key >> 42) & 2047u;
      u32 lo = sb ? cnt[sb - 1] : 0u;
      u32 hi = cnt[sb];
      u32 r = 0;
      for (u32 j = lo; j < hi; ++j) r += (candU[j] < key) ? 1u : 0u;
      u32 pos = lo + r;
      if (pos < (u32)R) kout[ns + pos] = key;
    }
  }
}

// ---------- K2: gather + decode + clip + sigmoid + validity ----------
__global__ void __launch_bounds__(256)
k_decode(const u64* __restrict__ keys, const float* __restrict__ deltas,
         const float* __restrict__ anchors, float* __restrict__ boxes,
         float* __restrict__ scores, u32* __restrict__ valid)
{
  int g = blockIdx.x * 256 + threadIdx.x;
  if (g >= 8 * KTOT) return;
  int b = g / KTOT, kpos = g % KTOT;
  int l = kpos / 1000; if (l > 4) l = 4;
  u64 key = keys[g];
  u32 idx = (u32)key;
  float o = funmap(~(u32)(key >> 32));
  int ai = c_LOFF[l] + (int)idx;
  const float* a = anchors + (size_t)ai * 4;
  const float* d = deltas + ((size_t)b * A_TOTAL + ai) * 4;
  float a0 = a[0], a1 = a[1], a2 = a[2], a3 = a[3];
  float wa = __fsub_rn(a2, a0), ha = __fsub_rn(a3, a1);
  float cxa = __fadd_rn(a0, __fmul_rn(0.5f, wa));
  float cya = __fadd_rn(a1, __fmul_rn(0.5f, ha));
  float dx = d[0], dy = d[1];
  float dw = fminf(d[2], 4.135166556742356f);   // log(1000/16)
  float dh = fminf(d[3], 4.135166556742356f);
  float cx = __fadd_rn(__fmul_rn(dx, wa), cxa);
  float cy = __fadd_rn(__fmul_rn(dy, ha), cya);
  float w  = __fmul_rn(expf(dw), wa);
  float h  = __fmul_rn(expf(dh), ha);
  float hw = __fmul_rn(0.5f, w), hh = __fmul_rn(0.5f, h);
  float x1 = __fsub_rn(cx, hw), y1 = __fsub_rn(cy, hh);
  float x2 = __fadd_rn(cx, hw), y2 = __fadd_rn(cy, hh);
  x1 = fminf(fmaxf(x1, 0.0f), 1216.0f);
  x2 = fminf(fmaxf(x2, 0.0f), 1216.0f);
  y1 = fminf(fmaxf(y1, 0.0f), 800.0f);
  y2 = fminf(fmaxf(y2, 0.0f), 800.0f);
  float s = __fdiv_rn(1.0f, __fadd_rn(1.0f, expf(-o)));
  int v = (__fsub_rn(x2, x1) >= 0.001f) && (__fsub_rn(y2, y1) >= 0.001f) && (s >= 0.0f);
  float* bo = boxes + (size_t)g * 4;
  bo[0] = x1; bo[1] = y1; bo[2] = x2; bo[3] = y2;
  scores[g] = s;
  valid[g] = (u32)v;
}

// ---------- K3: suppression bitmask, 256-row x 64-col (one-word) slabs ----------
// One block per (b, level, word w, rowblock): covers exactly the (row, word)
// entries k_nms reads (rows < min(N,(w+1)*64)). 1472 blocks (4x the tile
// version) fixes the 1.4-waves/SIMD latency bind; j-word boxes are a 1.2 KB
// LDS broadcast. IoU arithmetic bit-identical.
__global__ void __launch_bounds__(256)
k_mask(const float* __restrict__ boxes, u64* __restrict__ mask)
{
  int b = blockIdx.x / 184, s = blockIdx.x % 184;
  int l, idx;
  if (s < 160){ l = s / 40; idx = s % 40; }
  else        { l = 4;      idx = s - 160; }   // level 4: first 24 entries (w<=11)
  int w = c_MW[idx], rb = c_MR[idx];
  int N = c_LK[l];
  int koff = l * 1000;
  float offv = (float)(l * 4096);   // exact
  __shared__ float sjx1[64], sjy1[64], sjx2[64], sjy2[64], sjar[64];
  int jbase = w * 64;
  if (threadIdx.x < 64){
    int j = jbase + (int)threadIdx.x;
    float x1, y1, x2, y2, ar;
    if (j < N){
      float4 p = ((const float4*)boxes)[(size_t)(b * KTOT + koff + j)];
      x1 = __fadd_rn(p.x, offv); y1 = __fadd_rn(p.y, offv);
      x2 = __fadd_rn(p.z, offv); y2 = __fadd_rn(p.w, offv);
      ar = __fmul_rn(__fsub_rn(x2, x1), __fsub_rn(y2, y1));
    } else {
      // sentinel: empty far-away box -> inter = 0 -> never suppresses
      x1 = 3e38f; y1 = 3e38f; x2 = -3e38f; y2 = -3e38f; ar = 0.f;
    }
    sjx1[threadIdx.x] = x1; sjy1[threadIdx.x] = y1;
    sjx2[threadIdx.x] = x2; sjy2[threadIdx.x] = y2; sjar[threadIdx.x] = ar;
  }
  __syncthreads();
  int i = rb * 256 + (int)threadIdx.x;
  int rows = (w + 1) * 64; if (rows > N) rows = N;
  if (i >= rows) return;
  float4 p = ((const float4*)boxes)[(size_t)(b * KTOT + koff + i)];
  float bx1 = __fadd_rn(p.x, offv), by1 = __fadd_rn(p.y, offv);
  float bx2 = __fadd_rn(p.z, offv), by2 = __fadd_rn(p.w, offv);
  float bar = __fmul_rn(__fsub_rn(bx2, bx1), __fsub_rn(by2, by1));
  u64 bw = 0;
  #pragma unroll 16
  for (int jj = 0; jj < 64; ++jj){
    int j = jbase + jj;
    float ltx = fmaxf(bx1, sjx1[jj]), lty = fmaxf(by1, sjy1[jj]);
    float rbx = fminf(bx2, sjx2[jj]), rby = fminf(by2, sjy2[jj]);
    float wx = fmaxf(__fsub_rn(rbx, ltx), 0.0f);
    float wy = fmaxf(__fsub_rn(rby, lty), 0.0f);
    float inter = __fmul_rn(wx, wy);
    bool sup = false;
    if (inter > 0.0f && j > i){
      float den = __fsub_rn(__fadd_rn(bar, sjar[jj]), inter);
      sup = __fdiv_rn(inter, den) > 0.7f;
    }
    bw |= ((u64)sup) << jj;
  }
  mask[((size_t)(b * 5 + l) * 16 + w) * 1024 + i] = bw;
}

// ---------- K4: exact greedy NMS, sparse-conflict fast path ----------
__global__ void __launch_bounds__(256)
k_nms(const u64* __restrict__ mask, const u32* __restrict__ valid,
      const float* __restrict__ scores, u64* __restrict__ outk,
      u64* __restrict__ keepw)
{
  int bl = blockIdx.x; int b = bl / 5, l = bl % 5;
  int N = c_LK[l], koff = l * 1000;
  int WN = (N + 63) >> 6;           // 16 (levels 0-3) or 12 (level 4)
  int tid = threadIdx.x;
  __shared__ u64 s_kw[16];
  __shared__ u64 s_m[7680];         // 60 KiB: word w at 64*w*(w+1)/2, rows <(w+1)*64
  const u64* mb = mask + (size_t)bl * 16 * 1024;
  int wstage = (WN < 15) ? WN : 15;
  for (int w = 0; w < wstage; ++w){
    int rows = (w + 1) * 64;
    int base = 32 * w * (w + 1);    // = 64*w*(w+1)/2
    for (int r = tid; r < rows; r += 256)
      s_m[base + r] = mb[(size_t)w * 1024 + r];
  }
  __syncthreads();
  if (tid < 64){
    int lane = tid;
    // keep init = valid
    for (int c = 0; c < WN; ++c){
      int i = c * 64 + lane;
      int pred = (i < N) && (valid[(size_t)b * KTOT + koff + i] != 0u);
      u64 bal = __ballot(pred);
      if (lane == 0) s_kw[c] = bal;
    }
    for (int w = 0; w < WN; ++w){
      u64 kwv = s_kw[w];            // broadcast read (uniform)
      // cross-word suppression of word w's columns from finalized kept rows
      u64 supl = 0;
      if (w < 15){
        int base = 32 * w * (w + 1);
        for (int jb = 0; jb < w; ++jb){
          u64 kb = s_kw[jb];
          u64 m = s_m[base + jb * 64 + lane];            // unconditional ds_read
          supl |= (((kb >> lane) & 1ULL) ? m : 0ULL);
        }
      } else {
        for (int jb = 0; jb < w; ++jb){
          u64 kb = s_kw[jb];
          u64 m = mb[(size_t)w * 1024 + jb * 64 + lane]; // unconditional global
          supl |= (((kb >> lane) & 1ULL) ? m : 0ULL);
        }
      }
      // in-word rows (lane r owns row w*64+r's word-w column bits)
      int jr = w * 64 + lane;
      u64 rowl;
      if (w < 15) rowl = s_m[32 * w * (w + 1) + jr];     // diagonal rows staged
      else        rowl = (jr < N) ? mb[(size_t)w * 1024 + jr] : 0ULL;
      // per-lane in-word conflict contribution (candidates only)
      bool inC = ((kwv >> lane) & 1ULL) != 0ULL;
      u64 rkw = rowl & kwv;
      u64 confl = inC ? rkw : 0ULL;
      // fused OR-reduce of (supl, conf) across 64 lanes
      u32 a0 = (u32)supl, a1 = (u32)(supl >> 32);
      u32 a2 = (u32)confl, a3 = (u32)(confl >> 32);
      for (int off = 32; off; off >>= 1){
        a0 |= __shfl_xor(a0, off);
        a1 |= __shfl_xor(a1, off);
        a2 |= __shfl_xor(a2, off);
        a3 |= __shfl_xor(a3, off);
      }
      supl = ((u64)a1 << 32) | a0;
      u64 conf = ((u64)a3 << 32) | a2;          // union of in-word targets
      u64 srcb = __ballot(inC && (rkw != 0ULL)); // in-word source lanes
      u64 cur = kwv & ~supl;
      u64 kept = cur;
      if (((srcb & cur) != 0ULL) && ((conf & cur) != 0ULL)){
        // serial greedy over conflict-involved bits only
        u32 rowl_lo = (u32)rowl, rowl_hi = (u32)(rowl >> 32);
        u64 act = cur & (srcb | conf);
        while (act){
          int ib  = __ffsll((unsigned long long)act) - 1;  // wave-uniform
          int ibs = __builtin_amdgcn_readfirstlane(ib);
          u64 bit = 1ULL << ibs;
          act &= ~bit;
          if (kept & bit){
            u32 rlo = (u32)__builtin_amdgcn_readlane((int)rowl_lo, ibs);
            u32 rhi = (u32)__builtin_amdgcn_readlane((int)rowl_hi, ibs);
            u64 r   = ((u64)rhi << 32) | rlo;
            kept &= ~r;
            act  &= ~r;
          }
        }
      }
      if (lane == 0) s_kw[w] = kept;
    }
  }
  __syncthreads();
  // export keep words (zero beyond WN so popcounts are exact)
  if (tid < 16) keepw[(size_t)bl * 16 + tid] = (tid < WN) ? s_kw[tid] : 0ULL;
  // emit final-merge keys: (~fmap(score))<<32 | concat_pos ; suppressed -> ~0
  for (int i = tid; i < N; i += 256){
    u64 key = ~0ULL;
    if ((s_kw[i >> 6] >> (i & 63)) & 1ULL){
      float sc = scores[(size_t)b * KTOT + koff + i];
      key = ((u64)(~fmap(sc)) << 32) | (u32)(koff + i);
    }
    outk[(size_t)b * KTOT + koff + i] = key;
  }
}

// ---------- K5: 5-way merge-rank final selection (O(K log K)) ----------
#define CMPN 1024   // per-level compacted list, padded with ~0ULL (kept count <= 1000)
__global__ void __launch_bounds__(256)
k_rank(const u64* __restrict__ outk, const u64* __restrict__ keepw,
       const float* __restrict__ boxes, float* __restrict__ out)
{
  int b = blockIdx.x / 19, chunk = blockIdx.x % 19;
  int tid = threadIdx.x;
  __shared__ u64 cmp[5 * CMPN];   // 40 KiB
  __shared__ u64 kw[80];          // keep words for this image's 5 levels
  for (int i = tid; i < 5 * CMPN; i += 256) cmp[i] = ~0ULL;
  if (tid < 80) kw[tid] = keepw[(size_t)b * 80 + tid];
  __syncthreads();
  // scatter-compact kept keys per level (rank via popcount prefix; no atomics)
  for (int i = tid; i < KTOT; i += 256){
    u64 key = outk[(size_t)b * KTOT + i];
    if (key != ~0ULL){
      int l = i / 1000; if (l > 4) l = 4;
      int li = i - l * 1000;
      int wi = li >> 6, bit = li & 63;
      const u64* kwl = &kw[l * 16];
      int r = __popcll(kwl[wi] & ((1ULL << bit) - 1ULL));
      for (int w = 0; w < wi; ++w) r += __popcll(kwl[w]);
      cmp[l * CMPN + r] = key;
    }
  }
  __syncthreads();
  int i = chunk * 256 + tid;
  if (i >= KTOT) return;
  u64 key = outk[(size_t)b * KTOT + i];
  if (key == ~0ULL) return;     // suppressed / invalid
  int l = i / 1000; if (l > 4) l = 4;
  int li = i - l * 1000;
  int wi = li >> 6, bit = li & 63;
  const u64* kwl = &kw[l * 16];
  int rank = __popcll(kwl[wi] & ((1ULL << bit) - 1ULL));
  for (int w = 0; w < wi; ++w) rank += __popcll(kwl[w]);
  #pragma unroll
  for (int lo = 0; lo < 5; ++lo){
    if (lo == l) continue;
    int pos = 0;
    #pragma unroll
    for (int s = 512; s > 0; s >>= 1)
      if (cmp[lo * CMPN + pos + s - 1] < key) pos += s;
    rank += pos;   // count of kept keys in level lo that are < key
  }
  if (rank < 1000){
    float4 bx = ((const float4*)boxes)[(size_t)(b * KTOT + i)];
    ((float4*)out)[(size_t)(b * 1000 + rank)] = bx;
    out[32000 + b * 1000 + rank] = funmap(~(u32)(key >> 32));
  }
}

extern "C" void kernel_launch(void* const* d_in, const int* in_sizes, int n_in,
                              void* d_out, int out_size, void* d_ws, size_t ws_size,
                              hipStream_t stream)
{
  (void)in_sizes; (void)n_in; (void)ws_size; // needs ~8.73 MB ws
  const float* obj     = (const float*)d_in[0];
  const float* deltas  = (const float*)d_in[1];
  const float* anchors = (const float*)d_in[2];
  float* out = (float*)d_out;
  char* ws = (char*)d_ws;

  u32* hist    = (u32*)(ws + OFF_HIST);    // hist, then cum (in-place)
  u64* keepw   = (u64*)(ws + OFF_KEEPW);   // aliases hist (dead by k_nms time)
  u32* selcnt  = (u32*)(ws + OFF_SELCNT);
  u32* candcnt = (u32*)(ws + OFF_CANDCNT);
  u32* tbin    = (u32*)(ws + OFF_TBIN);
  u32* cless   = (u32*)(ws + OFF_CLESS);
  u64* selg    = (u64*)(ws + OFF_SELG);
  u64* candg   = (u64*)(ws + OFF_CANDG);
  u64* keys    = (u64*)(ws + OFF_KEYS);
  float* boxes = (float*)(ws + OFF_BOX);
  float* score = (float*)(ws + OFF_SCORE);
  u32* valid   = (u32*)(ws + OFF_VALID);
  u64* mask    = (u64*)(ws + OFF_MASK);
  u64* outk    = (u64*)(ws + OFF_OUTK);

  hipMemsetAsync(ws, 0, MEMSET_BYTES, stream);
  hipMemsetAsync(d_out, 0, (size_t)out_size * sizeof(float), stream);
  hipLaunchKernelGGL(k_hist,    dim3(264),  dim3(1024), 0, stream, obj, hist);
  hipLaunchKernelGGL(k_cutoff,  dim3(40),   dim3(256),  0, stream, hist, tbin, cless);
  hipLaunchKernelGGL(k_collect, dim3(264),  dim3(1024), 0, stream, obj, tbin, selcnt, candcnt, selg, candg);
  hipLaunchKernelGGL(k_select,  dim3(40),   dim3(1024), 0, stream, selcnt, candcnt, selg, candg, hist, keys);
  hipLaunchKernelGGL(k_decode,  dim3(149),  dim3(256),  0, stream, keys, deltas, anchors, boxes, score, valid);
  hipLaunchKernelGGL(k_mask,    dim3(1472), dim3(256),  0, stream, boxes, mask);
  hipLaunchKernelGGL(k_nms,     dim3(40),   dim3(256),  0, stream, mask, valid, score, outk, keepw);
  hipLaunchKernelGGL(k_rank,    dim3(152),  dim3(256),  0, stream, outk, keepw, boxes, out);
}

// Round 17
// 131.383 us; speedup vs baseline: 4.3184x; 1.0869x over previous
//
#include <hip/hip_runtime.h>
#include <stdint.h>

#pragma clang fp contract(off)

typedef unsigned int u32;
typedef unsigned long long u64;

#define A_TOTAL 242991
#define KTOT    4741

// level tables
__constant__ int c_LN[5]   = {182400, 45600, 11400, 2850, 741};
__constant__ int c_LOFF[5] = {0, 182400, 228000, 239400, 242250};
__constant__ int c_LK[5]   = {1000, 1000, 1000, 1000, 741};

// scan segment tables: 33 segments/image of <=8192 elements (23 l0, 6 l1, 2 l2, 1 l3, 1 l4)
__constant__ int c_SL[33] = {0,0,0,0,0,0,0,0,0,0,0,0,0,0,0,0,0,0,0,0,0,0,0,
                             1,1,1,1,1,1, 2,2, 3, 4};
__constant__ int c_SS[33] = {0,8192,16384,24576,32768,40960,49152,57344,65536,
                             73728,81920,90112,98304,106496,114688,122880,131072,
                             139264,147456,155648,163840,172032,180224,
                             0,8192,16384,24576,32768,40960, 0,8192, 0, 0};

// k_mask word-slab tables: per level, for word w the mask rows needed are
// < min(N,(w+1)*64); blocks of 256 rows. (w, rowblock) pairs in order:
// levels 0-3 use all 40 entries; level 4 (WN=12) uses the first 24.
__constant__ int c_MW[40] = {0,1,2,3, 4,4, 5,5, 6,6, 7,7, 8,8,8, 9,9,9,
                             10,10,10, 11,11,11, 12,12,12,12, 13,13,13,13,
                             14,14,14,14, 15,15,15,15};
__constant__ int c_MR[40] = {0,0,0,0, 0,1, 0,1, 0,1, 0,1, 0,1,2, 0,1,2,
                             0,1,2, 0,1,2, 0,1,2,3, 0,1,2,3,
                             0,1,2,3, 0,1,2,3};

// workspace byte offsets (total ~8.73 MB)
// keepw (40*16*8 = 5120 B) ALIASES the hist region: hist is dead after
// k_cutoff, and k_nms (writer) runs strictly before k_rank (reader).
static const size_t OFF_KEEPW    = 0;
static const size_t OFF_HIST     = 0;        // 40*2048*4 = 327680
static const size_t OFF_SELCNT   = 327680;   // 40*4
static const size_t OFF_CANDCNT  = 327840;   // 40*4
static const size_t MEMSET_BYTES = 328000;
static const size_t OFF_TBIN     = 328000;   // 40*4
static const size_t OFF_CLESS    = 328160;   // 40*4
static const size_t OFF_SELG     = 328320;   // 40*1024*8  -> 656000
static const size_t OFF_CANDG    = 656000;   // 40*4096*8  -> 1966720
static const size_t OFF_KEYS     = 1966720;  // 8*4741*8   -> 2270144
static const size_t OFF_BOX      = 2270144;  // 8*4741*4*4 -> 2876992
static const size_t OFF_SCORE    = 2876992;  // 8*4741*4   -> 3028704
static const size_t OFF_VALID    = 3028704;  // 8*4741*4   -> 3180416
static const size_t OFF_MASK     = 3180416;  // 8*5*16*1024*8 -> 8423296
static const size_t OFF_OUTK     = 8423296;  // 8*4741*8   -> 8726720

// monotone float<->uint map: fmap ascending in float value
__device__ __forceinline__ u32 fmap(float f){
  u32 b = __float_as_uint(f);
  return (b & 0x80000000u) ? ~b : (b | 0x80000000u);
}
__device__ __forceinline__ float funmap(u32 m){
  return __uint_as_float((m & 0x80000000u) ? (m & 0x7FFFFFFFu) : ~m);
}

// ---------- K1a: per-(b,l) 2048-bin histogram, float4 + 4-way privatized ----------
__global__ void __launch_bounds__(1024)
k_hist(const float* __restrict__ obj, u32* __restrict__ hist)
{
  int b = blockIdx.x / 33, s = blockIdx.x % 33;
  int l = c_SL[s], start = c_SS[s];
  int cnt = c_LN[l] - start; if (cnt > 8192) cnt = 8192;
  int bl = b * 5 + l;
  __shared__ u32 h[4][2048];   // 32 KiB
  for (int i = threadIdx.x; i < 8192; i += 1024) ((u32*)h)[i] = 0;
  __syncthreads();
  u32* hw = h[(threadIdx.x >> 6) & 3];
  const float* p = obj + (size_t)b * A_TOTAL + c_LOFF[l] + start;
  int head = (4 - (int)(((size_t)p >> 2) & 3)) & 3;
  if (head > cnt) head = cnt;
  if ((int)threadIdx.x < head) atomicAdd(&hw[(~fmap(p[threadIdx.x])) >> 21], 1u);
  int nvec = (cnt - head) >> 2;
  const float4* pv = (const float4*)(p + head);
  for (int i = threadIdx.x; i < nvec; i += 1024){
    float4 v = pv[i];
    atomicAdd(&hw[(~fmap(v.x)) >> 21], 1u);
    atomicAdd(&hw[(~fmap(v.y)) >> 21], 1u);
    atomicAdd(&hw[(~fmap(v.z)) >> 21], 1u);
    atomicAdd(&hw[(~fmap(v.w)) >> 21], 1u);
  }
  int tail0 = head + (nvec << 2);
  int ntail = cnt - tail0;
  if ((int)threadIdx.x < ntail) atomicAdd(&hw[(~fmap(p[tail0 + threadIdx.x])) >> 21], 1u);
  __syncthreads();
  for (int i = threadIdx.x; i < 2048; i += 1024){
    u32 v = h[0][i] + h[1][i] + h[2][i] + h[3][i];
    if (v) atomicAdd(&hist[bl * 2048 + i], v);
  }
}

// ---------- K1b: cutoff bin (prefix kept in LDS; cum no longer exported) ----------
__global__ void __launch_bounds__(256)
k_cutoff(u32* __restrict__ hist, u32* __restrict__ tbin, u32* __restrict__ cless)
{
  int bl = blockIdx.x; int l = bl % 5;
  int K = c_LK[l], n = c_LN[l];
  int tid = threadIdx.x;
  __shared__ u32 cum[2048];
  __shared__ u32 part[256];
  __shared__ int s_t;
  u32 vals[8]; u32 sum = 0;
  for (int q = 0; q < 8; ++q){ vals[q] = hist[bl * 2048 + tid * 8 + q]; sum += vals[q]; }
  part[tid] = sum;
  __syncthreads();
  for (int off = 1; off < 256; off <<= 1){
    u32 add = (tid >= off) ? part[tid - off] : 0u;
    __syncthreads();
    part[tid] += add;
    __syncthreads();
  }
  u32 run = (tid > 0) ? part[tid - 1] : 0u;
  for (int q = 0; q < 8; ++q){ run += vals[q]; cum[tid * 8 + q] = run; }
  __syncthreads();
  if (K >= n){ if (tid == 0){ tbin[bl] = 2048u; cless[bl] = (u32)n; } return; }
  if (tid == 0) s_t = 0;
  __syncthreads();
  for (int q = 0; q < 8; ++q){
    int i = tid * 8 + q;
    u32 c = cum[i], cp = (i > 0) ? cum[i - 1] : 0u;
    if (c >= (u32)K && cp < (u32)K) s_t = i;
  }
  __syncthreads();
  if (tid == 0){
    int t = s_t;
    tbin[bl] = (u32)t;
    cless[bl] = (t > 0) ? cum[t - 1] : 0u;
  }
}

// ---------- K1c: collect via LDS-staged compaction ----------
#define SELCAP 2048
#define CANDCAP 1024
__global__ void __launch_bounds__(1024)
k_collect(const float* __restrict__ obj, const u32* __restrict__ tbin,
          u32* __restrict__ selcnt, u32* __restrict__ candcnt,
          u64* __restrict__ selg, u64* __restrict__ candg)
{
  int b = blockIdx.x / 33, s = blockIdx.x % 33;
  int l = c_SL[s], start = c_SS[s];
  int cnt = c_LN[l] - start; if (cnt > 8192) cnt = 8192;
  int bl = b * 5 + l;
  u32 t = tbin[bl];
  __shared__ u64 lsel[SELCAP];    // 16 KiB
  __shared__ u64 lcand[CANDCAP];  //  8 KiB
  __shared__ u32 lcs, lcc, gbs, gbc;
  if (threadIdx.x == 0){ lcs = 0u; lcc = 0u; }
  __syncthreads();
  const float* p = obj + (size_t)b * A_TOTAL + c_LOFF[l] + start;

  auto push = [&](u32 m, int idx){
    u32 bin = m >> 21;
    u64 key = ((u64)m << 32) | (u32)idx;
    if (bin < t){
      u32 pos = atomicAdd(&lcs, 1u);                       // LDS atomic
      if (pos < SELCAP) lsel[pos] = key;
      else { u32 gp = atomicAdd(&selcnt[bl], 1u); selg[(size_t)bl * 1024 + gp] = key; }
    } else if (bin == t){
      u32 pos = atomicAdd(&lcc, 1u);                       // LDS atomic
      if (pos < CANDCAP) lcand[pos] = key;
      else { u32 gp = atomicAdd(&candcnt[bl], 1u); if (gp < 4096u) candg[(size_t)bl * 4096 + gp] = key; }
    }
  };

  int head = (4 - (int)(((size_t)p >> 2) & 3)) & 3;
  if (head > cnt) head = cnt;
  if ((int)threadIdx.x < head) push(~fmap(p[threadIdx.x]), start + (int)threadIdx.x);
  int nvec = (cnt - head) >> 2;
  const float4* pv = (const float4*)(p + head);
  for (int i = threadIdx.x; i < nvec; i += 1024){
    float4 v = pv[i];
    int e = start + head + (i << 2);
    push(~fmap(v.x), e);
    push(~fmap(v.y), e + 1);
    push(~fmap(v.z), e + 2);
    push(~fmap(v.w), e + 3);
  }
  int tail0 = head + (nvec << 2);
  int ntail = cnt - tail0;
  if ((int)threadIdx.x < ntail) push(~fmap(p[tail0 + threadIdx.x]), start + tail0 + (int)threadIdx.x);
  __syncthreads();
  u32 ns = lcs;  if (ns > SELCAP) ns = SELCAP;
  u32 ncd = lcc; if (ncd > CANDCAP) ncd = CANDCAP;
  if (threadIdx.x == 0){
    gbs = ns  ? atomicAdd(&selcnt[bl],  ns)  : 0u;
    gbc = ncd ? atomicAdd(&candcnt[bl], ncd) : 0u;
  }
  __syncthreads();
  u32 bs = gbs, bc = gbc;
  for (u32 i = threadIdx.x; i < ns; i += 1024)
    selg[(size_t)bl * 1024 + bs + i] = lsel[i];
  for (u32 i = threadIdx.x; i < ncd; i += 1024){
    u32 gp = bc + i;
    if (gp < 4096u) candg[(size_t)bl * 4096 + gp] = lcand[i];
  }
}

// ---------- K1d: flat counting-rank top-K (2 barriers, no atomics) ----------
// All sel keys (bin < t) sort below all cand keys (bin == t). Distinct keys =>
// rank = #{j: key_j < key} is an exact bijection. sel ranks fill kout[0..ns);
// cand keys with rank < R = K - ns fill kout[ns..K). Inner loops read LDS at a
// loop-uniform address (64-lane broadcast, conflict-free).
__global__ void __launch_bounds__(1024)
k_select(const u32* __restrict__ selcnt, const u32* __restrict__ candcnt,
         const u64* __restrict__ selg, const u64* __restrict__ candg,
         u64* __restrict__ keys)
{
  int bl = blockIdx.x; int b = bl / 5, l = bl % 5;
  int K = c_LK[l];
  int tid = threadIdx.x;
  __shared__ __align__(16) u64 selU[1024];     //  8 KiB (padded with ~0)
  __shared__ __align__(16) u64 candU[4098];    // 32 KiB (+pad slot)
  u32 ns = selcnt[bl]; if (ns > 1024u) ns = 1024u;
  u32 nc = candcnt[bl]; if (nc > 4096u) nc = 4096u;
  int R = K - (int)ns;
  selU[tid] = (tid < (int)ns) ? selg[(size_t)bl * 1024 + tid] : ~0ULL;
  for (u32 i = tid; i < nc; i += 1024) candU[i] = candg[(size_t)bl * 4096 + i];
  u32 nce = (nc + 1u) & ~1u;
  if (tid == 0 && nce > nc) candU[nc] = ~0ULL;
  __syncthreads();
  u64* kout = keys + (size_t)b * KTOT + l * 1000;
  // sel rank (fixed 512 broadcast ulonglong2 reads; pads compare false)
  if (tid < (int)ns){
    u64 key = selU[tid];
    u32 r = 0;
    #pragma unroll 8
    for (u32 j = 0; j < 1024; j += 2){
      ulonglong2 v = *reinterpret_cast<const ulonglong2*>(&selU[j]);
      r += (v.x < key) + (v.y < key);
    }
    kout[r] = key;
  }
  // cand rank -> keep positions < R
  if (R > 0){
    for (u32 s = tid; s < nc; s += 1024){
      u64 key = candU[s];
      u32 r = 0;
      #pragma unroll 8
      for (u32 j = 0; j < nce; j += 2){
        ulonglong2 v = *reinterpret_cast<const ulonglong2*>(&candU[j]);
        r += (v.x < key) + (v.y < key);
      }
      if (r < (u32)R) kout[ns + r] = key;
    }
  }
}

// ---------- K2: gather + decode + clip + sigmoid + validity ----------
__global__ void __launch_bounds__(256)
k_decode(const u64* __restrict__ keys, const float* __restrict__ deltas,
         const float* __restrict__ anchors, float* __restrict__ boxes,
         float* __restrict__ scores, u32* __restrict__ valid)
{
  int g = blockIdx.x * 256 + threadIdx.x;
  if (g >= 8 * KTOT) return;
  int b = g / KTOT, kpos = g % KTOT;
  int l = kpos / 1000; if (l > 4) l = 4;
  u64 key = keys[g];
  u32 idx = (u32)key;
  float o = funmap(~(u32)(key >> 32));
  int ai = c_LOFF[l] + (int)idx;
  const float* a = anchors + (size_t)ai * 4;
  const float* d = deltas + ((size_t)b * A_TOTAL + ai) * 4;
  float a0 = a[0], a1 = a[1], a2 = a[2], a3 = a[3];
  float wa = __fsub_rn(a2, a0), ha = __fsub_rn(a3, a1);
  float cxa = __fadd_rn(a0, __fmul_rn(0.5f, wa));
  float cya = __fadd_rn(a1, __fmul_rn(0.5f, ha));
  float dx = d[0], dy = d[1];
  float dw = fminf(d[2], 4.135166556742356f);   // log(1000/16)
  float dh = fminf(d[3], 4.135166556742356f);
  float cx = __fadd_rn(__fmul_rn(dx, wa), cxa);
  float cy = __fadd_rn(__fmul_rn(dy, ha), cya);
  float w  = __fmul_rn(expf(dw), wa);
  float h  = __fmul_rn(expf(dh), ha);
  float hw = __fmul_rn(0.5f, w), hh = __fmul_rn(0.5f, h);
  float x1 = __fsub_rn(cx, hw), y1 = __fsub_rn(cy, hh);
  float x2 = __fadd_rn(cx, hw), y2 = __fadd_rn(cy, hh);
  x1 = fminf(fmaxf(x1, 0.0f), 1216.0f);
  x2 = fminf(fmaxf(x2, 0.0f), 1216.0f);
  y1 = fminf(fmaxf(y1, 0.0f), 800.0f);
  y2 = fminf(fmaxf(y2, 0.0f), 800.0f);
  float s = __fdiv_rn(1.0f, __fadd_rn(1.0f, expf(-o)));
  int v = (__fsub_rn(x2, x1) >= 0.001f) && (__fsub_rn(y2, y1) >= 0.001f) && (s >= 0.0f);
  float* bo = boxes + (size_t)g * 4;
  bo[0] = x1; bo[1] = y1; bo[2] = x2; bo[3] = y2;
  scores[g] = s;
  valid[g] = (u32)v;
}

// ---------- K3: suppression bitmask, 256-row x 64-col (one-word) slabs ----------
__global__ void __launch_bounds__(256)
k_mask(const float* __restrict__ boxes, u64* __restrict__ mask)
{
  int b = blockIdx.x / 184, s = blockIdx.x % 184;
  int l, idx;
  if (s < 160){ l = s / 40; idx = s % 40; }
  else        { l = 4;      idx = s - 160; }   // level 4: first 24 entries (w<=11)
  int w = c_MW[idx], rb = c_MR[idx];
  int N = c_LK[l];
  int koff = l * 1000;
  float offv = (float)(l * 4096);   // exact
  __shared__ float sjx1[64], sjy1[64], sjx2[64], sjy2[64], sjar[64];
  int jbase = w * 64;
  if (threadIdx.x < 64){
    int j = jbase + (int)threadIdx.x;
    float x1, y1, x2, y2, ar;
    if (j < N){
      float4 p = ((const float4*)boxes)[(size_t)(b * KTOT + koff + j)];
      x1 = __fadd_rn(p.x, offv); y1 = __fadd_rn(p.y, offv);
      x2 = __fadd_rn(p.z, offv); y2 = __fadd_rn(p.w, offv);
      ar = __fmul_rn(__fsub_rn(x2, x1), __fsub_rn(y2, y1));
    } else {
      x1 = 3e38f; y1 = 3e38f; x2 = -3e38f; y2 = -3e38f; ar = 0.f;
    }
    sjx1[threadIdx.x] = x1; sjy1[threadIdx.x] = y1;
    sjx2[threadIdx.x] = x2; sjy2[threadIdx.x] = y2; sjar[threadIdx.x] = ar;
  }
  __syncthreads();
  int i = rb * 256 + (int)threadIdx.x;
  int rows = (w + 1) * 64; if (rows > N) rows = N;
  if (i >= rows) return;
  float4 p = ((const float4*)boxes)[(size_t)(b * KTOT + koff + i)];
  float bx1 = __fadd_rn(p.x, offv), by1 = __fadd_rn(p.y, offv);
  float bx2 = __fadd_rn(p.z, offv), by2 = __fadd_rn(p.w, offv);
  float bar = __fmul_rn(__fsub_rn(bx2, bx1), __fsub_rn(by2, by1));
  u64 bw = 0;
  #pragma unroll 16
  for (int jj = 0; jj < 64; ++jj){
    int j = jbase + jj;
    float ltx = fmaxf(bx1, sjx1[jj]), lty = fmaxf(by1, sjy1[jj]);
    float rbx = fminf(bx2, sjx2[jj]), rby = fminf(by2, sjy2[jj]);
    float wx = fmaxf(__fsub_rn(rbx, ltx), 0.0f);
    float wy = fmaxf(__fsub_rn(rby, lty), 0.0f);
    float inter = __fmul_rn(wx, wy);
    bool sup = false;
    if (inter > 0.0f && j > i){
      float den = __fsub_rn(__fadd_rn(bar, sjar[jj]), inter);
      sup = __fdiv_rn(inter, den) > 0.7f;
    }
    bw |= ((u64)sup) << jj;
  }
  mask[((size_t)(b * 5 + l) * 16 + w) * 1024 + i] = bw;
}

// ---------- K4: exact greedy NMS, sparse-conflict fast path ----------
__global__ void __launch_bounds__(256)
k_nms(const u64* __restrict__ mask, const u32* __restrict__ valid,
      const float* __restrict__ scores, u64* __restrict__ outk,
      u64* __restrict__ keepw)
{
  int bl = blockIdx.x; int b = bl / 5, l = bl % 5;
  int N = c_LK[l], koff = l * 1000;
  int WN = (N + 63) >> 6;           // 16 (levels 0-3) or 12 (level 4)
  int tid = threadIdx.x;
  __shared__ u64 s_kw[16];
  __shared__ u64 s_m[7680];         // 60 KiB: word w at 64*w*(w+1)/2, rows <(w+1)*64
  const u64* mb = mask + (size_t)bl * 16 * 1024;
  int wstage = (WN < 15) ? WN : 15;
  for (int w = 0; w < wstage; ++w){
    int rows = (w + 1) * 64;
    int base = 32 * w * (w + 1);    // = 64*w*(w+1)/2
    for (int r = tid; r < rows; r += 256)
      s_m[base + r] = mb[(size_t)w * 1024 + r];
  }
  __syncthreads();
  if (tid < 64){
    int lane = tid;
    // keep init = valid
    for (int c = 0; c < WN; ++c){
      int i = c * 64 + lane;
      int pred = (i < N) && (valid[(size_t)b * KTOT + koff + i] != 0u);
      u64 bal = __ballot(pred);
      if (lane == 0) s_kw[c] = bal;
    }
    for (int w = 0; w < WN; ++w){
      u64 kwv = s_kw[w];            // broadcast read (uniform)
      // cross-word suppression of word w's columns from finalized kept rows
      u64 supl = 0;
      if (w < 15){
        int base = 32 * w * (w + 1);
        for (int jb = 0; jb < w; ++jb){
          u64 kb = s_kw[jb];
          u64 m = s_m[base + jb * 64 + lane];            // unconditional ds_read
          supl |= (((kb >> lane) & 1ULL) ? m : 0ULL);
        }
      } else {
        for (int jb = 0; jb < w; ++jb){
          u64 kb = s_kw[jb];
          u64 m = mb[(size_t)w * 1024 + jb * 64 + lane]; // unconditional global
          supl |= (((kb >> lane) & 1ULL) ? m : 0ULL);
        }
      }
      // in-word rows (lane r owns row w*64+r's word-w column bits)
      int jr = w * 64 + lane;
      u64 rowl;
      if (w < 15) rowl = s_m[32 * w * (w + 1) + jr];     // diagonal rows staged
      else        rowl = (jr < N) ? mb[(size_t)w * 1024 + jr] : 0ULL;
      // per-lane in-word conflict contribution (candidates only)
      bool inC = ((kwv >> lane) & 1ULL) != 0ULL;
      u64 rkw = rowl & kwv;
      u64 confl = inC ? rkw : 0ULL;
      // fused OR-reduce of (supl, conf) across 64 lanes
      u32 a0 = (u32)supl, a1 = (u32)(supl >> 32);
      u32 a2 = (u32)confl, a3 = (u32)(confl >> 32);
      for (int off = 32; off; off >>= 1){
        a0 |= __shfl_xor(a0, off);
        a1 |= __shfl_xor(a1, off);
        a2 |= __shfl_xor(a2, off);
        a3 |= __shfl_xor(a3, off);
      }
      supl = ((u64)a1 << 32) | a0;
      u64 conf = ((u64)a3 << 32) | a2;          // union of in-word targets
      u64 srcb = __ballot(inC && (rkw != 0ULL)); // in-word source lanes
      u64 cur = kwv & ~supl;
      u64 kept = cur;
      if (((srcb & cur) != 0ULL) && ((conf & cur) != 0ULL)){
        // serial greedy over conflict-involved bits only
        u32 rowl_lo = (u32)rowl, rowl_hi = (u32)(rowl >> 32);
        u64 act = cur & (srcb | conf);
        while (act){
          int ib  = __ffsll((unsigned long long)act) - 1;  // wave-uniform
          int ibs = __builtin_amdgcn_readfirstlane(ib);
          u64 bit = 1ULL << ibs;
          act &= ~bit;
          if (kept & bit){
            u32 rlo = (u32)__builtin_amdgcn_readlane((int)rowl_lo, ibs);
            u32 rhi = (u32)__builtin_amdgcn_readlane((int)rowl_hi, ibs);
            u64 r   = ((u64)rhi << 32) | rlo;
            kept &= ~r;
            act  &= ~r;
          }
        }
      }
      if (lane == 0) s_kw[w] = kept;
    }
  }
  __syncthreads();
  // export keep words (zero beyond WN so popcounts are exact)
  if (tid < 16) keepw[(size_t)bl * 16 + tid] = (tid < WN) ? s_kw[tid] : 0ULL;
  // emit final-merge keys: (~fmap(score))<<32 | concat_pos ; suppressed -> ~0
  for (int i = tid; i < N; i += 256){
    u64 key = ~0ULL;
    if ((s_kw[i >> 6] >> (i & 63)) & 1ULL){
      float sc = scores[(size_t)b * KTOT + koff + i];
      key = ((u64)(~fmap(sc)) << 32) | (u32)(koff + i);
    }
    outk[(size_t)b * KTOT + koff + i] = key;
  }
}

// ---------- K5: 5-way merge-rank final selection (O(K log K)) ----------
#define CMPN 1024   // per-level compacted list, padded with ~0ULL (kept count <= 1000)
__global__ void __launch_bounds__(256)
k_rank(const u64* __restrict__ outk, const u64* __restrict__ keepw,
       const float* __restrict__ boxes, float* __restrict__ out)
{
  int b = blockIdx.x / 19, chunk = blockIdx.x % 19;
  int tid = threadIdx.x;
  __shared__ u64 cmp[5 * CMPN];   // 40 KiB
  __shared__ u64 kw[80];          // keep words for this image's 5 levels
  for (int i = tid; i < 5 * CMPN; i += 256) cmp[i] = ~0ULL;
  if (tid < 80) kw[tid] = keepw[(size_t)b * 80 + tid];
  __syncthreads();
  // scatter-compact kept keys per level (rank via popcount prefix; no atomics)
  for (int i = tid; i < KTOT; i += 256){
    u64 key = outk[(size_t)b * KTOT + i];
    if (key != ~0ULL){
      int l = i / 1000; if (l > 4) l = 4;
      int li = i - l * 1000;
      int wi = li >> 6, bit = li & 63;
      const u64* kwl = &kw[l * 16];
      int r = __popcll(kwl[wi] & ((1ULL << bit) - 1ULL));
      for (int w = 0; w < wi; ++w) r += __popcll(kwl[w]);
      cmp[l * CMPN + r] = key;
    }
  }
  __syncthreads();
  int i = chunk * 256 + tid;
  if (i >= KTOT) return;
  u64 key = outk[(size_t)b * KTOT + i];
  if (key == ~0ULL) return;     // suppressed / invalid
  int l = i / 1000; if (l > 4) l = 4;
  int li = i - l * 1000;
  int wi = li >> 6, bit = li & 63;
  const u64* kwl = &kw[l * 16];
  int rank = __popcll(kwl[wi] & ((1ULL << bit) - 1ULL));
  for (int w = 0; w < wi; ++w) rank += __popcll(kwl[w]);
  #pragma unroll
  for (int lo = 0; lo < 5; ++lo){
    if (lo == l) continue;
    int pos = 0;
    #pragma unroll
    for (int s = 512; s > 0; s >>= 1)
      if (cmp[lo * CMPN + pos + s - 1] < key) pos += s;
    rank += pos;   // count of kept keys in level lo that are < key
  }
  if (rank < 1000){
    float4 bx = ((const float4*)boxes)[(size_t)(b * KTOT + i)];
    ((float4*)out)[(size_t)(b * 1000 + rank)] = bx;
    out[32000 + b * 1000 + rank] = funmap(~(u32)(key >> 32));
  }
}

extern "C" void kernel_launch(void* const* d_in, const int* in_sizes, int n_in,
                              void* d_out, int out_size, void* d_ws, size_t ws_size,
                              hipStream_t stream)
{
  (void)in_sizes; (void)n_in; (void)ws_size; // needs ~8.73 MB ws
  const float* obj     = (const float*)d_in[0];
  const float* deltas  = (const float*)d_in[1];
  const float* anchors = (const float*)d_in[2];
  float* out = (float*)d_out;
  char* ws = (char*)d_ws;

  u32* hist    = (u32*)(ws + OFF_HIST);
  u64* keepw   = (u64*)(ws + OFF_KEEPW);   // aliases hist (dead by k_nms time)
  u32* selcnt  = (u32*)(ws + OFF_SELCNT);
  u32* candcnt = (u32*)(ws + OFF_CANDCNT);
  u32* tbin    = (u32*)(ws + OFF_TBIN);
  u32* cless   = (u32*)(ws + OFF_CLESS);
  u64* selg    = (u64*)(ws + OFF_SELG);
  u64* candg   = (u64*)(ws + OFF_CANDG);
  u64* keys    = (u64*)(ws + OFF_KEYS);
  float* boxes = (float*)(ws + OFF_BOX);
  float* score = (float*)(ws + OFF_SCORE);
  u32* valid   = (u32*)(ws + OFF_VALID);
  u64* mask    = (u64*)(ws + OFF_MASK);
  u64* outk    = (u64*)(ws + OFF_OUTK);

  hipMemsetAsync(ws, 0, MEMSET_BYTES, stream);
  hipMemsetAsync(d_out, 0, (size_t)out_size * sizeof(float), stream);
  hipLaunchKernelGGL(k_hist,    dim3(264),  dim3(1024), 0, stream, obj, hist);
  hipLaunchKernelGGL(k_cutoff,  dim3(40),   dim3(256),  0, stream, hist, tbin, cless);
  hipLaunchKernelGGL(k_collect, dim3(264),  dim3(1024), 0, stream, obj, tbin, selcnt, candcnt, selg, candg);
  hipLaunchKernelGGL(k_select,  dim3(40),   dim3(1024), 0, stream, selcnt, candcnt, selg, candg, keys);
  hipLaunchKernelGGL(k_decode,  dim3(149),  dim3(256),  0, stream, keys, deltas, anchors, boxes, score, valid);
  hipLaunchKernelGGL(k_mask,    dim3(1472), dim3(256),  0, stream, boxes, mask);
  hipLaunchKernelGGL(k_nms,     dim3(40),   dim3(256),  0, stream, mask, valid, score, outk, keepw);
  hipLaunchKernelGGL(k_rank,    dim3(152),  dim3(256),  0, stream, outk, keepw, boxes, out);
}

// Round 18
// 129.724 us; speedup vs baseline: 4.3736x; 1.0128x over previous
//
#include <hip/hip_runtime.h>
#include <stdint.h>

#pragma clang fp contract(off)

typedef unsigned int u32;
typedef unsigned long long u64;

#define A_TOTAL 242991
#define KTOT    4741

// level tables
__constant__ int c_LN[5]   = {182400, 45600, 11400, 2850, 741};
__constant__ int c_LOFF[5] = {0, 182400, 228000, 239400, 242250};
__constant__ int c_LK[5]   = {1000, 1000, 1000, 1000, 741};

// scan segment tables: 33 segments/image of <=8192 elements (23 l0, 6 l1, 2 l2, 1 l3, 1 l4)
__constant__ int c_SL[33] = {0,0,0,0,0,0,0,0,0,0,0,0,0,0,0,0,0,0,0,0,0,0,0,
                             1,1,1,1,1,1, 2,2, 3, 4};
__constant__ int c_SS[33] = {0,8192,16384,24576,32768,40960,49152,57344,65536,
                             73728,81920,90112,98304,106496,114688,122880,131072,
                             139264,147456,155648,163840,172032,180224,
                             0,8192,16384,24576,32768,40960, 0,8192, 0, 0};

// k_mask word-slab tables: per level, for word w the mask rows needed are
// < min(N,(w+1)*64); blocks of 256 rows. (w, rowblock) pairs in order:
// levels 0-3 use all 40 entries; level 4 (WN=12) uses the first 24.
__constant__ int c_MW[40] = {0,1,2,3, 4,4, 5,5, 6,6, 7,7, 8,8,8, 9,9,9,
                             10,10,10, 11,11,11, 12,12,12,12, 13,13,13,13,
                             14,14,14,14, 15,15,15,15};
__constant__ int c_MR[40] = {0,0,0,0, 0,1, 0,1, 0,1, 0,1, 0,1,2, 0,1,2,
                             0,1,2, 0,1,2, 0,1,2,3, 0,1,2,3,
                             0,1,2,3, 0,1,2,3};

// workspace byte offsets (total ~8.73 MB)
// keepw (40*16*8 = 5120 B) ALIASES the hist region: hist is dead after
// k_cutoff, and k_nms (writer) runs strictly before k_rank (reader).
static const size_t OFF_KEEPW    = 0;
static const size_t OFF_HIST     = 0;        // 40*2048*4 = 327680
static const size_t OFF_SELCNT   = 327680;   // 40*4
static const size_t OFF_CANDCNT  = 327840;   // 40*4
// zero-init region: [0, 328000) = 82000 u32 words (hist + selcnt + candcnt)
static const size_t OFF_TBIN     = 328000;   // 40*4
static const size_t OFF_CLESS    = 328160;   // 40*4
static const size_t OFF_SELG     = 328320;   // 40*1024*8  -> 656000
static const size_t OFF_CANDG    = 656000;   // 40*4096*8  -> 1966720
static const size_t OFF_KEYS     = 1966720;  // 8*4741*8   -> 2270144
static const size_t OFF_BOX      = 2270144;  // 8*4741*4*4 -> 2876992
static const size_t OFF_SCORE    = 2876992;  // 8*4741*4   -> 3028704
static const size_t OFF_VALID    = 3028704;  // 8*4741*4   -> 3180416
static const size_t OFF_MASK     = 3180416;  // 8*5*16*1024*8 -> 8423296
static const size_t OFF_OUTK     = 8423296;  // 8*4741*8   -> 8726720

// monotone float<->uint map: fmap ascending in float value
__device__ __forceinline__ u32 fmap(float f){
  u32 b = __float_as_uint(f);
  return (b & 0x80000000u) ? ~b : (b | 0x80000000u);
}
__device__ __forceinline__ float funmap(u32 m){
  return __uint_as_float((m & 0x80000000u) ? (m & 0x7FFFFFFFu) : ~m);
}

// ---------- K0: fused zero-init (replaces two pathological runtime fills) ----------
// Zeroes ws words [0, 82000) = hist+selcnt+candcnt, and d_out's 40000 floats.
// The rocclr fillBufferAligned dispatches measured ~41 us EACH for these tiny
// regions; this single coalesced kernel does both in ~2-3 us.
#define ZWS  82000
#define ZOUT 40000
__global__ void __launch_bounds__(256)
k_zero(u32* __restrict__ ws0, u32* __restrict__ outw)
{
  int i = blockIdx.x * 256 + (int)threadIdx.x;
  if (i < ZWS) ws0[i] = 0u;
  else {
    int j = i - ZWS;
    if (j < ZOUT) outw[j] = 0u;
  }
}

// ---------- K1a: per-(b,l) 2048-bin histogram, float4 + 4-way privatized ----------
__global__ void __launch_bounds__(1024)
k_hist(const float* __restrict__ obj, u32* __restrict__ hist)
{
  int b = blockIdx.x / 33, s = blockIdx.x % 33;
  int l = c_SL[s], start = c_SS[s];
  int cnt = c_LN[l] - start; if (cnt > 8192) cnt = 8192;
  int bl = b * 5 + l;
  __shared__ u32 h[4][2048];   // 32 KiB
  for (int i = threadIdx.x; i < 8192; i += 1024) ((u32*)h)[i] = 0;
  __syncthreads();
  u32* hw = h[(threadIdx.x >> 6) & 3];
  const float* p = obj + (size_t)b * A_TOTAL + c_LOFF[l] + start;
  int head = (4 - (int)(((size_t)p >> 2) & 3)) & 3;
  if (head > cnt) head = cnt;
  if ((int)threadIdx.x < head) atomicAdd(&hw[(~fmap(p[threadIdx.x])) >> 21], 1u);
  int nvec = (cnt - head) >> 2;
  const float4* pv = (const float4*)(p + head);
  for (int i = threadIdx.x; i < nvec; i += 1024){
    float4 v = pv[i];
    atomicAdd(&hw[(~fmap(v.x)) >> 21], 1u);
    atomicAdd(&hw[(~fmap(v.y)) >> 21], 1u);
    atomicAdd(&hw[(~fmap(v.z)) >> 21], 1u);
    atomicAdd(&hw[(~fmap(v.w)) >> 21], 1u);
  }
  int tail0 = head + (nvec << 2);
  int ntail = cnt - tail0;
  if ((int)threadIdx.x < ntail) atomicAdd(&hw[(~fmap(p[tail0 + threadIdx.x])) >> 21], 1u);
  __syncthreads();
  for (int i = threadIdx.x; i < 2048; i += 1024){
    u32 v = h[0][i] + h[1][i] + h[2][i] + h[3][i];
    if (v) atomicAdd(&hist[bl * 2048 + i], v);
  }
}

// ---------- K1b: cutoff bin ----------
__global__ void __launch_bounds__(256)
k_cutoff(u32* __restrict__ hist, u32* __restrict__ tbin, u32* __restrict__ cless)
{
  int bl = blockIdx.x; int l = bl % 5;
  int K = c_LK[l], n = c_LN[l];
  int tid = threadIdx.x;
  __shared__ u32 cum[2048];
  __shared__ u32 part[256];
  __shared__ int s_t;
  u32 vals[8]; u32 sum = 0;
  for (int q = 0; q < 8; ++q){ vals[q] = hist[bl * 2048 + tid * 8 + q]; sum += vals[q]; }
  part[tid] = sum;
  __syncthreads();
  for (int off = 1; off < 256; off <<= 1){
    u32 add = (tid >= off) ? part[tid - off] : 0u;
    __syncthreads();
    part[tid] += add;
    __syncthreads();
  }
  u32 run = (tid > 0) ? part[tid - 1] : 0u;
  for (int q = 0; q < 8; ++q){ run += vals[q]; cum[tid * 8 + q] = run; }
  __syncthreads();
  if (K >= n){ if (tid == 0){ tbin[bl] = 2048u; cless[bl] = (u32)n; } return; }
  if (tid == 0) s_t = 0;
  __syncthreads();
  for (int q = 0; q < 8; ++q){
    int i = tid * 8 + q;
    u32 c = cum[i], cp = (i > 0) ? cum[i - 1] : 0u;
    if (c >= (u32)K && cp < (u32)K) s_t = i;
  }
  __syncthreads();
  if (tid == 0){
    int t = s_t;
    tbin[bl] = (u32)t;
    cless[bl] = (t > 0) ? cum[t - 1] : 0u;
  }
}

// ---------- K1c: collect via LDS-staged compaction ----------
#define SELCAP 2048
#define CANDCAP 1024
__global__ void __launch_bounds__(1024)
k_collect(const float* __restrict__ obj, const u32* __restrict__ tbin,
          u32* __restrict__ selcnt, u32* __restrict__ candcnt,
          u64* __restrict__ selg, u64* __restrict__ candg)
{
  int b = blockIdx.x / 33, s = blockIdx.x % 33;
  int l = c_SL[s], start = c_SS[s];
  int cnt = c_LN[l] - start; if (cnt > 8192) cnt = 8192;
  int bl = b * 5 + l;
  u32 t = tbin[bl];
  __shared__ u64 lsel[SELCAP];    // 16 KiB
  __shared__ u64 lcand[CANDCAP];  //  8 KiB
  __shared__ u32 lcs, lcc, gbs, gbc;
  if (threadIdx.x == 0){ lcs = 0u; lcc = 0u; }
  __syncthreads();
  const float* p = obj + (size_t)b * A_TOTAL + c_LOFF[l] + start;

  auto push = [&](u32 m, int idx){
    u32 bin = m >> 21;
    u64 key = ((u64)m << 32) | (u32)idx;
    if (bin < t){
      u32 pos = atomicAdd(&lcs, 1u);                       // LDS atomic
      if (pos < SELCAP) lsel[pos] = key;
      else { u32 gp = atomicAdd(&selcnt[bl], 1u); selg[(size_t)bl * 1024 + gp] = key; }
    } else if (bin == t){
      u32 pos = atomicAdd(&lcc, 1u);                       // LDS atomic
      if (pos < CANDCAP) lcand[pos] = key;
      else { u32 gp = atomicAdd(&candcnt[bl], 1u); if (gp < 4096u) candg[(size_t)bl * 4096 + gp] = key; }
    }
  };

  int head = (4 - (int)(((size_t)p >> 2) & 3)) & 3;
  if (head > cnt) head = cnt;
  if ((int)threadIdx.x < head) push(~fmap(p[threadIdx.x]), start + (int)threadIdx.x);
  int nvec = (cnt - head) >> 2;
  const float4* pv = (const float4*)(p + head);
  for (int i = threadIdx.x; i < nvec; i += 1024){
    float4 v = pv[i];
    int e = start + head + (i << 2);
    push(~fmap(v.x), e);
    push(~fmap(v.y), e + 1);
    push(~fmap(v.z), e + 2);
    push(~fmap(v.w), e + 3);
  }
  int tail0 = head + (nvec << 2);
  int ntail = cnt - tail0;
  if ((int)threadIdx.x < ntail) push(~fmap(p[tail0 + threadIdx.x]), start + tail0 + (int)threadIdx.x);
  __syncthreads();
  u32 ns = lcs;  if (ns > SELCAP) ns = SELCAP;
  u32 ncd = lcc; if (ncd > CANDCAP) ncd = CANDCAP;
  if (threadIdx.x == 0){
    gbs = ns  ? atomicAdd(&selcnt[bl],  ns)  : 0u;
    gbc = ncd ? atomicAdd(&candcnt[bl], ncd) : 0u;
  }
  __syncthreads();
  u32 bs = gbs, bc = gbc;
  for (u32 i = threadIdx.x; i < ns; i += 1024)
    selg[(size_t)bl * 1024 + bs + i] = lsel[i];
  for (u32 i = threadIdx.x; i < ncd; i += 1024){
    u32 gp = bc + i;
    if (gp < 4096u) candg[(size_t)bl * 4096 + gp] = lcand[i];
  }
}

// ---------- K1d: flat counting-rank top-K (2 barriers, no atomics) ----------
__global__ void __launch_bounds__(1024)
k_select(const u32* __restrict__ selcnt, const u32* __restrict__ candcnt,
         const u64* __restrict__ selg, const u64* __restrict__ candg,
         u64* __restrict__ keys)
{
  int bl = blockIdx.x; int b = bl / 5, l = bl % 5;
  int K = c_LK[l];
  int tid = threadIdx.x;
  __shared__ __align__(16) u64 selU[1024];     //  8 KiB (padded with ~0)
  __shared__ __align__(16) u64 candU[4098];    // 32 KiB (+pad slot)
  u32 ns = selcnt[bl]; if (ns > 1024u) ns = 1024u;
  u32 nc = candcnt[bl]; if (nc > 4096u) nc = 4096u;
  int R = K - (int)ns;
  selU[tid] = (tid < (int)ns) ? selg[(size_t)bl * 1024 + tid] : ~0ULL;
  for (u32 i = tid; i < nc; i += 1024) candU[i] = candg[(size_t)bl * 4096 + i];
  u32 nce = (nc + 1u) & ~1u;
  if (tid == 0 && nce > nc) candU[nc] = ~0ULL;
  __syncthreads();
  u64* kout = keys + (size_t)b * KTOT + l * 1000;
  // sel rank (fixed 512 broadcast ulonglong2 reads; pads compare false)
  if (tid < (int)ns){
    u64 key = selU[tid];
    u32 r = 0;
    #pragma unroll 8
    for (u32 j = 0; j < 1024; j += 2){
      ulonglong2 v = *reinterpret_cast<const ulonglong2*>(&selU[j]);
      r += (v.x < key) + (v.y < key);
    }
    kout[r] = key;
  }
  // cand rank -> keep positions < R
  if (R > 0){
    for (u32 s = tid; s < nc; s += 1024){
      u64 key = candU[s];
      u32 r = 0;
      #pragma unroll 8
      for (u32 j = 0; j < nce; j += 2){
        ulonglong2 v = *reinterpret_cast<const ulonglong2*>(&candU[j]);
        r += (v.x < key) + (v.y < key);
      }
      if (r < (u32)R) kout[ns + r] = key;
    }
  }
}

// ---------- K2: gather + decode + clip + sigmoid + validity ----------
__global__ void __launch_bounds__(256)
k_decode(const u64* __restrict__ keys, const float* __restrict__ deltas,
         const float* __restrict__ anchors, float* __restrict__ boxes,
         float* __restrict__ scores, u32* __restrict__ valid)
{
  int g = blockIdx.x * 256 + threadIdx.x;
  if (g >= 8 * KTOT) return;
  int b = g / KTOT, kpos = g % KTOT;
  int l = kpos / 1000; if (l > 4) l = 4;
  u64 key = keys[g];
  u32 idx = (u32)key;
  float o = funmap(~(u32)(key >> 32));
  int ai = c_LOFF[l] + (int)idx;
  const float* a = anchors + (size_t)ai * 4;
  const float* d = deltas + ((size_t)b * A_TOTAL + ai) * 4;
  float a0 = a[0], a1 = a[1], a2 = a[2], a3 = a[3];
  float wa = __fsub_rn(a2, a0), ha = __fsub_rn(a3, a1);
  float cxa = __fadd_rn(a0, __fmul_rn(0.5f, wa));
  float cya = __fadd_rn(a1, __fmul_rn(0.5f, ha));
  float dx = d[0], dy = d[1];
  float dw = fminf(d[2], 4.135166556742356f);   // log(1000/16)
  float dh = fminf(d[3], 4.135166556742356f);
  float cx = __fadd_rn(__fmul_rn(dx, wa), cxa);
  float cy = __fadd_rn(__fmul_rn(dy, ha), cya);
  float w  = __fmul_rn(expf(dw), wa);
  float h  = __fmul_rn(expf(dh), ha);
  float hw = __fmul_rn(0.5f, w), hh = __fmul_rn(0.5f, h);
  float x1 = __fsub_rn(cx, hw), y1 = __fsub_rn(cy, hh);
  float x2 = __fadd_rn(cx, hw), y2 = __fadd_rn(cy, hh);
  x1 = fminf(fmaxf(x1, 0.0f), 1216.0f);
  x2 = fminf(fmaxf(x2, 0.0f), 1216.0f);
  y1 = fminf(fmaxf(y1, 0.0f), 800.0f);
  y2 = fminf(fmaxf(y2, 0.0f), 800.0f);
  float s = __fdiv_rn(1.0f, __fadd_rn(1.0f, expf(-o)));
  int v = (__fsub_rn(x2, x1) >= 0.001f) && (__fsub_rn(y2, y1) >= 0.001f) && (s >= 0.0f);
  float* bo = boxes + (size_t)g * 4;
  bo[0] = x1; bo[1] = y1; bo[2] = x2; bo[3] = y2;
  scores[g] = s;
  valid[g] = (u32)v;
}

// ---------- K3: suppression bitmask, 256-row x 64-col (one-word) slabs ----------
__global__ void __launch_bounds__(256)
k_mask(const float* __restrict__ boxes, u64* __restrict__ mask)
{
  int b = blockIdx.x / 184, s = blockIdx.x % 184;
  int l, idx;
  if (s < 160){ l = s / 40; idx = s % 40; }
  else        { l = 4;      idx = s - 160; }   // level 4: first 24 entries (w<=11)
  int w = c_MW[idx], rb = c_MR[idx];
  int N = c_LK[l];
  int koff = l * 1000;
  float offv = (float)(l * 4096);   // exact
  __shared__ float sjx1[64], sjy1[64], sjx2[64], sjy2[64], sjar[64];
  int jbase = w * 64;
  if (threadIdx.x < 64){
    int j = jbase + (int)threadIdx.x;
    float x1, y1, x2, y2, ar;
    if (j < N){
      float4 p = ((const float4*)boxes)[(size_t)(b * KTOT + koff + j)];
      x1 = __fadd_rn(p.x, offv); y1 = __fadd_rn(p.y, offv);
      x2 = __fadd_rn(p.z, offv); y2 = __fadd_rn(p.w, offv);
      ar = __fmul_rn(__fsub_rn(x2, x1), __fsub_rn(y2, y1));
    } else {
      x1 = 3e38f; y1 = 3e38f; x2 = -3e38f; y2 = -3e38f; ar = 0.f;
    }
    sjx1[threadIdx.x] = x1; sjy1[threadIdx.x] = y1;
    sjx2[threadIdx.x] = x2; sjy2[threadIdx.x] = y2; sjar[threadIdx.x] = ar;
  }
  __syncthreads();
  int i = rb * 256 + (int)threadIdx.x;
  int rows = (w + 1) * 64; if (rows > N) rows = N;
  if (i >= rows) return;
  float4 p = ((const float4*)boxes)[(size_t)(b * KTOT + koff + i)];
  float bx1 = __fadd_rn(p.x, offv), by1 = __fadd_rn(p.y, offv);
  float bx2 = __fadd_rn(p.z, offv), by2 = __fadd_rn(p.w, offv);
  float bar = __fmul_rn(__fsub_rn(bx2, bx1), __fsub_rn(by2, by1));
  u64 bw = 0;
  #pragma unroll 16
  for (int jj = 0; jj < 64; ++jj){
    int j = jbase + jj;
    float ltx = fmaxf(bx1, sjx1[jj]), lty = fmaxf(by1, sjy1[jj]);
    float rbx = fminf(bx2, sjx2[jj]), rby = fminf(by2, sjy2[jj]);
    float wx = fmaxf(__fsub_rn(rbx, ltx), 0.0f);
    float wy = fmaxf(__fsub_rn(rby, lty), 0.0f);
    float inter = __fmul_rn(wx, wy);
    bool sup = false;
    if (inter > 0.0f && j > i){
      float den = __fsub_rn(__fadd_rn(bar, sjar[jj]), inter);
      sup = __fdiv_rn(inter, den) > 0.7f;
    }
    bw |= ((u64)sup) << jj;
  }
  mask[((size_t)(b * 5 + l) * 16 + w) * 1024 + i] = bw;
}

// ---------- K4: exact greedy NMS, sparse-conflict fast path ----------
__global__ void __launch_bounds__(256)
k_nms(const u64* __restrict__ mask, const u32* __restrict__ valid,
      const float* __restrict__ scores, u64* __restrict__ outk,
      u64* __restrict__ keepw)
{
  int bl = blockIdx.x; int b = bl / 5, l = bl % 5;
  int N = c_LK[l], koff = l * 1000;
  int WN = (N + 63) >> 6;           // 16 (levels 0-3) or 12 (level 4)
  int tid = threadIdx.x;
  __shared__ u64 s_kw[16];
  __shared__ u64 s_m[7680];         // 60 KiB: word w at 64*w*(w+1)/2, rows <(w+1)*64
  const u64* mb = mask + (size_t)bl * 16 * 1024;
  int wstage = (WN < 15) ? WN : 15;
  for (int w = 0; w < wstage; ++w){
    int rows = (w + 1) * 64;
    int base = 32 * w * (w + 1);    // = 64*w*(w+1)/2
    for (int r = tid; r < rows; r += 256)
      s_m[base + r] = mb[(size_t)w * 1024 + r];
  }
  __syncthreads();
  if (tid < 64){
    int lane = tid;
    // keep init = valid
    for (int c = 0; c < WN; ++c){
      int i = c * 64 + lane;
      int pred = (i < N) && (valid[(size_t)b * KTOT + koff + i] != 0u);
      u64 bal = __ballot(pred);
      if (lane == 0) s_kw[c] = bal;
    }
    for (int w = 0; w < WN; ++w){
      u64 kwv = s_kw[w];            // broadcast read (uniform)
      // cross-word suppression of word w's columns from finalized kept rows
      u64 supl = 0;
      if (w < 15){
        int base = 32 * w * (w + 1);
        for (int jb = 0; jb < w; ++jb){
          u64 kb = s_kw[jb];
          u64 m = s_m[base + jb * 64 + lane];            // unconditional ds_read
          supl |= (((kb >> lane) & 1ULL) ? m : 0ULL);
        }
      } else {
        for (int jb = 0; jb < w; ++jb){
          u64 kb = s_kw[jb];
          u64 m = mb[(size_t)w * 1024 + jb * 64 + lane]; // unconditional global
          supl |= (((kb >> lane) & 1ULL) ? m : 0ULL);
        }
      }
      // in-word rows (lane r owns row w*64+r's word-w column bits)
      int jr = w * 64 + lane;
      u64 rowl;
      if (w < 15) rowl = s_m[32 * w * (w + 1) + jr];     // diagonal rows staged
      else        rowl = (jr < N) ? mb[(size_t)w * 1024 + jr] : 0ULL;
      // per-lane in-word conflict contribution (candidates only)
      bool inC = ((kwv >> lane) & 1ULL) != 0ULL;
      u64 rkw = rowl & kwv;
      u64 confl = inC ? rkw : 0ULL;
      // fused OR-reduce of (supl, conf) across 64 lanes
      u32 a0 = (u32)supl, a1 = (u32)(supl >> 32);
      u32 a2 = (u32)confl, a3 = (u32)(confl >> 32);
      for (int off = 32; off; off >>= 1){
        a0 |= __shfl_xor(a0, off);
        a1 |= __shfl_xor(a1, off);
        a2 |= __shfl_xor(a2, off);
        a3 |= __shfl_xor(a3, off);
      }
      supl = ((u64)a1 << 32) | a0;
      u64 conf = ((u64)a3 << 32) | a2;          // union of in-word targets
      u64 srcb = __ballot(inC && (rkw != 0ULL)); // in-word source lanes
      u64 cur = kwv & ~supl;
      u64 kept = cur;
      if (((srcb & cur) != 0ULL) && ((conf & cur) != 0ULL)){
        // serial greedy over conflict-involved bits only
        u32 rowl_lo = (u32)rowl, rowl_hi = (u32)(rowl >> 32);
        u64 act = cur & (srcb | conf);
        while (act){
          int ib  = __ffsll((unsigned long long)act) - 1;  // wave-uniform
          int ibs = __builtin_amdgcn_readfirstlane(ib);
          u64 bit = 1ULL << ibs;
          act &= ~bit;
          if (kept & bit){
            u32 rlo = (u32)__builtin_amdgcn_readlane((int)rowl_lo, ibs);
            u32 rhi = (u32)__builtin_amdgcn_readlane((int)rowl_hi, ibs);
            u64 r   = ((u64)rhi << 32) | rlo;
            kept &= ~r;
            act  &= ~r;
          }
        }
      }
      if (lane == 0) s_kw[w] = kept;
    }
  }
  __syncthreads();
  // export keep words (zero beyond WN so popcounts are exact)
  if (tid < 16) keepw[(size_t)bl * 16 + tid] = (tid < WN) ? s_kw[tid] : 0ULL;
  // emit final-merge keys: (~fmap(score))<<32 | concat_pos ; suppressed -> ~0
  for (int i = tid; i < N; i += 256){
    u64 key = ~0ULL;
    if ((s_kw[i >> 6] >> (i & 63)) & 1ULL){
      float sc = scores[(size_t)b * KTOT + koff + i];
      key = ((u64)(~fmap(sc)) << 32) | (u32)(koff + i);
    }
    outk[(size_t)b * KTOT + koff + i] = key;
  }
}

// ---------- K5: 5-way merge-rank final selection (O(K log K)) ----------
#define CMPN 1024   // per-level compacted list, padded with ~0ULL (kept count <= 1000)
__global__ void __launch_bounds__(256)
k_rank(const u64* __restrict__ outk, const u64* __restrict__ keepw,
       const float* __restrict__ boxes, float* __restrict__ out)
{
  int b = blockIdx.x / 19, chunk = blockIdx.x % 19;
  int tid = threadIdx.x;
  __shared__ u64 cmp[5 * CMPN];   // 40 KiB
  __shared__ u64 kw[80];          // keep words for this image's 5 levels
  for (int i = tid; i < 5 * CMPN; i += 256) cmp[i] = ~0ULL;
  if (tid < 80) kw[tid] = keepw[(size_t)b * 80 + tid];
  __syncthreads();
  // scatter-compact kept keys per level (rank via popcount prefix; no atomics)
  for (int i = tid; i < KTOT; i += 256){
    u64 key = outk[(size_t)b * KTOT + i];
    if (key != ~0ULL){
      int l = i / 1000; if (l > 4) l = 4;
      int li = i - l * 1000;
      int wi = li >> 6, bit = li & 63;
      const u64* kwl = &kw[l * 16];
      int r = __popcll(kwl[wi] & ((1ULL << bit) - 1ULL));
      for (int w = 0; w < wi; ++w) r += __popcll(kwl[w]);
      cmp[l * CMPN + r] = key;
    }
  }
  __syncthreads();
  int i = chunk * 256 + tid;
  if (i >= KTOT) return;
  u64 key = outk[(size_t)b * KTOT + i];
  if (key == ~0ULL) return;     // suppressed / invalid
  int l = i / 1000; if (l > 4) l = 4;
  int li = i - l * 1000;
  int wi = li >> 6, bit = li & 63;
  const u64* kwl = &kw[l * 16];
  int rank = __popcll(kwl[wi] & ((1ULL << bit) - 1ULL));
  for (int w = 0; w < wi; ++w) rank += __popcll(kwl[w]);
  #pragma unroll
  for (int lo = 0; lo < 5; ++lo){
    if (lo == l) continue;
    int pos = 0;
    #pragma unroll
    for (int s = 512; s > 0; s >>= 1)
      if (cmp[lo * CMPN + pos + s - 1] < key) pos += s;
    rank += pos;   // count of kept keys in level lo that are < key
  }
  if (rank < 1000){
    float4 bx = ((const float4*)boxes)[(size_t)(b * KTOT + i)];
    ((float4*)out)[(size_t)(b * 1000 + rank)] = bx;
    out[32000 + b * 1000 + rank] = funmap(~(u32)(key >> 32));
  }
}

extern "C" void kernel_launch(void* const* d_in, const int* in_sizes, int n_in,
                              void* d_out, int out_size, void* d_ws, size_t ws_size,
                              hipStream_t stream)
{
  (void)in_sizes; (void)n_in; (void)out_size; (void)ws_size; // needs ~8.73 MB ws
  const float* obj     = (const float*)d_in[0];
  const float* deltas  = (const float*)d_in[1];
  const float* anchors = (const float*)d_in[2];
  float* out = (float*)d_out;
  char* ws = (char*)d_ws;

  u32* hist    = (u32*)(ws + OFF_HIST);
  u64* keepw   = (u64*)(ws + OFF_KEEPW);   // aliases hist (dead by k_nms time)
  u32* selcnt  = (u32*)(ws + OFF_SELCNT);
  u32* candcnt = (u32*)(ws + OFF_CANDCNT);
  u32* tbin    = (u32*)(ws + OFF_TBIN);
  u32* cless   = (u32*)(ws + OFF_CLESS);
  u64* selg    = (u64*)(ws + OFF_SELG);
  u64* candg   = (u64*)(ws + OFF_CANDG);
  u64* keys    = (u64*)(ws + OFF_KEYS);
  float* boxes = (float*)(ws + OFF_BOX);
  float* score = (float*)(ws + OFF_SCORE);
  u32* valid   = (u32*)(ws + OFF_VALID);
  u64* mask    = (u64*)(ws + OFF_MASK);
  u64* outk    = (u64*)(ws + OFF_OUTK);

  // one fused zero kernel instead of two slow runtime fills (~41 us each)
  hipLaunchKernelGGL(k_zero,    dim3((ZWS + ZOUT + 255) / 256), dim3(256), 0, stream,
                     (u32*)ws, (u32*)out);
  hipLaunchKernelGGL(k_hist,    dim3(264),  dim3(1024), 0, stream, obj, hist);
  hipLaunchKernelGGL(k_cutoff,  dim3(40),   dim3(256),  0, stream, hist, tbin, cless);
  hipLaunchKernelGGL(k_collect, dim3(264),  dim3(1024), 0, stream, obj, tbin, selcnt, candcnt, selg, candg);
  hipLaunchKernelGGL(k_select,  dim3(40),   dim3(1024), 0, stream, selcnt, candcnt, selg, candg, keys);
  hipLaunchKernelGGL(k_decode,  dim3(149),  dim3(256),  0, stream, keys, deltas, anchors, boxes, score, valid);
  hipLaunchKernelGGL(k_mask,    dim3(1472), dim3(256),  0, stream, boxes, mask);
  hipLaunchKernelGGL(k_nms,     dim3(40),   dim3(256),  0, stream, mask, valid, score, outk, keepw);
  hipLaunchKernelGGL(k_rank,    dim3(152),  dim3(256),  0, stream, outk, keepw, boxes, out);
}